// Round 2
// baseline (6379.123 us; speedup 1.0000x reference)
//
#include <hip/hip_runtime.h>
#include <hip/hip_bf16.h>
#include <math.h>

typedef __attribute__((ext_vector_type(8))) short           short8;   // 8 bf16 (4 VGPRs)
typedef __attribute__((ext_vector_type(8))) unsigned short  ushort8;
typedef __attribute__((ext_vector_type(4))) float           f32x4;

__device__ __forceinline__ float lreluf(float v){ return v >= 0.f ? v : 0.01f*v; }
__device__ __forceinline__ float sigf(float v){ return 1.f/(1.f + expf(-v)); }

#define OP_NONE  0
#define OP_LRELU 1
#define OP_RELU  2

__device__ __forceinline__ float applyOp(float v, int op){
  if (op == OP_LRELU) return v >= 0.f ? v : 0.01f*v;
  if (op == OP_RELU)  return v > 0.f ? v : 0.f;
  return v;
}

// f32 -> bf16 RNE, raw ushort
__device__ __forceinline__ unsigned short f2b(float f){
  unsigned x = __float_as_uint(f);
  unsigned lsb = (x >> 16) & 1u;
  return (unsigned short)((x + 0x7fffu + lsb) >> 16);
}
__device__ __forceinline__ float b2f(unsigned short h){
  return __uint_as_float((unsigned)h << 16);
}

__device__ __forceinline__ float blkSum(float v, float* red){
  int t = threadIdx.x;
  red[t] = v; __syncthreads();
  for (int s = 128; s > 0; s >>= 1){ if (t < s) red[t] += red[t+s]; __syncthreads(); }
  float r = red[0]; __syncthreads();
  return r;
}
__device__ __forceinline__ float blkMax(float v, float* red){
  int t = threadIdx.x;
  red[t] = v; __syncthreads();
  for (int s = 128; s > 0; s >>= 1){ if (t < s) red[t] = fmaxf(red[t], red[t+s]); __syncthreads(); }
  float r = red[0]; __syncthreads();
  return r;
}

// 3-product split-precision accumulate: acc += (aH+aL)*(bH+bL) (drop lo*lo)
__device__ __forceinline__ f32x4 mfma3(short8 aH, short8 aL, short8 bH, short8 bL, f32x4 acc){
  acc = __builtin_amdgcn_mfma_f32_16x16x32_bf16(aL, bH, acc, 0, 0, 0);
  acc = __builtin_amdgcn_mfma_f32_16x16x32_bf16(aH, bL, acc, 0, 0, 0);
  acc = __builtin_amdgcn_mfma_f32_16x16x32_bf16(aH, bH, acc, 0, 0, 0);
  return acc;
}

// ---- load A fragment (8 f32) and convert to split bf16 in registers ----
__device__ __forceinline__ void loadA2(const float* __restrict__ A, int M, int row, int ks,
                                       short8& aH, short8& aL)
{
  float f[8];
  if (row < M){
    const float* p = A + (size_t)row*256 + ks;
    float4 f0 = *(const float4*)p, f1 = *(const float4*)(p+4);
    f[0]=f0.x; f[1]=f0.y; f[2]=f0.z; f[3]=f0.w;
    f[4]=f1.x; f[5]=f1.y; f[6]=f1.z; f[7]=f1.w;
  } else {
    #pragma unroll
    for (int u = 0; u < 8; ++u) f[u] = 0.f;
  }
  #pragma unroll
  for (int u = 0; u < 8; ++u){
    unsigned short hh = f2b(f[u]);
    aH[u] = (short)hh;
    aL[u] = (short)f2b(f[u] - b2f(hh));
  }
}

// ================= weight pre-split: f32 [rows][lda] -> H/L ushort [rows][K] =================
__global__ void wsplit_k(const float* __restrict__ src, unsigned short* __restrict__ Hd,
                         unsigned short* __restrict__ Ld, int lda, int K, long long tot)
{
  long long i = (long long)blockIdx.x*256 + threadIdx.x;
  if (i >= tot) return;
  long long r = i / K; int c = (int)(i % K);
  float v = src[r*lda + c];
  unsigned short h = f2b(v);
  Hd[r*(long long)K + c] = h;
  Ld[r*(long long)K + c] = f2b(v - b2f(h));
}

// ---- stage 64x32 f32 tile -> split bf16 hi/lo LDS [64][32]. 256 threads. ----
// (kept for the K!=256 GEMMs: lin1 / lin2-head / fc1-head)
__device__ __forceinline__ void stage2(const float* __restrict__ src, int lda,
    int row0, int rowmax, int k0, int K,
    unsigned short* __restrict__ ldsH, unsigned short* __restrict__ ldsL, int tid)
{
  int r = tid >> 2, kc = (tid & 3) * 8;
  int gr = row0 + r, gk = k0 + kc;
  const float* p = src + (size_t)gr*lda + gk;
  float f[8];
  if (gr < rowmax && gk + 8 <= K && ((lda & 3) == 0)){
    float4 f0 = *(const float4*)p;
    float4 f1 = *(const float4*)(p+4);
    f[0]=f0.x; f[1]=f0.y; f[2]=f0.z; f[3]=f0.w;
    f[4]=f1.x; f[5]=f1.y; f[6]=f1.z; f[7]=f1.w;
  } else {
    #pragma unroll
    for (int j = 0; j < 8; ++j) f[j] = (gr < rowmax && gk + j < K) ? p[j] : 0.f;
  }
  ushort8 vh, vl;
  #pragma unroll
  for (int j = 0; j < 8; ++j){
    unsigned short h = f2b(f[j]);
    vh[j] = h;
    vl[j] = f2b(f[j] - b2f(h));
  }
  *(ushort8*)&ldsH[r*32 + kc] = vh;
  *(ushort8*)&ldsL[r*32 + kc] = vl;
}

// ---------------- split-MFMA GEMM (LDS path, generic K): C = act(A @ W^T + bias) ----------------
__global__ __launch_bounds__(256) void gemm_mfma_k(
    const float* __restrict__ A, int lda,
    const float* __restrict__ W, int ldw,
    const float* __restrict__ bias,
    float* __restrict__ C,
    int M, int N, int K, int op)
{
  __shared__ unsigned short AsH[64*32], AsL[64*32];
  __shared__ unsigned short WsH[64*32], WsL[64*32];
  const int tid = threadIdx.x;
  const int bm = blockIdx.y * 64, bn = blockIdx.x * 64;
  const int wave = tid >> 6, lane = tid & 63;
  const int wr = wave >> 1, wc = wave & 1;
  const int quad = lane >> 4, id = lane & 15;

  f32x4 acc[2][2] = {};
  const int iters = (K + 31) / 32;
  for (int kt = 0; kt < iters; ++kt){
    int k0 = kt * 32;
    stage2(A, lda, bm, M, k0, K, AsH, AsL, tid);
    stage2(W, ldw, bn, N, k0, K, WsH, WsL, tid);
    __syncthreads();
    short8 aH[2], aL[2], bH[2], bL[2];
    #pragma unroll
    for (int i = 0; i < 2; ++i){
      int off = (wr*32 + i*16 + id)*32 + quad*8;
      aH[i] = *(const short8*)&AsH[off];
      aL[i] = *(const short8*)&AsL[off];
    }
    #pragma unroll
    for (int j = 0; j < 2; ++j){
      int off = (wc*32 + j*16 + id)*32 + quad*8;
      bH[j] = *(const short8*)&WsH[off];
      bL[j] = *(const short8*)&WsL[off];
    }
    #pragma unroll
    for (int i = 0; i < 2; ++i)
      #pragma unroll
      for (int j = 0; j < 2; ++j)
        acc[i][j] = mfma3(aH[i], aL[i], bH[j], bL[j], acc[i][j]);
    __syncthreads();
  }
  #pragma unroll
  for (int i = 0; i < 2; ++i){
    int gr0 = bm + wr*32 + i*16 + quad*4;
    #pragma unroll
    for (int j = 0; j < 2; ++j){
      int gc = bn + wc*32 + j*16 + id;
      if (gc >= N) continue;
      float bv = bias ? bias[gc] : 0.f;
      #pragma unroll
      for (int r = 0; r < 4; ++r){
        int row = gr0 + r;
        if (row < M)
          C[(size_t)row*N + gc] = applyOp(acc[i][j][r] + bv, op);
      }
    }
  }
}

// ---------------- direct-load GEMM: C[M,256] = A[M,256] @ Wpre[256,256]^T ----------------
// No LDS, no barriers. W pre-split bf16 hi/lo row-major. A f32, converted in-register.
__global__ __launch_bounds__(256) void gemm_pre_k(const float* __restrict__ A,
    const unsigned short* __restrict__ WH_, const unsigned short* __restrict__ WL_,
    float* __restrict__ C, int M)
{
  // XCD-bijective swizzle: each XCD gets a contiguous run of (bm,bn) with bn fastest
  int nwg = gridDim.x, bid = blockIdx.x;
  int q = nwg >> 3, r = nwg & 7;
  int xcd = bid & 7, jj = bid >> 3;
  int idx = (xcd < r ? xcd*(q+1) : r*(q+1) + (xcd - r)*q) + jj;
  const int bm = (idx >> 2)*64, bn = (idx & 3)*64;
  const int tid = threadIdx.x;
  const int wave = tid >> 6, lane = tid & 63;
  const int wr = wave >> 1, wc = wave & 1;
  const int quad = lane >> 4, id = lane & 15;
  const int arow0 = bm + wr*32 + id;
  const int brow0 = bn + wc*32 + id;

  f32x4 acc[2][2] = {};
  for (int k8 = 0; k8 < 8; ++k8){
    const int ks = k8*32 + quad*8;
    short8 aH[2], aL[2];
    #pragma unroll
    for (int i = 0; i < 2; ++i) loadA2(A, M, arow0 + i*16, ks, aH[i], aL[i]);
    #pragma unroll
    for (int j = 0; j < 2; ++j){
      size_t ro = (size_t)(brow0 + j*16)*256 + ks;
      short8 bH = *(const short8*)&WH_[ro];
      short8 bL = *(const short8*)&WL_[ro];
      #pragma unroll
      for (int i = 0; i < 2; ++i)
        acc[i][j] = mfma3(aH[i], aL[i], bH, bL, acc[i][j]);
    }
  }
  #pragma unroll
  for (int i = 0; i < 2; ++i){
    int gr0 = bm + wr*32 + i*16 + quad*4;
    #pragma unroll
    for (int j = 0; j < 2; ++j){
      int gc = bn + wc*32 + j*16 + id;
      #pragma unroll
      for (int rr = 0; rr < 4; ++rr){
        int row = gr0 + rr;
        if (row < M) C[(size_t)row*256 + gc] = acc[i][j][rr];
      }
    }
  }
}

// ---------------- direct-load GRU phase helper ----------------
__device__ __forceinline__ void gru_phase(const float* __restrict__ A,
    const unsigned short* __restrict__ WH_, const unsigned short* __restrict__ WL_,
    int M, int arow0, int brow0, int quad,
    f32x4 (&accR)[2][2], f32x4 (&accZ)[2][2], f32x4 (&accN)[2][2])
{
  for (int k8 = 0; k8 < 8; ++k8){
    const int ks = k8*32 + quad*8;
    short8 aH[2], aL[2];
    #pragma unroll
    for (int i = 0; i < 2; ++i) loadA2(A, M, arow0 + i*16, ks, aH[i], aL[i]);
    #pragma unroll
    for (int j = 0; j < 2; ++j){
      size_t ro = (size_t)(brow0 + j*16)*256 + ks;
      short8 brH = *(const short8*)&WH_[ro];
      short8 brL = *(const short8*)&WL_[ro];
      short8 bzH = *(const short8*)&WH_[ro + 65536];
      short8 bzL = *(const short8*)&WL_[ro + 65536];
      short8 bnH = *(const short8*)&WH_[ro + 131072];
      short8 bnL = *(const short8*)&WL_[ro + 131072];
      #pragma unroll
      for (int i = 0; i < 2; ++i){
        accR[i][j] = mfma3(aH[i], aL[i], brH, brL, accR[i][j]);
        accZ[i][j] = mfma3(aH[i], aL[i], bzH, bzL, accZ[i][j]);
        accN[i][j] = mfma3(aH[i], aL[i], bnH, bnL, accN[i][j]);
      }
    }
  }
}

// ---------------- direct-load fused GRU: Out = relu(gru(Xin, Hid)) ----------------
// Weights pre-split bf16 [768][256] hi/lo, gate order r,z,n. No LDS, no barriers.
__global__ __launch_bounds__(256) void gru_pre_k(
    const float* __restrict__ Xin, const float* __restrict__ Hid,
    const unsigned short* __restrict__ wihH, const unsigned short* __restrict__ wihL,
    const unsigned short* __restrict__ whhH, const unsigned short* __restrict__ whhL,
    const float* __restrict__ bih, const float* __restrict__ bhh,
    float* __restrict__ Out, int M)
{
  int nwg = gridDim.x, bid = blockIdx.x;
  int q = nwg >> 3, r = nwg & 7;
  int xcd = bid & 7, jj = bid >> 3;
  int idx = (xcd < r ? xcd*(q+1) : r*(q+1) + (xcd - r)*q) + jj;
  const int bm = (idx >> 2)*64, bn = (idx & 3)*64;
  const int tid = threadIdx.x;
  const int wave = tid >> 6, lane = tid & 63;
  const int wr = wave >> 1, wc = wave & 1;
  const int quad = lane >> 4, id = lane & 15;
  const int arow0 = bm + wr*32 + id;
  const int brow0 = bn + wc*32 + id;

  f32x4 accR[2][2] = {}, accZ[2][2] = {}, accI[2][2] = {}, accH[2][2] = {};

  gru_phase(Xin, wihH, wihL, M, arow0, brow0, quad, accR, accZ, accI);
  gru_phase(Hid, whhH, whhL, M, arow0, brow0, quad, accR, accZ, accH);

  #pragma unroll
  for (int i = 0; i < 2; ++i){
    int gr0 = bm + wr*32 + i*16 + quad*4;
    #pragma unroll
    for (int j = 0; j < 2; ++j){
      int gc = bn + wc*32 + j*16 + id;
      float br_  = bih[gc]     + bhh[gc];
      float bz_  = bih[256+gc] + bhh[256+gc];
      float bn_i = bih[512+gc], bn_h = bhh[512+gc];
      #pragma unroll
      for (int rr = 0; rr < 4; ++rr){
        int row = gr0 + rr;
        if (row >= M) continue;
        float rg = sigf(accR[i][j][rr] + br_);
        float zg = sigf(accZ[i][j][rr] + bz_);
        float ng = tanhf(accI[i][j][rr] + bn_i + rg*(accH[i][j][rr] + bn_h));
        float hv = Hid[(size_t)row*256 + gc];
        float o = (1.f - zg)*ng + zg*hv;
        Out[(size_t)row*256 + gc] = o > 0.f ? o : 0.f;
      }
    }
  }
}

// ---------------- row dots: y1[m]=dot(X[m,:256],w1), y2 optional ----------------
__global__ __launch_bounds__(256) void rowdot2_k(const float* __restrict__ X,
    const float* __restrict__ w1, const float* __restrict__ w2,
    float* __restrict__ y1, float* __restrict__ y2, int M)
{
  int m = blockIdx.x*4 + (threadIdx.x >> 6);
  if (m >= M) return;
  int lane = threadIdx.x & 63;
  float p1 = 0.f, p2 = 0.f;
  for (int c = lane; c < 256; c += 64){
    float xv = X[(size_t)m*256 + c];
    p1 += xv * w1[c];
    if (w2) p2 += xv * w2[c];
  }
  for (int o = 32; o > 0; o >>= 1){
    p1 += __shfl_down(p1, o);
    if (w2) p2 += __shfl_down(p2, o);
  }
  if (lane == 0){ y1[m] = p1; if (w2) y2[m] = p2; }
}

// ================= CSR build (dst-sorted incoming-edge lists) =================
__global__ void hist_k(const int* __restrict__ dst, unsigned* __restrict__ deg, int E){
  int e = blockIdx.x*256 + threadIdx.x;
  if (e >= E) return;
  atomicAdd(&deg[dst[e]], 1u);
}

__global__ __launch_bounds__(256) void scan1_k(const unsigned* __restrict__ deg,
    unsigned* __restrict__ incl, unsigned* __restrict__ bsum, int N)
{
  __shared__ unsigned sm[256];
  int t = threadIdx.x;
  int i = blockIdx.x*256 + t;
  unsigned v = (i < N) ? deg[i] : 0u;
  sm[t] = v; __syncthreads();
  for (int s = 1; s < 256; s <<= 1){
    unsigned u = (t >= s) ? sm[t - s] : 0u;
    __syncthreads();
    sm[t] += u;
    __syncthreads();
  }
  if (i < N) incl[i] = sm[t];
  if (t == 255) bsum[blockIdx.x] = sm[255];
}

__global__ __launch_bounds__(256) void scan2_k(unsigned* __restrict__ bsum, int nb){
  __shared__ unsigned sm[256];
  __shared__ unsigned carry;
  int t = threadIdx.x;
  if (t == 0) carry = 0u;
  __syncthreads();
  for (int base = 0; base < nb; base += 256){
    int i = base + t;
    unsigned v = (i < nb) ? bsum[i] : 0u;
    sm[t] = v; __syncthreads();
    for (int s = 1; s < 256; s <<= 1){
      unsigned u = (t >= s) ? sm[t - s] : 0u;
      __syncthreads();
      sm[t] += u;
      __syncthreads();
    }
    unsigned total = sm[255];
    unsigned c = carry;
    if (i < nb) bsum[i] = c + sm[t] - v;
    __syncthreads();
    if (t == 0) carry = c + total;
    __syncthreads();
  }
}

__global__ void scan3_k(const unsigned* __restrict__ incl, const unsigned* __restrict__ deg,
    const unsigned* __restrict__ bsum, unsigned* __restrict__ off, int N, int E)
{
  int i = blockIdx.x*256 + threadIdx.x;
  if (i < N) off[i] = incl[i] - deg[i] + bsum[blockIdx.x];
  if (i == 0) off[N] = (unsigned)E;
}

__global__ void fill_k(const int* __restrict__ src, const int* __restrict__ dst,
    const unsigned* __restrict__ off, unsigned* __restrict__ cur,
    int* __restrict__ csr_src, int* __restrict__ csr_eid, int E)
{
  int e = blockIdx.x*256 + threadIdx.x;
  if (e >= E) return;
  int d = dst[e];
  unsigned p = off[d] + atomicAdd(&cur[d], 1u);
  csr_src[p] = src[e];
  csr_eid[p] = e;
}

// ---------------- GATEConv edge score, written in CSR order ----------------
__global__ __launch_bounds__(256) void gate_edge_score_csr_k(
    const float* __restrict__ Y, const float* __restrict__ g_lin1W,
    const float* __restrict__ att_l, const float* __restrict__ ea_in,
    const float* __restrict__ xr, const int* __restrict__ csr_src,
    const int* __restrict__ csr_eid, const int* __restrict__ dst,
    float* __restrict__ a_out, int E, int H)
{
  int p = blockIdx.x*4 + (threadIdx.x >> 6);
  if (p >= E) return;
  int lane = threadIdx.x & 63;
  int s = csr_src[p];
  int e = csr_eid[p];
  int d = dst[e];
  float eav = ea_in[e];
  float acc = 0.f;
  for (int c = lane; c < 256; c += 64){
    float yv = Y[(size_t)s*256 + c] + eav * g_lin1W[(size_t)c*(H+1) + H];
    acc += lreluf(yv) * att_l[c];
  }
  for (int o = 32; o > 0; o >>= 1) acc += __shfl_down(acc, o);
  if (lane == 0) a_out[p] = lreluf(acc + xr[d]);
}

// ---------------- per-node segment softmax over CSR (no atomics) ----------------
__global__ void node_softmax_k(const unsigned* __restrict__ off, const int* __restrict__ csr_src,
    const float* __restrict__ nd1, const float* __restrict__ nd2,
    float* __restrict__ w, int N, int mode)
{
  int n = blockIdx.x*256 + threadIdx.x;
  if (n >= N) return;
  unsigned p0 = off[n], p1 = off[n+1];
  float m = -INFINITY;
  if (mode){
    float d = nd2[n];
    for (unsigned p = p0; p < p1; ++p){
      float a = lreluf(nd1[csr_src[p]] + d);
      w[p] = a;
      m = fmaxf(m, a);
    }
  } else {
    for (unsigned p = p0; p < p1; ++p) m = fmaxf(m, w[p]);
  }
  float ssum = 0.f;
  for (unsigned p = p0; p < p1; ++p){
    float e = expf(w[p] - m);
    w[p] = e; ssum += e;
  }
  float inv = (ssum > 0.f) ? 1.f/ssum : 0.f;
  for (unsigned p = p0; p < p1; ++p) w[p] *= inv;
}

// ---------------- gather: h[n] = elu( sum_e w[e]*Z[src[e]] + bias ) ----------------
__global__ __launch_bounds__(256) void gather_h_k(const float* __restrict__ Z,
    const float* __restrict__ w, const unsigned* __restrict__ off,
    const int* __restrict__ csr_src, const float* __restrict__ bias,
    float* __restrict__ h, int N)
{
  int n = blockIdx.x*4 + (threadIdx.x >> 6);
  if (n >= N) return;
  int lane = threadIdx.x & 63;
  unsigned p0 = off[n], p1 = off[n+1];
  float4 acc = make_float4(0.f, 0.f, 0.f, 0.f);
  for (unsigned p = p0; p < p1; ++p){
    float wv = w[p];
    const float4 z = *(const float4*)&Z[(size_t)csr_src[p]*256 + lane*4];
    acc.x = fmaf(wv, z.x, acc.x);
    acc.y = fmaf(wv, z.y, acc.y);
    acc.z = fmaf(wv, z.z, acc.z);
    acc.w = fmaf(wv, z.w, acc.w);
  }
  const float4 b = *(const float4*)&bias[lane*4];
  float4 o;
  float v;
  v = acc.x + b.x; o.x = v > 0.f ? v : expf(v) - 1.f;
  v = acc.y + b.y; o.y = v > 0.f ? v : expf(v) - 1.f;
  v = acc.z + b.z; o.z = v > 0.f ? v : expf(v) - 1.f;
  v = acc.w + b.w; o.w = v > 0.f ? v : expf(v) - 1.f;
  *(float4*)&h[(size_t)n*256 + lane*4] = o;
}

// ---------------- pooling ----------------
__global__ void seg_bounds_k(const int* __restrict__ batch, unsigned* __restrict__ gs,
                             unsigned* __restrict__ ge, int N){
  int n = blockIdx.x*256 + threadIdx.x;
  if (n >= N) return;
  int g = batch[n];
  atomicMin(&gs[g], (unsigned)n);
  atomicMax(&ge[g], (unsigned)(n+1));
}
__global__ __launch_bounds__(256) void graph_pool_k(const float* __restrict__ x,
    const unsigned* __restrict__ gs, const unsigned* __restrict__ ge,
    float* __restrict__ outg)
{
  int g = blockIdx.x, t = threadIdx.x;
  unsigned s0 = gs[g], e0 = ge[g];
  float acc = 0.f;
  for (unsigned n = s0; n < e0; ++n) acc += x[(size_t)n*256 + t];
  outg[(size_t)g*256 + t] = acc > 0.f ? acc : 0.f;
}
__global__ void precompute_v_k(const float* __restrict__ W, const float* __restrict__ ad,
                               float* __restrict__ v){
  int i = threadIdx.x;
  float acc = 0.f;
  for (int j = 0; j < 256; ++j) acc += W[(size_t)j*256 + i] * ad[j];
  v[i] = acc;
}
// fused mol attention timestep
__global__ __launch_bounds__(256) void mol_pool_k(const float* __restrict__ outg,
    const float* __restrict__ v, const float* __restrict__ asrc,
    const float* __restrict__ xw, const unsigned* __restrict__ gs,
    const unsigned* __restrict__ geb, const float* __restrict__ bias,
    float* __restrict__ hg)
{
  __shared__ float red[256];
  int g = blockIdx.x, t = threadIdx.x;
  float tg = blkSum(outg[(size_t)g*256 + t] * v[t], red);
  unsigned s0 = gs[g], e0 = geb[g];
  float mx = -INFINITY;
  for (unsigned n = s0 + t; n < e0; n += 256) mx = fmaxf(mx, lreluf(asrc[n] + tg));
  mx = blkMax(mx, red);
  float sm = 0.f;
  for (unsigned n = s0 + t; n < e0; n += 256) sm += expf(lreluf(asrc[n] + tg) - mx);
  sm = blkSum(sm, red);
  float acc = 0.f;
  if (e0 > s0 && sm > 0.f){
    float inv = 1.f / sm;
    for (unsigned n = s0; n < e0; ++n){
      float w = expf(lreluf(asrc[n] + tg) - mx) * inv;
      acc = fmaf(w, xw[(size_t)n*256 + t], acc);
    }
  }
  float h = acc + bias[t];
  hg[(size_t)g*256 + t] = h > 0.f ? h : expf(h) - 1.f;
}

// ---------------- launcher ----------------
extern "C" void kernel_launch(void* const* d_in, const int* in_sizes, int n_in,
                              void* d_out, int out_size, void* d_ws, size_t ws_size,
                              hipStream_t stream)
{
  (void)n_in; (void)ws_size;
  const int H    = in_sizes[3];          // 256
  const int NIN  = in_sizes[2] / H;      // 300
  const int N    = in_sizes[0] / NIN;    // 100000
  const int E    = in_sizes[1];          // 400000
  const int NL   = in_sizes[16] / H;     // 3
  const int NHID = in_sizes[30];         // 512
  const int NOUT = in_sizes[32];         // 768
  const int G    = out_size / NOUT;      // 2048
  const int T    = 16;

  const float* x_in     = (const float*)d_in[0];
  const float* ea_in    = (const float*)d_in[1];
  const float* lin1_W   = (const float*)d_in[2];
  const float* lin1_b   = (const float*)d_in[3];
  const float* g_lin1W  = (const float*)d_in[4];
  const float* g_lin2W  = (const float*)d_in[5];
  const float* g_att_l  = (const float*)d_in[6];
  const float* g_att_r  = (const float*)d_in[7];
  const float* g_bias   = (const float*)d_in[8];
  const float* gru0_wih = (const float*)d_in[9];
  const float* gru0_whh = (const float*)d_in[10];
  const float* gru0_bih = (const float*)d_in[11];
  const float* gru0_bhh = (const float*)d_in[12];
  const float* atom_W   = (const float*)d_in[13];
  const float* atom_as  = (const float*)d_in[14];
  const float* atom_ad  = (const float*)d_in[15];
  const float* atom_b   = (const float*)d_in[16];
  const float* agru_wih = (const float*)d_in[17];
  const float* agru_whh = (const float*)d_in[18];
  const float* agru_bih = (const float*)d_in[19];
  const float* agru_bhh = (const float*)d_in[20];
  const float* mol_W    = (const float*)d_in[21];
  const float* mol_as   = (const float*)d_in[22];
  const float* mol_ad   = (const float*)d_in[23];
  const float* mol_b    = (const float*)d_in[24];
  const float* mgru_wih = (const float*)d_in[25];
  const float* mgru_whh = (const float*)d_in[26];
  const float* mgru_bih = (const float*)d_in[27];
  const float* mgru_bhh = (const float*)d_in[28];
  const float* lin2_W   = (const float*)d_in[29];
  const float* lin2_b   = (const float*)d_in[30];
  const float* fc1_W    = (const float*)d_in[31];
  const float* fc1_b    = (const float*)d_in[32];
  const int*  eidx      = (const int*)d_in[33];
  const int*  batch     = (const int*)d_in[34];
  const int*  srcI = eidx;
  const int*  dstI = eidx + E;

  char* wp = (char*)d_ws;
  auto alloc = [&](size_t bytes)->void*{
    void* p = (void*)wp;
    wp += (bytes + 255) & ~(size_t)255;
    return p;
  };
  float*    x     = (float*)alloc((size_t)N*H*4);
  float*    hb    = (float*)alloc((size_t)N*H*4);
  float*    tA    = (float*)alloc((size_t)N*H*4);
  float*    tB    = (float*)alloc((size_t)N*H*4);
  float*    ea    = (float*)alloc((size_t)E*4);       // CSR-ordered scores/weights
  float*    nd1   = (float*)alloc((size_t)N*4);
  float*    nd2   = (float*)alloc((size_t)N*4);
  float*    outg  = (float*)alloc((size_t)G*H*4);
  float*    outg2 = (float*)alloc((size_t)G*H*4);
  float*    hg    = (float*)alloc((size_t)G*H*4);
  unsigned* gsb   = (unsigned*)alloc((size_t)G*4);
  unsigned* geb   = (unsigned*)alloc((size_t)G*4);
  float*    vvec  = (float*)alloc((size_t)H*4);
  float*    o2    = (float*)alloc((size_t)G*NHID*4);
  // CSR structures
  const int nb = (N + 255) / 256;
  unsigned* deg     = (unsigned*)alloc((size_t)N*4);
  unsigned* cur     = (unsigned*)alloc((size_t)N*4);
  unsigned* incl    = (unsigned*)alloc((size_t)N*4);
  unsigned* off     = (unsigned*)alloc((size_t)(N+1)*4);
  unsigned* bsum    = (unsigned*)alloc((size_t)nb*4);
  int*      csr_src = (int*)alloc((size_t)E*4);
  int*      csr_eid = (int*)alloc((size_t)E*4);
  // pre-split weight buffers (ushort hi/lo)
  auto allocUS = [&](size_t elems)->unsigned short*{ return (unsigned short*)alloc(elems*2); };
  const size_t WG = (size_t)768*256;   // one GRU weight matrix
  const size_t WS = (size_t)256*256;   // one square GAT weight
  unsigned short *g0ihH = allocUS(WG), *g0ihL = allocUS(WG);
  unsigned short *g0hhH = allocUS(WG), *g0hhL = allocUS(WG);
  unsigned short *aihH  = allocUS(WG*NL), *aihL = allocUS(WG*NL);
  unsigned short *ahhH  = allocUS(WG*NL), *ahhL = allocUS(WG*NL);
  unsigned short *mihH  = allocUS(WG), *mihL = allocUS(WG);
  unsigned short *mhhH  = allocUS(WG), *mhhL = allocUS(WG);
  unsigned short *gl1H  = allocUS(WS), *gl1L = allocUS(WS);
  unsigned short *gl2H  = allocUS(WS), *gl2L = allocUS(WS);
  unsigned short *atWH  = allocUS(WS*NL), *atWL = allocUS(WS*NL);
  unsigned short *molH  = allocUS(WS), *molL = allocUS(WS);

  auto gemm = [&](const float* Ain, int lda, const float* W, int ldw, const float* bias,
                  float* Cout, int M_, int N_, int K_, int op){
    dim3 gr((N_ + 63)/64, (M_ + 63)/64);
    gemm_mfma_k<<<gr, dim3(256), 0, stream>>>(Ain, lda, W, ldw, bias, Cout, M_, N_, K_, op);
  };
  auto gemmp = [&](const float* Ain, const unsigned short* WH_, const unsigned short* WL_,
                   float* Cout, int M_){
    int nwg = ((M_ + 63)/64)*4;
    gemm_pre_k<<<dim3(nwg), dim3(256), 0, stream>>>(Ain, WH_, WL_, Cout, M_);
  };
  auto grup = [&](const float* xin, const float* hid,
                  const unsigned short* ihH, const unsigned short* ihL,
                  const unsigned short* hhH, const unsigned short* hhL,
                  const float* bih, const float* bhh, float* out, int M_){
    int nwg = ((M_ + 63)/64)*4;
    gru_pre_k<<<dim3(nwg), dim3(256), 0, stream>>>(xin, hid, ihH, ihL, hhH, hhL, bih, bhh, out, M_);
  };
  auto wsplit = [&](const float* src, unsigned short* Hd, unsigned short* Ld,
                    int lda, int K, long long rows){
    long long tot = rows * K;
    wsplit_k<<<dim3((unsigned)((tot + 255)/256)), dim3(256), 0, stream>>>(src, Hd, Ld, lda, K, tot);
  };

  // ---- pre-split all MFMA weights (cheap; removes per-block re-conversion)
  wsplit(gru0_wih, g0ihH, g0ihL, 256, 256, 768);
  wsplit(gru0_whh, g0hhH, g0hhL, 256, 256, 768);
  wsplit(agru_wih, aihH, aihL, 256, 256, (long long)NL*768);
  wsplit(agru_whh, ahhH, ahhL, 256, 256, (long long)NL*768);
  wsplit(mgru_wih, mihH, mihL, 256, 256, 768);
  wsplit(mgru_whh, mhhH, mhhL, 256, 256, 768);
  wsplit(g_lin1W,  gl1H, gl1L, H+1, 256, 256);
  wsplit(g_lin2W,  gl2H, gl2L, 256, 256, 256);
  wsplit(atom_W,   atWH, atWL, 256, 256, (long long)NL*256);
  wsplit(mol_W,    molH, molL, 256, 256, 256);

  // ---- build CSR of incoming edges (reused by all 4 attention layers)
  hipMemsetAsync(deg, 0, (size_t)N*4, stream);
  hist_k<<<dim3((E+255)/256), dim3(256), 0, stream>>>(dstI, deg, E);
  scan1_k<<<dim3(nb), dim3(256), 0, stream>>>(deg, incl, bsum, N);
  scan2_k<<<dim3(1), dim3(256), 0, stream>>>(bsum, nb);
  scan3_k<<<dim3(nb), dim3(256), 0, stream>>>(incl, deg, bsum, off, N, E);
  hipMemsetAsync(cur, 0, (size_t)N*4, stream);
  fill_k<<<dim3((E+255)/256), dim3(256), 0, stream>>>(srcI, dstI, off, cur, csr_src, csr_eid, E);

  // ---- input projection (K=300, zero-padded in staging; LDS path)
  gemm(x_in, NIN, lin1_W, NIN, lin1_b, x, N, H, NIN, OP_LRELU);

  // ---- GATEConv
  gemmp(x, gl1H, gl1L, tA, N);                                                 // Y
  rowdot2_k<<<dim3((N+3)/4), dim3(256), 0, stream>>>(x, g_att_r, (const float*)nullptr,
                                                     nd1, (float*)nullptr, N);
  gate_edge_score_csr_k<<<dim3((E+3)/4), dim3(256), 0, stream>>>(tA, g_lin1W, g_att_l,
                                                                 ea_in, nd1, csr_src, csr_eid,
                                                                 dstI, ea, E, H);
  gemmp(x, gl2H, gl2L, tA, N);                                                 // Z
  node_softmax_k<<<dim3(nb), dim3(256), 0, stream>>>(off, csr_src, nullptr, nullptr, ea, N, 0);
  gather_h_k<<<dim3((N+3)/4), dim3(256), 0, stream>>>(tA, ea, off, csr_src, g_bias, hb, N);
  grup(hb, x, g0ihH, g0ihL, g0hhH, g0hhL, gru0_bih, gru0_bhh, tB, N);
  { float* t = x; x = tB; tB = t; }

  // ---- atom GATConv layers
  for (int l = 0; l < NL; ++l){
    gemmp(x, atWH + (size_t)l*WS, atWL + (size_t)l*WS, tA, N);                 // xw
    rowdot2_k<<<dim3((N+3)/4), dim3(256), 0, stream>>>(tA, atom_as + (size_t)l*H,
                                                       atom_ad + (size_t)l*H, nd1, nd2, N);
    node_softmax_k<<<dim3(nb), dim3(256), 0, stream>>>(off, csr_src, nd1, nd2, ea, N, 1);
    gather_h_k<<<dim3((N+3)/4), dim3(256), 0, stream>>>(tA, ea, off, csr_src,
                                                        atom_b + (size_t)l*H, hb, N);
    grup(hb, x, aihH + (size_t)l*WG, aihL + (size_t)l*WG,
         ahhH + (size_t)l*WG, ahhL + (size_t)l*WG,
         agru_bih + (size_t)l*3*H, agru_bhh + (size_t)l*3*H, tB, N);
    { float* t = x; x = tB; tB = t; }
  }

  // ---- attentive pooling
  hipMemsetAsync(gsb, 0xFF, (size_t)G*4, stream);
  hipMemsetAsync(geb, 0x00, (size_t)G*4, stream);
  seg_bounds_k<<<dim3((N+255)/256), dim3(256), 0, stream>>>(batch, gsb, geb, N);
  graph_pool_k<<<dim3(G), dim3(256), 0, stream>>>(x, gsb, geb, outg);
  gemmp(x, molH, molL, hb, N);                                                 // xw (persists)
  rowdot2_k<<<dim3((N+3)/4), dim3(256), 0, stream>>>(hb, mol_as, (const float*)nullptr,
                                                     nd1, (float*)nullptr, N);
  precompute_v_k<<<dim3(1), dim3(256), 0, stream>>>(mol_W, mol_ad, vvec);
  float* og  = outg;
  float* og2 = outg2;
  for (int t = 0; t < T; ++t){
    mol_pool_k<<<dim3(G), dim3(256), 0, stream>>>(og, vvec, nd1, hb, gsb, geb, mol_b, hg);
    grup(hg, og, mihH, mihL, mhhH, mhhL, mgru_bih, mgru_bhh, og2, G);
    { float* tt = og; og = og2; og2 = tt; }
  }

  // ---- head
  gemm(og, H, lin2_W, H, lin2_b, o2, G, NHID, H, OP_RELU);
  gemm(o2, NHID, fc1_W, NHID, fc1_b, (float*)d_out, G, NOUT, NHID, OP_NONE);
}

// Round 3
// 4014.216 us; speedup vs baseline: 1.5891x; 1.5891x over previous
//
#include <hip/hip_runtime.h>
#include <hip/hip_bf16.h>
#include <math.h>

typedef __attribute__((ext_vector_type(8))) short           short8;   // 8 bf16 (4 VGPRs)
typedef __attribute__((ext_vector_type(8))) unsigned short  ushort8;
typedef __attribute__((ext_vector_type(4))) float           f32x4;

__device__ __forceinline__ float lreluf(float v){ return v >= 0.f ? v : 0.01f*v; }
__device__ __forceinline__ float sigf(float v){ return 1.f/(1.f + expf(-v)); }

#define OP_NONE  0
#define OP_LRELU 1
#define OP_RELU  2

__device__ __forceinline__ float applyOp(float v, int op){
  if (op == OP_LRELU) return v >= 0.f ? v : 0.01f*v;
  if (op == OP_RELU)  return v > 0.f ? v : 0.f;
  return v;
}

// f32 -> bf16 RNE, raw ushort
__device__ __forceinline__ unsigned short f2b(float f){
  unsigned x = __float_as_uint(f);
  unsigned lsb = (x >> 16) & 1u;
  return (unsigned short)((x + 0x7fffu + lsb) >> 16);
}
__device__ __forceinline__ float b2f(unsigned short h){
  return __uint_as_float((unsigned)h << 16);
}

// LDS tile [rows][32] ushort, 16B-chunk XOR swizzle: spreads 16 id-lanes (64B row
// stride) over 8 distinct 16B bank slots -> 2-way (free) instead of 8-way conflict.
__device__ __forceinline__ int ldsOff(int row, int chunk){
  return row*32 + ((chunk ^ ((row >> 1) & 3)) << 3);
}

__device__ __forceinline__ float blkSum(float v, float* red){
  int t = threadIdx.x;
  red[t] = v; __syncthreads();
  for (int s = 128; s > 0; s >>= 1){ if (t < s) red[t] += red[t+s]; __syncthreads(); }
  float r = red[0]; __syncthreads();
  return r;
}
__device__ __forceinline__ float blkMax(float v, float* red){
  int t = threadIdx.x;
  red[t] = v; __syncthreads();
  for (int s = 128; s > 0; s >>= 1){ if (t < s) red[t] = fmaxf(red[t], red[t+s]); __syncthreads(); }
  float r = red[0]; __syncthreads();
  return r;
}

// 3-product split-precision accumulate: acc += (aH+aL)*(bH+bL) (drop lo*lo)
__device__ __forceinline__ f32x4 mfma3(short8 aH, short8 aL, short8 bH, short8 bL, f32x4 acc){
  acc = __builtin_amdgcn_mfma_f32_16x16x32_bf16(aL, bH, acc, 0, 0, 0);
  acc = __builtin_amdgcn_mfma_f32_16x16x32_bf16(aH, bL, acc, 0, 0, 0);
  acc = __builtin_amdgcn_mfma_f32_16x16x32_bf16(aH, bH, acc, 0, 0, 0);
  return acc;
}

// ================= weight pre-split: f32 [rows][lda] -> H/L ushort [rows][K] =================
__global__ void wsplit_k(const float* __restrict__ src, unsigned short* __restrict__ Hd,
                         unsigned short* __restrict__ Ld, int lda, int K, long long tot)
{
  long long i = (long long)blockIdx.x*256 + threadIdx.x;
  if (i >= tot) return;
  long long r = i / K; int c = (int)(i % K);
  float v = src[r*lda + c];
  unsigned short h = f2b(v);
  Hd[r*(long long)K + c] = h;
  Ld[r*(long long)K + c] = f2b(v - b2f(h));
}

// ---- stage 64x32 f32 tile -> split bf16 hi/lo LDS (swizzled). 256 threads. generic K ----
__device__ __forceinline__ void stage2(const float* __restrict__ src, int lda,
    int row0, int rowmax, int k0, int K,
    unsigned short* __restrict__ ldsH, unsigned short* __restrict__ ldsL, int tid)
{
  int r = tid >> 2, c = tid & 3;
  int gr = row0 + r, gk = k0 + c*8;
  const float* p = src + (size_t)gr*lda + gk;
  float f[8];
  if (gr < rowmax && gk + 8 <= K && ((lda & 3) == 0)){
    float4 f0 = *(const float4*)p;
    float4 f1 = *(const float4*)(p+4);
    f[0]=f0.x; f[1]=f0.y; f[2]=f0.z; f[3]=f0.w;
    f[4]=f1.x; f[5]=f1.y; f[6]=f1.z; f[7]=f1.w;
  } else {
    #pragma unroll
    for (int j = 0; j < 8; ++j) f[j] = (gr < rowmax && gk + j < K) ? p[j] : 0.f;
  }
  ushort8 vh, vl;
  #pragma unroll
  for (int j = 0; j < 8; ++j){
    unsigned short h = f2b(f[j]);
    vh[j] = h;
    vl[j] = f2b(f[j] - b2f(h));
  }
  int off = ldsOff(r, c);
  *(ushort8*)&ldsH[off] = vh;
  *(ushort8*)&ldsL[off] = vl;
}

// ---- stage 64x32 pre-split W tile -> LDS (pure copy, swizzled). rows always in-bounds ----
__device__ __forceinline__ void stageW(const unsigned short* __restrict__ WH_,
    const unsigned short* __restrict__ WL_, int row0, int k0,
    unsigned short* __restrict__ ldsH, unsigned short* __restrict__ ldsL, int tid)
{
  int r = tid >> 2, c = tid & 3;
  size_t go = (size_t)(row0 + r)*256 + k0 + c*8;
  ushort8 vh = *(const ushort8*)&WH_[go];
  ushort8 vl = *(const ushort8*)&WL_[go];
  int off = ldsOff(r, c);
  *(ushort8*)&ldsH[off] = vh;
  *(ushort8*)&ldsL[off] = vl;
}

// ---------------- split-MFMA GEMM (LDS path, generic K): C = act(A @ W^T + bias) ----------------
__global__ __launch_bounds__(256) void gemm_mfma_k(
    const float* __restrict__ A, int lda,
    const float* __restrict__ W, int ldw,
    const float* __restrict__ bias,
    float* __restrict__ C,
    int M, int N, int K, int op)
{
  __shared__ unsigned short AsH[64*32], AsL[64*32];
  __shared__ unsigned short WsH[64*32], WsL[64*32];
  const int tid = threadIdx.x;
  const int bm = blockIdx.y * 64, bn = blockIdx.x * 64;
  const int wave = tid >> 6, lane = tid & 63;
  const int wr = wave >> 1, wc = wave & 1;
  const int quad = lane >> 4, id = lane & 15;

  f32x4 acc[2][2] = {};
  const int iters = (K + 31) / 32;
  for (int kt = 0; kt < iters; ++kt){
    int k0 = kt * 32;
    stage2(A, lda, bm, M, k0, K, AsH, AsL, tid);
    stage2(W, ldw, bn, N, k0, K, WsH, WsL, tid);
    __syncthreads();
    short8 aH[2], aL[2], bH[2], bL[2];
    #pragma unroll
    for (int i = 0; i < 2; ++i){
      int row = wr*32 + i*16 + id;
      int off = ldsOff(row, quad);
      aH[i] = *(const short8*)&AsH[off];
      aL[i] = *(const short8*)&AsL[off];
    }
    #pragma unroll
    for (int j = 0; j < 2; ++j){
      int row = wc*32 + j*16 + id;
      int off = ldsOff(row, quad);
      bH[j] = *(const short8*)&WsH[off];
      bL[j] = *(const short8*)&WsL[off];
    }
    #pragma unroll
    for (int i = 0; i < 2; ++i)
      #pragma unroll
      for (int j = 0; j < 2; ++j)
        acc[i][j] = mfma3(aH[i], aL[i], bH[j], bL[j], acc[i][j]);
    __syncthreads();
  }
  #pragma unroll
  for (int i = 0; i < 2; ++i){
    int gr0 = bm + wr*32 + i*16 + quad*4;
    #pragma unroll
    for (int j = 0; j < 2; ++j){
      int gc = bn + wc*32 + j*16 + id;
      if (gc >= N) continue;
      float bv = bias ? bias[gc] : 0.f;
      #pragma unroll
      for (int r = 0; r < 4; ++r){
        int row = gr0 + r;
        if (row < M)
          C[(size_t)row*N + gc] = applyOp(acc[i][j][r] + bv, op);
      }
    }
  }
}

// ---------------- LDS-staged GEMM with pre-split W: C[M,256] = A[M,256] @ Wpre^T ----------------
__global__ __launch_bounds__(256) void gemm_pre2_k(const float* __restrict__ A,
    const unsigned short* __restrict__ WH_, const unsigned short* __restrict__ WL_,
    float* __restrict__ C, int M)
{
  __shared__ unsigned short AsH[64*32], AsL[64*32];
  __shared__ unsigned short WsH[64*32], WsL[64*32];
  // XCD-bijective swizzle
  int nwg = gridDim.x, bid = blockIdx.x;
  int q = nwg >> 3, r = nwg & 7;
  int xcd = bid & 7, jj = bid >> 3;
  int idx = (xcd < r ? xcd*(q+1) : r*(q+1) + (xcd - r)*q) + jj;
  const int bm = (idx >> 2)*64, bn = (idx & 3)*64;
  const int tid = threadIdx.x;
  const int wave = tid >> 6, lane = tid & 63;
  const int wr = wave >> 1, wc = wave & 1;
  const int quad = lane >> 4, id = lane & 15;

  f32x4 acc[2][2] = {};
  for (int kt = 0; kt < 8; ++kt){
    int k0 = kt * 32;
    stage2(A, 256, bm, M, k0, 256, AsH, AsL, tid);
    stageW(WH_, WL_, bn, k0, WsH, WsL, tid);
    __syncthreads();
    short8 aH[2], aL[2], bH[2], bL[2];
    #pragma unroll
    for (int i = 0; i < 2; ++i){
      int row = wr*32 + i*16 + id;
      int off = ldsOff(row, quad);
      aH[i] = *(const short8*)&AsH[off];
      aL[i] = *(const short8*)&AsL[off];
    }
    #pragma unroll
    for (int j = 0; j < 2; ++j){
      int row = wc*32 + j*16 + id;
      int off = ldsOff(row, quad);
      bH[j] = *(const short8*)&WsH[off];
      bL[j] = *(const short8*)&WsL[off];
    }
    #pragma unroll
    for (int i = 0; i < 2; ++i)
      #pragma unroll
      for (int j = 0; j < 2; ++j)
        acc[i][j] = mfma3(aH[i], aL[i], bH[j], bL[j], acc[i][j]);
    __syncthreads();
  }
  #pragma unroll
  for (int i = 0; i < 2; ++i){
    int gr0 = bm + wr*32 + i*16 + quad*4;
    #pragma unroll
    for (int j = 0; j < 2; ++j){
      int gc = bn + wc*32 + j*16 + id;
      #pragma unroll
      for (int rr = 0; rr < 4; ++rr){
        int row = gr0 + rr;
        if (row < M) C[(size_t)row*256 + gc] = acc[i][j][rr];
      }
    }
  }
}

// ---------------- GRU phase: acc{R,Z,N} += [A @ W{r,z,n}^T] over K=256 ----------------
__device__ __forceinline__ void gru_phase_lds(const float* __restrict__ A,
    const unsigned short* __restrict__ WH_, const unsigned short* __restrict__ WL_,
    int M, int bm, int bn, int tid, int wr, int wc, int quad, int id,
    unsigned short* AsH, unsigned short* AsL,
    unsigned short* W0H, unsigned short* W0L,
    unsigned short* W1H, unsigned short* W1L,
    unsigned short* W2H, unsigned short* W2L,
    f32x4 (&accR)[2][2], f32x4 (&accZ)[2][2], f32x4 (&accN)[2][2])
{
  for (int kt = 0; kt < 8; ++kt){
    int k0 = kt * 32;
    stage2(A, 256, bm, M, k0, 256, AsH, AsL, tid);
    stageW(WH_,          WL_,          bn, k0, W0H, W0L, tid);
    stageW(WH_ + 65536,  WL_ + 65536,  bn, k0, W1H, W1L, tid);
    stageW(WH_ + 131072, WL_ + 131072, bn, k0, W2H, W2L, tid);
    __syncthreads();
    short8 aH[2], aL[2];
    #pragma unroll
    for (int i = 0; i < 2; ++i){
      int row = wr*32 + i*16 + id;
      int off = ldsOff(row, quad);
      aH[i] = *(const short8*)&AsH[off];
      aL[i] = *(const short8*)&AsL[off];
    }
    #pragma unroll
    for (int j = 0; j < 2; ++j){
      int row = wc*32 + j*16 + id;
      int off = ldsOff(row, quad);
      short8 bh, bl;
      bh = *(const short8*)&W0H[off]; bl = *(const short8*)&W0L[off];
      #pragma unroll
      for (int i = 0; i < 2; ++i) accR[i][j] = mfma3(aH[i], aL[i], bh, bl, accR[i][j]);
      bh = *(const short8*)&W1H[off]; bl = *(const short8*)&W1L[off];
      #pragma unroll
      for (int i = 0; i < 2; ++i) accZ[i][j] = mfma3(aH[i], aL[i], bh, bl, accZ[i][j]);
      bh = *(const short8*)&W2H[off]; bl = *(const short8*)&W2L[off];
      #pragma unroll
      for (int i = 0; i < 2; ++i) accN[i][j] = mfma3(aH[i], aL[i], bh, bl, accN[i][j]);
    }
    __syncthreads();
  }
}

// ---------------- LDS-staged fused GRU with pre-split weights: Out = relu(gru(Xin,Hid)) ----------------
__global__ __launch_bounds__(256) void gru_pre_k(
    const float* __restrict__ Xin, const float* __restrict__ Hid,
    const unsigned short* __restrict__ wihH, const unsigned short* __restrict__ wihL,
    const unsigned short* __restrict__ whhH, const unsigned short* __restrict__ whhL,
    const float* __restrict__ bih, const float* __restrict__ bhh,
    float* __restrict__ Out, int M)
{
  __shared__ unsigned short AsH[64*32], AsL[64*32];
  __shared__ unsigned short W0H[64*32], W0L[64*32];
  __shared__ unsigned short W1H[64*32], W1L[64*32];
  __shared__ unsigned short W2H[64*32], W2L[64*32];
  int nwg = gridDim.x, bid = blockIdx.x;
  int q = nwg >> 3, r = nwg & 7;
  int xcd = bid & 7, jj = bid >> 3;
  int idx = (xcd < r ? xcd*(q+1) : r*(q+1) + (xcd - r)*q) + jj;
  const int bm = (idx >> 2)*64, bn = (idx & 3)*64;
  const int tid = threadIdx.x;
  const int wave = tid >> 6, lane = tid & 63;
  const int wr = wave >> 1, wc = wave & 1;
  const int quad = lane >> 4, id = lane & 15;

  f32x4 accR[2][2] = {}, accZ[2][2] = {}, accI[2][2] = {}, accH[2][2] = {};

  gru_phase_lds(Xin, wihH, wihL, M, bm, bn, tid, wr, wc, quad, id,
                AsH, AsL, W0H, W0L, W1H, W1L, W2H, W2L, accR, accZ, accI);
  gru_phase_lds(Hid, whhH, whhL, M, bm, bn, tid, wr, wc, quad, id,
                AsH, AsL, W0H, W0L, W1H, W1L, W2H, W2L, accR, accZ, accH);

  #pragma unroll
  for (int i = 0; i < 2; ++i){
    int gr0 = bm + wr*32 + i*16 + quad*4;
    #pragma unroll
    for (int j = 0; j < 2; ++j){
      int gc = bn + wc*32 + j*16 + id;
      float br_  = bih[gc]     + bhh[gc];
      float bz_  = bih[256+gc] + bhh[256+gc];
      float bn_i = bih[512+gc], bn_h = bhh[512+gc];
      #pragma unroll
      for (int rr = 0; rr < 4; ++rr){
        int row = gr0 + rr;
        if (row >= M) continue;
        float rg = sigf(accR[i][j][rr] + br_);
        float zg = sigf(accZ[i][j][rr] + bz_);
        float ng = tanhf(accI[i][j][rr] + bn_i + rg*(accH[i][j][rr] + bn_h));
        float hv = Hid[(size_t)row*256 + gc];
        float o = (1.f - zg)*ng + zg*hv;
        Out[(size_t)row*256 + gc] = o > 0.f ? o : 0.f;
      }
    }
  }
}

// ---------------- row dots: y1[m]=dot(X[m,:256],w1), y2 optional ----------------
__global__ __launch_bounds__(256) void rowdot2_k(const float* __restrict__ X,
    const float* __restrict__ w1, const float* __restrict__ w2,
    float* __restrict__ y1, float* __restrict__ y2, int M)
{
  int m = blockIdx.x*4 + (threadIdx.x >> 6);
  if (m >= M) return;
  int lane = threadIdx.x & 63;
  float p1 = 0.f, p2 = 0.f;
  for (int c = lane; c < 256; c += 64){
    float xv = X[(size_t)m*256 + c];
    p1 += xv * w1[c];
    if (w2) p2 += xv * w2[c];
  }
  for (int o = 32; o > 0; o >>= 1){
    p1 += __shfl_down(p1, o);
    if (w2) p2 += __shfl_down(p2, o);
  }
  if (lane == 0){ y1[m] = p1; if (w2) y2[m] = p2; }
}

// ================= CSR build (dst-sorted incoming-edge lists) =================
__global__ void hist_k(const int* __restrict__ dst, unsigned* __restrict__ deg, int E){
  int e = blockIdx.x*256 + threadIdx.x;
  if (e >= E) return;
  atomicAdd(&deg[dst[e]], 1u);
}

__global__ __launch_bounds__(256) void scan1_k(const unsigned* __restrict__ deg,
    unsigned* __restrict__ incl, unsigned* __restrict__ bsum, int N)
{
  __shared__ unsigned sm[256];
  int t = threadIdx.x;
  int i = blockIdx.x*256 + t;
  unsigned v = (i < N) ? deg[i] : 0u;
  sm[t] = v; __syncthreads();
  for (int s = 1; s < 256; s <<= 1){
    unsigned u = (t >= s) ? sm[t - s] : 0u;
    __syncthreads();
    sm[t] += u;
    __syncthreads();
  }
  if (i < N) incl[i] = sm[t];
  if (t == 255) bsum[blockIdx.x] = sm[255];
}

__global__ __launch_bounds__(256) void scan2_k(unsigned* __restrict__ bsum, int nb){
  __shared__ unsigned sm[256];
  __shared__ unsigned carry;
  int t = threadIdx.x;
  if (t == 0) carry = 0u;
  __syncthreads();
  for (int base = 0; base < nb; base += 256){
    int i = base + t;
    unsigned v = (i < nb) ? bsum[i] : 0u;
    sm[t] = v; __syncthreads();
    for (int s = 1; s < 256; s <<= 1){
      unsigned u = (t >= s) ? sm[t - s] : 0u;
      __syncthreads();
      sm[t] += u;
      __syncthreads();
    }
    unsigned total = sm[255];
    unsigned c = carry;
    if (i < nb) bsum[i] = c + sm[t] - v;
    __syncthreads();
    if (t == 0) carry = c + total;
    __syncthreads();
  }
}

__global__ void scan3_k(const unsigned* __restrict__ incl, const unsigned* __restrict__ deg,
    const unsigned* __restrict__ bsum, unsigned* __restrict__ off, int N, int E)
{
  int i = blockIdx.x*256 + threadIdx.x;
  if (i < N) off[i] = incl[i] - deg[i] + bsum[blockIdx.x];
  if (i == 0) off[N] = (unsigned)E;
}

__global__ void fill_k(const int* __restrict__ src, const int* __restrict__ dst,
    const unsigned* __restrict__ off, unsigned* __restrict__ cur,
    int* __restrict__ csr_src, int* __restrict__ csr_eid, int E)
{
  int e = blockIdx.x*256 + threadIdx.x;
  if (e >= E) return;
  int d = dst[e];
  unsigned p = off[d] + atomicAdd(&cur[d], 1u);
  csr_src[p] = src[e];
  csr_eid[p] = e;
}

// ---------------- GATEConv edge score, written in CSR order ----------------
__global__ __launch_bounds__(256) void gate_edge_score_csr_k(
    const float* __restrict__ Y, const float* __restrict__ g_lin1W,
    const float* __restrict__ att_l, const float* __restrict__ ea_in,
    const float* __restrict__ xr, const int* __restrict__ csr_src,
    const int* __restrict__ csr_eid, const int* __restrict__ dst,
    float* __restrict__ a_out, int E, int H)
{
  int p = blockIdx.x*4 + (threadIdx.x >> 6);
  if (p >= E) return;
  int lane = threadIdx.x & 63;
  int s = csr_src[p];
  int e = csr_eid[p];
  int d = dst[e];
  float eav = ea_in[e];
  float acc = 0.f;
  for (int c = lane; c < 256; c += 64){
    float yv = Y[(size_t)s*256 + c] + eav * g_lin1W[(size_t)c*(H+1) + H];
    acc += lreluf(yv) * att_l[c];
  }
  for (int o = 32; o > 0; o >>= 1) acc += __shfl_down(acc, o);
  if (lane == 0) a_out[p] = lreluf(acc + xr[d]);
}

// ---------------- per-node segment softmax over CSR (no atomics) ----------------
__global__ void node_softmax_k(const unsigned* __restrict__ off, const int* __restrict__ csr_src,
    const float* __restrict__ nd1, const float* __restrict__ nd2,
    float* __restrict__ w, int N, int mode)
{
  int n = blockIdx.x*256 + threadIdx.x;
  if (n >= N) return;
  unsigned p0 = off[n], p1 = off[n+1];
  float m = -INFINITY;
  if (mode){
    float d = nd2[n];
    for (unsigned p = p0; p < p1; ++p){
      float a = lreluf(nd1[csr_src[p]] + d);
      w[p] = a;
      m = fmaxf(m, a);
    }
  } else {
    for (unsigned p = p0; p < p1; ++p) m = fmaxf(m, w[p]);
  }
  float ssum = 0.f;
  for (unsigned p = p0; p < p1; ++p){
    float e = expf(w[p] - m);
    w[p] = e; ssum += e;
  }
  float inv = (ssum > 0.f) ? 1.f/ssum : 0.f;
  for (unsigned p = p0; p < p1; ++p) w[p] *= inv;
}

// ---------------- gather: h[n] = elu( sum_e w[e]*Z[src[e]] + bias ) ----------------
__global__ __launch_bounds__(256) void gather_h_k(const float* __restrict__ Z,
    const float* __restrict__ w, const unsigned* __restrict__ off,
    const int* __restrict__ csr_src, const float* __restrict__ bias,
    float* __restrict__ h, int N)
{
  int n = blockIdx.x*4 + (threadIdx.x >> 6);
  if (n >= N) return;
  int lane = threadIdx.x & 63;
  unsigned p0 = off[n], p1 = off[n+1];
  float4 acc = make_float4(0.f, 0.f, 0.f, 0.f);
  for (unsigned p = p0; p < p1; ++p){
    float wv = w[p];
    const float4 z = *(const float4*)&Z[(size_t)csr_src[p]*256 + lane*4];
    acc.x = fmaf(wv, z.x, acc.x);
    acc.y = fmaf(wv, z.y, acc.y);
    acc.z = fmaf(wv, z.z, acc.z);
    acc.w = fmaf(wv, z.w, acc.w);
  }
  const float4 b = *(const float4*)&bias[lane*4];
  float4 o;
  float v;
  v = acc.x + b.x; o.x = v > 0.f ? v : expf(v) - 1.f;
  v = acc.y + b.y; o.y = v > 0.f ? v : expf(v) - 1.f;
  v = acc.z + b.z; o.z = v > 0.f ? v : expf(v) - 1.f;
  v = acc.w + b.w; o.w = v > 0.f ? v : expf(v) - 1.f;
  *(float4*)&h[(size_t)n*256 + lane*4] = o;
}

// ---------------- pooling ----------------
__global__ void seg_bounds_k(const int* __restrict__ batch, unsigned* __restrict__ gs,
                             unsigned* __restrict__ ge, int N){
  int n = blockIdx.x*256 + threadIdx.x;
  if (n >= N) return;
  int g = batch[n];
  atomicMin(&gs[g], (unsigned)n);
  atomicMax(&ge[g], (unsigned)(n+1));
}
__global__ __launch_bounds__(256) void graph_pool_k(const float* __restrict__ x,
    const unsigned* __restrict__ gs, const unsigned* __restrict__ ge,
    float* __restrict__ outg)
{
  int g = blockIdx.x, t = threadIdx.x;
  unsigned s0 = gs[g], e0 = ge[g];
  float acc = 0.f;
  for (unsigned n = s0; n < e0; ++n) acc += x[(size_t)n*256 + t];
  outg[(size_t)g*256 + t] = acc > 0.f ? acc : 0.f;
}
__global__ void precompute_v_k(const float* __restrict__ W, const float* __restrict__ ad,
                               float* __restrict__ v){
  int i = threadIdx.x;
  float acc = 0.f;
  for (int j = 0; j < 256; ++j) acc += W[(size_t)j*256 + i] * ad[j];
  v[i] = acc;
}
// fused mol attention timestep
__global__ __launch_bounds__(256) void mol_pool_k(const float* __restrict__ outg,
    const float* __restrict__ v, const float* __restrict__ asrc,
    const float* __restrict__ xw, const unsigned* __restrict__ gs,
    const unsigned* __restrict__ geb, const float* __restrict__ bias,
    float* __restrict__ hg)
{
  __shared__ float red[256];
  int g = blockIdx.x, t = threadIdx.x;
  float tg = blkSum(outg[(size_t)g*256 + t] * v[t], red);
  unsigned s0 = gs[g], e0 = geb[g];
  float mx = -INFINITY;
  for (unsigned n = s0 + t; n < e0; n += 256) mx = fmaxf(mx, lreluf(asrc[n] + tg));
  mx = blkMax(mx, red);
  float sm = 0.f;
  for (unsigned n = s0 + t; n < e0; n += 256) sm += expf(lreluf(asrc[n] + tg) - mx);
  sm = blkSum(sm, red);
  float acc = 0.f;
  if (e0 > s0 && sm > 0.f){
    float inv = 1.f / sm;
    for (unsigned n = s0; n < e0; ++n){
      float w = expf(lreluf(asrc[n] + tg) - mx) * inv;
      acc = fmaf(w, xw[(size_t)n*256 + t], acc);
    }
  }
  float h = acc + bias[t];
  hg[(size_t)g*256 + t] = h > 0.f ? h : expf(h) - 1.f;
}

// ---------------- launcher ----------------
extern "C" void kernel_launch(void* const* d_in, const int* in_sizes, int n_in,
                              void* d_out, int out_size, void* d_ws, size_t ws_size,
                              hipStream_t stream)
{
  (void)n_in; (void)ws_size;
  const int H    = in_sizes[3];          // 256
  const int NIN  = in_sizes[2] / H;      // 300
  const int N    = in_sizes[0] / NIN;    // 100000
  const int E    = in_sizes[1];          // 400000
  const int NL   = in_sizes[16] / H;     // 3
  const int NHID = in_sizes[30];         // 512
  const int NOUT = in_sizes[32];         // 768
  const int G    = out_size / NOUT;      // 2048
  const int T    = 16;

  const float* x_in     = (const float*)d_in[0];
  const float* ea_in    = (const float*)d_in[1];
  const float* lin1_W   = (const float*)d_in[2];
  const float* lin1_b   = (const float*)d_in[3];
  const float* g_lin1W  = (const float*)d_in[4];
  const float* g_lin2W  = (const float*)d_in[5];
  const float* g_att_l  = (const float*)d_in[6];
  const float* g_att_r  = (const float*)d_in[7];
  const float* g_bias   = (const float*)d_in[8];
  const float* gru0_wih = (const float*)d_in[9];
  const float* gru0_whh = (const float*)d_in[10];
  const float* gru0_bih = (const float*)d_in[11];
  const float* gru0_bhh = (const float*)d_in[12];
  const float* atom_W   = (const float*)d_in[13];
  const float* atom_as  = (const float*)d_in[14];
  const float* atom_ad  = (const float*)d_in[15];
  const float* atom_b   = (const float*)d_in[16];
  const float* agru_wih = (const float*)d_in[17];
  const float* agru_whh = (const float*)d_in[18];
  const float* agru_bih = (const float*)d_in[19];
  const float* agru_bhh = (const float*)d_in[20];
  const float* mol_W    = (const float*)d_in[21];
  const float* mol_as   = (const float*)d_in[22];
  const float* mol_ad   = (const float*)d_in[23];
  const float* mol_b    = (const float*)d_in[24];
  const float* mgru_wih = (const float*)d_in[25];
  const float* mgru_whh = (const float*)d_in[26];
  const float* mgru_bih = (const float*)d_in[27];
  const float* mgru_bhh = (const float*)d_in[28];
  const float* lin2_W   = (const float*)d_in[29];
  const float* lin2_b   = (const float*)d_in[30];
  const float* fc1_W    = (const float*)d_in[31];
  const float* fc1_b    = (const float*)d_in[32];
  const int*  eidx      = (const int*)d_in[33];
  const int*  batch     = (const int*)d_in[34];
  const int*  srcI = eidx;
  const int*  dstI = eidx + E;

  char* wp = (char*)d_ws;
  auto alloc = [&](size_t bytes)->void*{
    void* p = (void*)wp;
    wp += (bytes + 255) & ~(size_t)255;
    return p;
  };
  float*    x     = (float*)alloc((size_t)N*H*4);
  float*    hb    = (float*)alloc((size_t)N*H*4);
  float*    tA    = (float*)alloc((size_t)N*H*4);
  float*    tB    = (float*)alloc((size_t)N*H*4);
  float*    ea    = (float*)alloc((size_t)E*4);       // CSR-ordered scores/weights
  float*    nd1   = (float*)alloc((size_t)N*4);
  float*    nd2   = (float*)alloc((size_t)N*4);
  float*    outg  = (float*)alloc((size_t)G*H*4);
  float*    outg2 = (float*)alloc((size_t)G*H*4);
  float*    hg    = (float*)alloc((size_t)G*H*4);
  unsigned* gsb   = (unsigned*)alloc((size_t)G*4);
  unsigned* geb   = (unsigned*)alloc((size_t)G*4);
  float*    vvec  = (float*)alloc((size_t)H*4);
  float*    o2    = (float*)alloc((size_t)G*NHID*4);
  // CSR structures
  const int nb = (N + 255) / 256;
  unsigned* deg     = (unsigned*)alloc((size_t)N*4);
  unsigned* cur     = (unsigned*)alloc((size_t)N*4);
  unsigned* incl    = (unsigned*)alloc((size_t)N*4);
  unsigned* off     = (unsigned*)alloc((size_t)(N+1)*4);
  unsigned* bsum    = (unsigned*)alloc((size_t)nb*4);
  int*      csr_src = (int*)alloc((size_t)E*4);
  int*      csr_eid = (int*)alloc((size_t)E*4);
  // pre-split weight buffers (ushort hi/lo)
  auto allocUS = [&](size_t elems)->unsigned short*{ return (unsigned short*)alloc(elems*2); };
  const size_t WG = (size_t)768*256;   // one GRU weight matrix
  const size_t WS = (size_t)256*256;   // one square GAT weight
  unsigned short *g0ihH = allocUS(WG), *g0ihL = allocUS(WG);
  unsigned short *g0hhH = allocUS(WG), *g0hhL = allocUS(WG);
  unsigned short *aihH  = allocUS(WG*NL), *aihL = allocUS(WG*NL);
  unsigned short *ahhH  = allocUS(WG*NL), *ahhL = allocUS(WG*NL);
  unsigned short *mihH  = allocUS(WG), *mihL = allocUS(WG);
  unsigned short *mhhH  = allocUS(WG), *mhhL = allocUS(WG);
  unsigned short *gl1H  = allocUS(WS), *gl1L = allocUS(WS);
  unsigned short *gl2H  = allocUS(WS), *gl2L = allocUS(WS);
  unsigned short *atWH  = allocUS(WS*NL), *atWL = allocUS(WS*NL);
  unsigned short *molH  = allocUS(WS), *molL = allocUS(WS);

  auto gemm = [&](const float* Ain, int lda, const float* W, int ldw, const float* bias,
                  float* Cout, int M_, int N_, int K_, int op){
    dim3 gr((N_ + 63)/64, (M_ + 63)/64);
    gemm_mfma_k<<<gr, dim3(256), 0, stream>>>(Ain, lda, W, ldw, bias, Cout, M_, N_, K_, op);
  };
  auto gemmp = [&](const float* Ain, const unsigned short* WH_, const unsigned short* WL_,
                   float* Cout, int M_){
    int nwg = ((M_ + 63)/64)*4;
    gemm_pre2_k<<<dim3(nwg), dim3(256), 0, stream>>>(Ain, WH_, WL_, Cout, M_);
  };
  auto grup = [&](const float* xin, const float* hid,
                  const unsigned short* ihH, const unsigned short* ihL,
                  const unsigned short* hhH, const unsigned short* hhL,
                  const float* bih, const float* bhh, float* out, int M_){
    int nwg = ((M_ + 63)/64)*4;
    gru_pre_k<<<dim3(nwg), dim3(256), 0, stream>>>(xin, hid, ihH, ihL, hhH, hhL, bih, bhh, out, M_);
  };
  auto wsplit = [&](const float* src, unsigned short* Hd, unsigned short* Ld,
                    int lda, int K, long long rows){
    long long tot = rows * K;
    wsplit_k<<<dim3((unsigned)((tot + 255)/256)), dim3(256), 0, stream>>>(src, Hd, Ld, lda, K, tot);
  };

  // ---- pre-split all MFMA weights (cheap; removes per-block re-conversion)
  wsplit(gru0_wih, g0ihH, g0ihL, 256, 256, 768);
  wsplit(gru0_whh, g0hhH, g0hhL, 256, 256, 768);
  wsplit(agru_wih, aihH, aihL, 256, 256, (long long)NL*768);
  wsplit(agru_whh, ahhH, ahhL, 256, 256, (long long)NL*768);
  wsplit(mgru_wih, mihH, mihL, 256, 256, 768);
  wsplit(mgru_whh, mhhH, mhhL, 256, 256, 768);
  wsplit(g_lin1W,  gl1H, gl1L, H+1, 256, 256);
  wsplit(g_lin2W,  gl2H, gl2L, 256, 256, 256);
  wsplit(atom_W,   atWH, atWL, 256, 256, (long long)NL*256);
  wsplit(mol_W,    molH, molL, 256, 256, 256);

  // ---- build CSR of incoming edges (reused by all 4 attention layers)
  hipMemsetAsync(deg, 0, (size_t)N*4, stream);
  hist_k<<<dim3((E+255)/256), dim3(256), 0, stream>>>(dstI, deg, E);
  scan1_k<<<dim3(nb), dim3(256), 0, stream>>>(deg, incl, bsum, N);
  scan2_k<<<dim3(1), dim3(256), 0, stream>>>(bsum, nb);
  scan3_k<<<dim3(nb), dim3(256), 0, stream>>>(incl, deg, bsum, off, N, E);
  hipMemsetAsync(cur, 0, (size_t)N*4, stream);
  fill_k<<<dim3((E+255)/256), dim3(256), 0, stream>>>(srcI, dstI, off, cur, csr_src, csr_eid, E);

  // ---- input projection (K=300, zero-padded in staging; LDS path)
  gemm(x_in, NIN, lin1_W, NIN, lin1_b, x, N, H, NIN, OP_LRELU);

  // ---- GATEConv
  gemmp(x, gl1H, gl1L, tA, N);                                                 // Y
  rowdot2_k<<<dim3((N+3)/4), dim3(256), 0, stream>>>(x, g_att_r, (const float*)nullptr,
                                                     nd1, (float*)nullptr, N);
  gate_edge_score_csr_k<<<dim3((E+3)/4), dim3(256), 0, stream>>>(tA, g_lin1W, g_att_l,
                                                                 ea_in, nd1, csr_src, csr_eid,
                                                                 dstI, ea, E, H);
  gemmp(x, gl2H, gl2L, tA, N);                                                 // Z
  node_softmax_k<<<dim3(nb), dim3(256), 0, stream>>>(off, csr_src, nullptr, nullptr, ea, N, 0);
  gather_h_k<<<dim3((N+3)/4), dim3(256), 0, stream>>>(tA, ea, off, csr_src, g_bias, hb, N);
  grup(hb, x, g0ihH, g0ihL, g0hhH, g0hhL, gru0_bih, gru0_bhh, tB, N);
  { float* t = x; x = tB; tB = t; }

  // ---- atom GATConv layers
  for (int l = 0; l < NL; ++l){
    gemmp(x, atWH + (size_t)l*WS, atWL + (size_t)l*WS, tA, N);                 // xw
    rowdot2_k<<<dim3((N+3)/4), dim3(256), 0, stream>>>(tA, atom_as + (size_t)l*H,
                                                       atom_ad + (size_t)l*H, nd1, nd2, N);
    node_softmax_k<<<dim3(nb), dim3(256), 0, stream>>>(off, csr_src, nd1, nd2, ea, N, 1);
    gather_h_k<<<dim3((N+3)/4), dim3(256), 0, stream>>>(tA, ea, off, csr_src,
                                                        atom_b + (size_t)l*H, hb, N);
    grup(hb, x, aihH + (size_t)l*WG, aihL + (size_t)l*WG,
         ahhH + (size_t)l*WG, ahhL + (size_t)l*WG,
         agru_bih + (size_t)l*3*H, agru_bhh + (size_t)l*3*H, tB, N);
    { float* t = x; x = tB; tB = t; }
  }

  // ---- attentive pooling
  hipMemsetAsync(gsb, 0xFF, (size_t)G*4, stream);
  hipMemsetAsync(geb, 0x00, (size_t)G*4, stream);
  seg_bounds_k<<<dim3((N+255)/256), dim3(256), 0, stream>>>(batch, gsb, geb, N);
  graph_pool_k<<<dim3(G), dim3(256), 0, stream>>>(x, gsb, geb, outg);
  gemmp(x, molH, molL, hb, N);                                                 // xw (persists)
  rowdot2_k<<<dim3((N+3)/4), dim3(256), 0, stream>>>(hb, mol_as, (const float*)nullptr,
                                                     nd1, (float*)nullptr, N);
  precompute_v_k<<<dim3(1), dim3(256), 0, stream>>>(mol_W, mol_ad, vvec);
  float* og  = outg;
  float* og2 = outg2;
  for (int t = 0; t < T; ++t){
    mol_pool_k<<<dim3(G), dim3(256), 0, stream>>>(og, vvec, nd1, hb, gsb, geb, mol_b, hg);
    grup(hg, og, mihH, mihL, mhhH, mhhL, mgru_bih, mgru_bhh, og2, G);
    { float* tt = og; og = og2; og2 = tt; }
  }

  // ---- head
  gemm(og, H, lin2_W, H, lin2_b, o2, G, NHID, H, OP_RELU);
  gemm(o2, NHID, fc1_W, NHID, fc1_b, (float*)d_out, G, NOUT, NHID, OP_NONE);
}

// Round 5
// 3996.242 us; speedup vs baseline: 1.5963x; 1.0045x over previous
//
#include <hip/hip_runtime.h>
#include <hip/hip_bf16.h>
#include <math.h>

typedef __attribute__((ext_vector_type(8))) short           short8;   // 8 bf16 (4 VGPRs)
typedef __attribute__((ext_vector_type(8))) unsigned short  ushort8;
typedef __attribute__((ext_vector_type(4))) unsigned short  us4;
typedef __attribute__((ext_vector_type(4))) float           f32x4;

__device__ __forceinline__ float lreluf(float v){ return v >= 0.f ? v : 0.01f*v; }
__device__ __forceinline__ float sigf(float v){ return 1.f/(1.f + expf(-v)); }

#define OP_NONE  0
#define OP_LRELU 1
#define OP_RELU  2

__device__ __forceinline__ float applyOp(float v, int op){
  if (op == OP_LRELU) return v >= 0.f ? v : 0.01f*v;
  if (op == OP_RELU)  return v > 0.f ? v : 0.f;
  return v;
}

// f32 -> bf16 RNE, raw ushort
__device__ __forceinline__ unsigned short f2b(float f){
  unsigned x = __float_as_uint(f);
  unsigned lsb = (x >> 16) & 1u;
  return (unsigned short)((x + 0x7fffu + lsb) >> 16);
}
__device__ __forceinline__ float b2f(unsigned short h){
  return __uint_as_float((unsigned)h << 16);
}
__device__ __forceinline__ void split2(float v, unsigned short& h, unsigned short& l){
  h = f2b(v);
  l = f2b(v - b2f(h));
}
__device__ __forceinline__ float rec2(unsigned short h, unsigned short l){
  return b2f(h) + b2f(l);
}

// LDS tile [rows][32] ushort, 16B-chunk XOR swizzle (R3-verified: conflicts = 0)
__device__ __forceinline__ int ldsOff(int row, int chunk){
  return row*32 + ((chunk ^ ((row >> 1) & 3)) << 3);
}

__device__ __forceinline__ float blkSum(float v, float* red){
  int t = threadIdx.x;
  red[t] = v; __syncthreads();
  for (int s = 128; s > 0; s >>= 1){ if (t < s) red[t] += red[t+s]; __syncthreads(); }
  float r = red[0]; __syncthreads();
  return r;
}
__device__ __forceinline__ float blkMax(float v, float* red){
  int t = threadIdx.x;
  red[t] = v; __syncthreads();
  for (int s = 128; s > 0; s >>= 1){ if (t < s) red[t] = fmaxf(red[t], red[t+s]); __syncthreads(); }
  float r = red[0]; __syncthreads();
  return r;
}

// 3-product split-precision accumulate: acc += (aH+aL)*(bH+bL) (drop lo*lo)
__device__ __forceinline__ f32x4 mfma3(short8 aH, short8 aL, short8 bH, short8 bL, f32x4 acc){
  acc = __builtin_amdgcn_mfma_f32_16x16x32_bf16(aL, bH, acc, 0, 0, 0);
  acc = __builtin_amdgcn_mfma_f32_16x16x32_bf16(aH, bL, acc, 0, 0, 0);
  acc = __builtin_amdgcn_mfma_f32_16x16x32_bf16(aH, bH, acc, 0, 0, 0);
  return acc;
}

// ================= weight pre-split: f32 [rows][lda] -> H/L ushort [rows][K] =================
__global__ void wsplit_k(const float* __restrict__ src, unsigned short* __restrict__ Hd,
                         unsigned short* __restrict__ Ld, int lda, int K, long long tot)
{
  long long i = (long long)blockIdx.x*256 + threadIdx.x;
  if (i >= tot) return;
  long long r = i / K; int c = (int)(i % K);
  float v = src[r*lda + c];
  unsigned short h = f2b(v);
  Hd[r*(long long)K + c] = h;
  Ld[r*(long long)K + c] = f2b(v - b2f(h));
}

// ---- stage 64x32 pre-split tile pair -> swizzled LDS (pure copy). 256 threads ----
__device__ __forceinline__ void stagePS(const unsigned short* __restrict__ GH,
    const unsigned short* __restrict__ GL, int ldk, int row0, int k0,
    unsigned short* __restrict__ ldsH, unsigned short* __restrict__ ldsL, int tid)
{
  int r = tid >> 2, c = tid & 3;
  size_t go = (size_t)(row0 + r)*ldk + k0 + c*8;
  ushort8 vh = *(const ushort8*)&GH[go];
  ushort8 vl = *(const ushort8*)&GL[go];
  int off = ldsOff(r, c);
  *(ushort8*)&ldsH[off] = vh;
  *(ushort8*)&ldsL[off] = vl;
}

// ---- stage 64x32 f32 tile -> split bf16 hi/lo LDS (swizzled). generic K (lin1 only) ----
__device__ __forceinline__ void stage2(const float* __restrict__ src, int lda,
    int row0, int rowmax, int k0, int K,
    unsigned short* __restrict__ ldsH, unsigned short* __restrict__ ldsL, int tid)
{
  int r = tid >> 2, c = tid & 3;
  int gr = row0 + r, gk = k0 + c*8;
  const float* p = src + (size_t)gr*lda + gk;
  float f[8];
  if (gr < rowmax && gk + 8 <= K && ((lda & 3) == 0)){
    float4 f0 = *(const float4*)p;
    float4 f1 = *(const float4*)(p+4);
    f[0]=f0.x; f[1]=f0.y; f[2]=f0.z; f[3]=f0.w;
    f[4]=f1.x; f[5]=f1.y; f[6]=f1.z; f[7]=f1.w;
  } else {
    #pragma unroll
    for (int j = 0; j < 8; ++j) f[j] = (gr < rowmax && gk + j < K) ? p[j] : 0.f;
  }
  ushort8 vh, vl;
  #pragma unroll
  for (int j = 0; j < 8; ++j){
    unsigned short h, l; split2(f[j], h, l);
    vh[j] = h; vl[j] = l;
  }
  int off = ldsOff(r, c);
  *(ushort8*)&ldsH[off] = vh;
  *(ushort8*)&ldsL[off] = vl;
}

// ---------------- generic-K GEMM (f32 inputs; lin1 only): split out ----------------
__global__ __launch_bounds__(256) void gemm_mfma_k(
    const float* __restrict__ A, int lda,
    const float* __restrict__ W, int ldw,
    const float* __restrict__ bias,
    unsigned short* __restrict__ CH, unsigned short* __restrict__ CL,
    int M, int N, int K, int op)
{
  __shared__ unsigned short AsH[64*32], AsL[64*32];
  __shared__ unsigned short WsH[64*32], WsL[64*32];
  const int tid = threadIdx.x;
  const int bm = blockIdx.y * 64, bn = blockIdx.x * 64;
  const int wave = tid >> 6, lane = tid & 63;
  const int wr = wave >> 1, wc = wave & 1;
  const int quad = lane >> 4, id = lane & 15;

  f32x4 acc[2][2] = {};
  const int iters = (K + 31) / 32;
  for (int kt = 0; kt < iters; ++kt){
    int k0 = kt * 32;
    stage2(A, lda, bm, M, k0, K, AsH, AsL, tid);
    stage2(W, ldw, bn, N, k0, K, WsH, WsL, tid);
    __syncthreads();
    short8 aH[2], aL[2], bH[2], bL[2];
    #pragma unroll
    for (int i = 0; i < 2; ++i){
      int off = ldsOff(wr*32 + i*16 + id, quad);
      aH[i] = *(const short8*)&AsH[off];
      aL[i] = *(const short8*)&AsL[off];
    }
    #pragma unroll
    for (int j = 0; j < 2; ++j){
      int off = ldsOff(wc*32 + j*16 + id, quad);
      bH[j] = *(const short8*)&WsH[off];
      bL[j] = *(const short8*)&WsL[off];
    }
    #pragma unroll
    for (int i = 0; i < 2; ++i)
      #pragma unroll
      for (int j = 0; j < 2; ++j)
        acc[i][j] = mfma3(aH[i], aL[i], bH[j], bL[j], acc[i][j]);
    __syncthreads();
  }
  #pragma unroll
  for (int i = 0; i < 2; ++i){
    int gr0 = bm + wr*32 + i*16 + quad*4;
    #pragma unroll
    for (int j = 0; j < 2; ++j){
      int gc = bn + wc*32 + j*16 + id;
      if (gc >= N) continue;
      float bv = bias ? bias[gc] : 0.f;
      #pragma unroll
      for (int r = 0; r < 4; ++r){
        int row = gr0 + r;
        if (row >= M) continue;
        float v = applyOp(acc[i][j][r] + bv, op);
        unsigned short h, l; split2(v, h, l);
        CH[(size_t)row*N + gc] = h;
        CL[(size_t)row*N + gc] = l;
      }
    }
  }
}

// ---------------- pre-split GEMM: C = act(A @ W^T + b); f32 and/or split out ----------------
__global__ __launch_bounds__(256) void gemm_ps_k(
    const unsigned short* __restrict__ AH, const unsigned short* __restrict__ AL,
    const unsigned short* __restrict__ WH_, const unsigned short* __restrict__ WL_,
    const float* __restrict__ bias, float* __restrict__ C,
    unsigned short* __restrict__ CH, unsigned short* __restrict__ CL,
    int M, int N, int K, int op, int ncb)
{
  __shared__ unsigned short AsH[64*32], AsL[64*32];
  __shared__ unsigned short WsH[64*32], WsL[64*32];
  int nwg = gridDim.x, bid = blockIdx.x;
  int q = nwg >> 3, r = nwg & 7;
  int xcd = bid & 7, jj = bid >> 3;
  int idx = (xcd < r ? xcd*(q+1) : r*(q+1) + (xcd - r)*q) + jj;
  const int bm = (idx / ncb)*64, bn = (idx % ncb)*64;
  const int tid = threadIdx.x;
  const int wave = tid >> 6, lane = tid & 63;
  const int wr = wave >> 1, wc = wave & 1;
  const int quad = lane >> 4, id = lane & 15;

  f32x4 acc[2][2] = {};
  const int iters = K >> 5;
  for (int kt = 0; kt < iters; ++kt){
    int k0 = kt * 32;
    stagePS(AH, AL, K, bm, k0, AsH, AsL, tid);
    stagePS(WH_, WL_, K, bn, k0, WsH, WsL, tid);
    __syncthreads();
    short8 aH[2], aL[2], bH[2], bL[2];
    #pragma unroll
    for (int i = 0; i < 2; ++i){
      int off = ldsOff(wr*32 + i*16 + id, quad);
      aH[i] = *(const short8*)&AsH[off];
      aL[i] = *(const short8*)&AsL[off];
    }
    #pragma unroll
    for (int j = 0; j < 2; ++j){
      int off = ldsOff(wc*32 + j*16 + id, quad);
      bH[j] = *(const short8*)&WsH[off];
      bL[j] = *(const short8*)&WsL[off];
    }
    #pragma unroll
    for (int i = 0; i < 2; ++i)
      #pragma unroll
      for (int j = 0; j < 2; ++j)
        acc[i][j] = mfma3(aH[i], aL[i], bH[j], bL[j], acc[i][j]);
    __syncthreads();
  }
  #pragma unroll
  for (int i = 0; i < 2; ++i){
    int gr0 = bm + wr*32 + i*16 + quad*4;
    #pragma unroll
    for (int j = 0; j < 2; ++j){
      int gc = bn + wc*32 + j*16 + id;
      float bv = bias ? bias[gc] : 0.f;
      #pragma unroll
      for (int rr = 0; rr < 4; ++rr){
        int row = gr0 + rr;
        if (row >= M) continue;
        float v = applyOp(acc[i][j][rr] + bv, op);
        if (C)  C[(size_t)row*N + gc] = v;
        if (CH){
          unsigned short h, l; split2(v, h, l);
          CH[(size_t)row*N + gc] = h;
          CL[(size_t)row*N + gc] = l;
        }
      }
    }
  }
}

// ---------------- fused dual GEMM (GATEConv): Y = A@W1^T, Z = A@W2^T (split out) ----------------
__global__ __launch_bounds__(256) void gemm2_ps_k(
    const unsigned short* __restrict__ AH, const unsigned short* __restrict__ AL,
    const unsigned short* __restrict__ W1H, const unsigned short* __restrict__ W1L,
    const unsigned short* __restrict__ W2H, const unsigned short* __restrict__ W2L,
    unsigned short* __restrict__ YH, unsigned short* __restrict__ YL,
    unsigned short* __restrict__ ZH, unsigned short* __restrict__ ZL, int M)
{
  __shared__ unsigned short AsH[64*32], AsL[64*32];
  __shared__ unsigned short U1H[64*32], U1L[64*32];
  __shared__ unsigned short U2H[64*32], U2L[64*32];
  int nwg = gridDim.x, bid = blockIdx.x;
  int q = nwg >> 3, r = nwg & 7;
  int xcd = bid & 7, jj = bid >> 3;
  int idx = (xcd < r ? xcd*(q+1) : r*(q+1) + (xcd - r)*q) + jj;
  const int bm = (idx >> 2)*64, bn = (idx & 3)*64;
  const int tid = threadIdx.x;
  const int wave = tid >> 6, lane = tid & 63;
  const int wr = wave >> 1, wc = wave & 1;
  const int quad = lane >> 4, id = lane & 15;

  f32x4 acc1[2][2] = {}, acc2[2][2] = {};
  for (int kt = 0; kt < 8; ++kt){
    int k0 = kt * 32;
    stagePS(AH, AL, 256, bm, k0, AsH, AsL, tid);
    stagePS(W1H, W1L, 256, bn, k0, U1H, U1L, tid);
    stagePS(W2H, W2L, 256, bn, k0, U2H, U2L, tid);
    __syncthreads();
    short8 aH[2], aL[2];
    #pragma unroll
    for (int i = 0; i < 2; ++i){
      int off = ldsOff(wr*32 + i*16 + id, quad);
      aH[i] = *(const short8*)&AsH[off];
      aL[i] = *(const short8*)&AsL[off];
    }
    #pragma unroll
    for (int j = 0; j < 2; ++j){
      int off = ldsOff(wc*32 + j*16 + id, quad);
      short8 bh, bl;
      bh = *(const short8*)&U1H[off]; bl = *(const short8*)&U1L[off];
      #pragma unroll
      for (int i = 0; i < 2; ++i) acc1[i][j] = mfma3(aH[i], aL[i], bh, bl, acc1[i][j]);
      bh = *(const short8*)&U2H[off]; bl = *(const short8*)&U2L[off];
      #pragma unroll
      for (int i = 0; i < 2; ++i) acc2[i][j] = mfma3(aH[i], aL[i], bh, bl, acc2[i][j]);
    }
    __syncthreads();
  }
  #pragma unroll
  for (int i = 0; i < 2; ++i){
    int gr0 = bm + wr*32 + i*16 + quad*4;
    #pragma unroll
    for (int j = 0; j < 2; ++j){
      int gc = bn + wc*32 + j*16 + id;
      #pragma unroll
      for (int rr = 0; rr < 4; ++rr){
        int row = gr0 + rr;
        if (row >= M) continue;
        unsigned short h, l;
        split2(acc1[i][j][rr], h, l);
        YH[(size_t)row*256 + gc] = h; YL[(size_t)row*256 + gc] = l;
        split2(acc2[i][j][rr], h, l);
        ZH[(size_t)row*256 + gc] = h; ZL[(size_t)row*256 + gc] = l;
      }
    }
  }
}

// ---------------- GRU phase over pre-split A and 3 gate weights ----------------
__device__ __forceinline__ void gru_phase_ps(
    const unsigned short* __restrict__ AH, const unsigned short* __restrict__ AL,
    const unsigned short* __restrict__ WH_, const unsigned short* __restrict__ WL_,
    int bm, int bn, int tid, int wr, int wc, int quad, int id,
    unsigned short* AsH, unsigned short* AsL,
    unsigned short* W0H, unsigned short* W0L,
    unsigned short* W1H, unsigned short* W1L,
    unsigned short* W2H, unsigned short* W2L,
    f32x4 (&accR)[2][2], f32x4 (&accZ)[2][2], f32x4 (&accN)[2][2])
{
  for (int kt = 0; kt < 8; ++kt){
    int k0 = kt * 32;
    stagePS(AH, AL, 256, bm, k0, AsH, AsL, tid);
    stagePS(WH_,          WL_,          256, bn, k0, W0H, W0L, tid);
    stagePS(WH_ + 65536,  WL_ + 65536,  256, bn, k0, W1H, W1L, tid);
    stagePS(WH_ + 131072, WL_ + 131072, 256, bn, k0, W2H, W2L, tid);
    __syncthreads();
    short8 aH[2], aL[2];
    #pragma unroll
    for (int i = 0; i < 2; ++i){
      int off = ldsOff(wr*32 + i*16 + id, quad);
      aH[i] = *(const short8*)&AsH[off];
      aL[i] = *(const short8*)&AsL[off];
    }
    #pragma unroll
    for (int j = 0; j < 2; ++j){
      int off = ldsOff(wc*32 + j*16 + id, quad);
      short8 bh, bl;
      bh = *(const short8*)&W0H[off]; bl = *(const short8*)&W0L[off];
      #pragma unroll
      for (int i = 0; i < 2; ++i) accR[i][j] = mfma3(aH[i], aL[i], bh, bl, accR[i][j]);
      bh = *(const short8*)&W1H[off]; bl = *(const short8*)&W1L[off];
      #pragma unroll
      for (int i = 0; i < 2; ++i) accZ[i][j] = mfma3(aH[i], aL[i], bh, bl, accZ[i][j]);
      bh = *(const short8*)&W2H[off]; bl = *(const short8*)&W2L[off];
      #pragma unroll
      for (int i = 0; i < 2; ++i) accN[i][j] = mfma3(aH[i], aL[i], bh, bl, accN[i][j]);
    }
    __syncthreads();
  }
}

// ---------------- pre-split fused GRU: Out = relu(gru(Xin, Hid)), split I/O only ----------------
__global__ __launch_bounds__(256) void gru_ps_k(
    const unsigned short* __restrict__ XinH, const unsigned short* __restrict__ XinL,
    const unsigned short* __restrict__ HidH, const unsigned short* __restrict__ HidL,
    const unsigned short* __restrict__ wihH, const unsigned short* __restrict__ wihL,
    const unsigned short* __restrict__ whhH, const unsigned short* __restrict__ whhL,
    const float* __restrict__ bih, const float* __restrict__ bhh,
    unsigned short* __restrict__ OutH, unsigned short* __restrict__ OutL, int M)
{
  __shared__ unsigned short AsH[64*32], AsL[64*32];
  __shared__ unsigned short W0H[64*32], W0L[64*32];
  __shared__ unsigned short W1H[64*32], W1L[64*32];
  __shared__ unsigned short W2H[64*32], W2L[64*32];
  int nwg = gridDim.x, bid = blockIdx.x;
  int q = nwg >> 3, r = nwg & 7;
  int xcd = bid & 7, jj = bid >> 3;
  int idx = (xcd < r ? xcd*(q+1) : r*(q+1) + (xcd - r)*q) + jj;
  const int bm = (idx >> 2)*64, bn = (idx & 3)*64;
  const int tid = threadIdx.x;
  const int wave = tid >> 6, lane = tid & 63;
  const int wr = wave >> 1, wc = wave & 1;
  const int quad = lane >> 4, id = lane & 15;

  f32x4 accR[2][2] = {}, accZ[2][2] = {}, accI[2][2] = {}, accH[2][2] = {};

  gru_phase_ps(XinH, XinL, wihH, wihL, bm, bn, tid, wr, wc, quad, id,
               AsH, AsL, W0H, W0L, W1H, W1L, W2H, W2L, accR, accZ, accI);
  gru_phase_ps(HidH, HidL, whhH, whhL, bm, bn, tid, wr, wc, quad, id,
               AsH, AsL, W0H, W0L, W1H, W1L, W2H, W2L, accR, accZ, accH);

  #pragma unroll
  for (int i = 0; i < 2; ++i){
    int gr0 = bm + wr*32 + i*16 + quad*4;
    #pragma unroll
    for (int j = 0; j < 2; ++j){
      int gc = bn + wc*32 + j*16 + id;
      float br_  = bih[gc]     + bhh[gc];
      float bz_  = bih[256+gc] + bhh[256+gc];
      float bn_i = bih[512+gc], bn_h = bhh[512+gc];
      #pragma unroll
      for (int rr = 0; rr < 4; ++rr){
        int row = gr0 + rr;
        if (row >= M) continue;
        float rg = sigf(accR[i][j][rr] + br_);
        float zg = sigf(accZ[i][j][rr] + bz_);
        float ng = tanhf(accI[i][j][rr] + bn_i + rg*(accH[i][j][rr] + bn_h));
        float hv = rec2(HidH[(size_t)row*256 + gc], HidL[(size_t)row*256 + gc]);
        float o = (1.f - zg)*ng + zg*hv;
        o = o > 0.f ? o : 0.f;
        unsigned short h, l; split2(o, h, l);
        OutH[(size_t)row*256 + gc] = h;
        OutL[(size_t)row*256 + gc] = l;
      }
    }
  }
}

// ---------------- row dots over split pair: y1[m]=dot(X[m,:],w1), y2 optional ----------------
__global__ __launch_bounds__(256) void rowdot2_ps_k(
    const unsigned short* __restrict__ XH, const unsigned short* __restrict__ XL,
    const float* __restrict__ w1, const float* __restrict__ w2,
    float* __restrict__ y1, float* __restrict__ y2, int M)
{
  int m = blockIdx.x*4 + (threadIdx.x >> 6);
  if (m >= M) return;
  int lane = threadIdx.x & 63;
  us4 vh = *(const us4*)&XH[(size_t)m*256 + lane*4];
  us4 vl = *(const us4*)&XL[(size_t)m*256 + lane*4];
  float p1 = 0.f, p2 = 0.f;
  #pragma unroll
  for (int u = 0; u < 4; ++u){
    float xv = rec2(vh[u], vl[u]);
    int c = lane*4 + u;
    p1 += xv * w1[c];
    if (w2) p2 += xv * w2[c];
  }
  for (int o = 32; o > 0; o >>= 1){
    p1 += __shfl_down(p1, o);
    if (w2) p2 += __shfl_down(p2, o);
  }
  if (lane == 0){ y1[m] = p1; if (w2) y2[m] = p2; }
}

// ================= CSR build (dst-sorted incoming-edge lists) =================
__global__ void hist_k(const int* __restrict__ dst, unsigned* __restrict__ deg, int E){
  int e = blockIdx.x*256 + threadIdx.x;
  if (e >= E) return;
  atomicAdd(&deg[dst[e]], 1u);
}

__global__ __launch_bounds__(256) void scan1_k(const unsigned* __restrict__ deg,
    unsigned* __restrict__ incl, unsigned* __restrict__ bsum, int N)
{
  __shared__ unsigned sm[256];
  int t = threadIdx.x;
  int i = blockIdx.x*256 + t;
  unsigned v = (i < N) ? deg[i] : 0u;
  sm[t] = v; __syncthreads();
  for (int s = 1; s < 256; s <<= 1){
    unsigned u = (t >= s) ? sm[t - s] : 0u;
    __syncthreads();
    sm[t] += u;
    __syncthreads();
  }
  if (i < N) incl[i] = sm[t];
  if (t == 255) bsum[blockIdx.x] = sm[255];
}

__global__ __launch_bounds__(256) void scan2_k(unsigned* __restrict__ bsum, int nb){
  __shared__ unsigned sm[256];
  __shared__ unsigned carry;
  int t = threadIdx.x;
  if (t == 0) carry = 0u;
  __syncthreads();
  for (int base = 0; base < nb; base += 256){
    int i = base + t;
    unsigned v = (i < nb) ? bsum[i] : 0u;
    sm[t] = v; __syncthreads();
    for (int s = 1; s < 256; s <<= 1){
      unsigned u = (t >= s) ? sm[t - s] : 0u;
      __syncthreads();
      sm[t] += u;
      __syncthreads();
    }
    unsigned total = sm[255];
    unsigned c = carry;
    if (i < nb) bsum[i] = c + sm[t] - v;
    __syncthreads();
    if (t == 0) carry = c + total;
    __syncthreads();
  }
}

__global__ void scan3_k(const unsigned* __restrict__ incl, const unsigned* __restrict__ deg,
    const unsigned* __restrict__ bsum, unsigned* __restrict__ off, int N, int E)
{
  int i = blockIdx.x*256 + threadIdx.x;
  if (i < N) off[i] = incl[i] - deg[i] + bsum[blockIdx.x];
  if (i == 0) off[N] = (unsigned)E;
}

__global__ void fill_k(const int* __restrict__ src, const int* __restrict__ dst,
    const unsigned* __restrict__ off, unsigned* __restrict__ cur,
    int* __restrict__ csr_src, int* __restrict__ csr_eid, int E)
{
  int e = blockIdx.x*256 + threadIdx.x;
  if (e >= E) return;
  int d = dst[e];
  unsigned p = off[d] + atomicAdd(&cur[d], 1u);
  csr_src[p] = src[e];
  csr_eid[p] = e;
}

// ---------------- GATEConv edge score (Y split), written in CSR order ----------------
__global__ __launch_bounds__(256) void gate_edge_score_csr_k(
    const unsigned short* __restrict__ YH, const unsigned short* __restrict__ YL,
    const float* __restrict__ g_lin1W,
    const float* __restrict__ att_l, const float* __restrict__ ea_in,
    const float* __restrict__ xr, const int* __restrict__ csr_src,
    const int* __restrict__ csr_eid, const int* __restrict__ dst,
    float* __restrict__ a_out, int E, int H)
{
  int p = blockIdx.x*4 + (threadIdx.x >> 6);
  if (p >= E) return;
  int lane = threadIdx.x & 63;
  int s = csr_src[p];
  int e = csr_eid[p];
  int d = dst[e];
  float eav = ea_in[e];
  us4 vh = *(const us4*)&YH[(size_t)s*256 + lane*4];
  us4 vl = *(const us4*)&YL[(size_t)s*256 + lane*4];
  float acc = 0.f;
  #pragma unroll
  for (int u = 0; u < 4; ++u){
    int c = lane*4 + u;
    float yv = rec2(vh[u], vl[u]) + eav * g_lin1W[(size_t)c*(H+1) + H];
    acc += lreluf(yv) * att_l[c];
  }
  for (int o = 32; o > 0; o >>= 1) acc += __shfl_down(acc, o);
  if (lane == 0) a_out[p] = lreluf(acc + xr[d]);
}

// ---------------- per-node segment softmax over CSR (no atomics) ----------------
__global__ void node_softmax_k(const unsigned* __restrict__ off, const int* __restrict__ csr_src,
    const float* __restrict__ nd1, const float* __restrict__ nd2,
    float* __restrict__ w, int N, int mode)
{
  int n = blockIdx.x*256 + threadIdx.x;
  if (n >= N) return;
  unsigned p0 = off[n], p1 = off[n+1];
  float m = -INFINITY;
  if (mode){
    float d = nd2[n];
    for (unsigned p = p0; p < p1; ++p){
      float a = lreluf(nd1[csr_src[p]] + d);
      w[p] = a;
      m = fmaxf(m, a);
    }
  } else {
    for (unsigned p = p0; p < p1; ++p) m = fmaxf(m, w[p]);
  }
  float ssum = 0.f;
  for (unsigned p = p0; p < p1; ++p){
    float e = expf(w[p] - m);
    w[p] = e; ssum += e;
  }
  float inv = (ssum > 0.f) ? 1.f/ssum : 0.f;
  for (unsigned p = p0; p < p1; ++p) w[p] *= inv;
}

// ---------------- gather: h[n] = elu( sum_e w[e]*Z[src[e]] + bias ), split in/out ----------------
__global__ __launch_bounds__(256) void gather_h_k(
    const unsigned short* __restrict__ ZH, const unsigned short* __restrict__ ZL,
    const float* __restrict__ w, const unsigned* __restrict__ off,
    const int* __restrict__ csr_src, const float* __restrict__ bias,
    unsigned short* __restrict__ hH, unsigned short* __restrict__ hL, int N)
{
  int n = blockIdx.x*4 + (threadIdx.x >> 6);
  if (n >= N) return;
  int lane = threadIdx.x & 63;
  unsigned p0 = off[n], p1 = off[n+1];
  float4 acc = make_float4(0.f, 0.f, 0.f, 0.f);
  for (unsigned p = p0; p < p1; ++p){
    float wv = w[p];
    size_t zo = (size_t)csr_src[p]*256 + lane*4;
    us4 zh = *(const us4*)&ZH[zo];
    us4 zl = *(const us4*)&ZL[zo];
    acc.x = fmaf(wv, rec2(zh[0], zl[0]), acc.x);
    acc.y = fmaf(wv, rec2(zh[1], zl[1]), acc.y);
    acc.z = fmaf(wv, rec2(zh[2], zl[2]), acc.z);
    acc.w = fmaf(wv, rec2(zh[3], zl[3]), acc.w);
  }
  const float4 b = *(const float4*)&bias[lane*4];
  float vals[4];
  float v;
  v = acc.x + b.x; vals[0] = v > 0.f ? v : expf(v) - 1.f;
  v = acc.y + b.y; vals[1] = v > 0.f ? v : expf(v) - 1.f;
  v = acc.z + b.z; vals[2] = v > 0.f ? v : expf(v) - 1.f;
  v = acc.w + b.w; vals[3] = v > 0.f ? v : expf(v) - 1.f;
  us4 vh, vl;
  #pragma unroll
  for (int u = 0; u < 4; ++u){
    unsigned short h, l; split2(vals[u], h, l);
    vh[u] = h; vl[u] = l;
  }
  *(us4*)&hH[(size_t)n*256 + lane*4] = vh;
  *(us4*)&hL[(size_t)n*256 + lane*4] = vl;
}

// ---------------- pooling ----------------
__global__ void seg_bounds_k(const int* __restrict__ batch, unsigned* __restrict__ gs,
                             unsigned* __restrict__ ge, int N){
  int n = blockIdx.x*256 + threadIdx.x;
  if (n >= N) return;
  int g = batch[n];
  atomicMin(&gs[g], (unsigned)n);
  atomicMax(&ge[g], (unsigned)(n+1));
}
__global__ __launch_bounds__(256) void graph_pool_k(
    const unsigned short* __restrict__ xH, const unsigned short* __restrict__ xL,
    const unsigned* __restrict__ gs, const unsigned* __restrict__ ge,
    unsigned short* __restrict__ outgH, unsigned short* __restrict__ outgL)
{
  int g = blockIdx.x, t = threadIdx.x;
  unsigned s0 = gs[g], e0 = ge[g];
  float acc = 0.f;
  for (unsigned n = s0; n < e0; ++n)
    acc += rec2(xH[(size_t)n*256 + t], xL[(size_t)n*256 + t]);
  acc = acc > 0.f ? acc : 0.f;
  unsigned short h, l; split2(acc, h, l);
  outgH[(size_t)g*256 + t] = h;
  outgL[(size_t)g*256 + t] = l;
}
__global__ void precompute_v_k(const float* __restrict__ W, const float* __restrict__ ad,
                               float* __restrict__ v){
  int i = threadIdx.x;
  float acc = 0.f;
  for (int j = 0; j < 256; ++j) acc += W[(size_t)j*256 + i] * ad[j];
  v[i] = acc;
}
// fused mol attention timestep (split in/out)
__global__ __launch_bounds__(256) void mol_pool_k(
    const unsigned short* __restrict__ ogH, const unsigned short* __restrict__ ogL,
    const float* __restrict__ v, const float* __restrict__ asrc,
    const unsigned short* __restrict__ xwH, const unsigned short* __restrict__ xwL,
    const unsigned* __restrict__ gs, const unsigned* __restrict__ geb,
    const float* __restrict__ bias,
    unsigned short* __restrict__ hgH, unsigned short* __restrict__ hgL)
{
  __shared__ float red[256];
  int g = blockIdx.x, t = threadIdx.x;
  float ogv = rec2(ogH[(size_t)g*256 + t], ogL[(size_t)g*256 + t]);
  float tg = blkSum(ogv * v[t], red);
  unsigned s0 = gs[g], e0 = geb[g];
  float mx = -INFINITY;
  for (unsigned n = s0 + t; n < e0; n += 256) mx = fmaxf(mx, lreluf(asrc[n] + tg));
  mx = blkMax(mx, red);
  float sm = 0.f;
  for (unsigned n = s0 + t; n < e0; n += 256) sm += expf(lreluf(asrc[n] + tg) - mx);
  sm = blkSum(sm, red);
  float acc = 0.f;
  if (e0 > s0 && sm > 0.f){
    float inv = 1.f / sm;
    for (unsigned n = s0; n < e0; ++n){
      float w = expf(lreluf(asrc[n] + tg) - mx) * inv;
      acc = fmaf(w, rec2(xwH[(size_t)n*256 + t], xwL[(size_t)n*256 + t]), acc);
    }
  }
  float h0 = acc + bias[t];
  h0 = h0 > 0.f ? h0 : expf(h0) - 1.f;
  unsigned short h, l; split2(h0, h, l);
  hgH[(size_t)g*256 + t] = h;
  hgL[(size_t)g*256 + t] = l;
}

// ---------------- launcher ----------------
extern "C" void kernel_launch(void* const* d_in, const int* in_sizes, int n_in,
                              void* d_out, int out_size, void* d_ws, size_t ws_size,
                              hipStream_t stream)
{
  (void)n_in; (void)ws_size;
  const int H    = in_sizes[3];          // 256
  const int NIN  = in_sizes[2] / H;      // 300
  const int N    = in_sizes[0] / NIN;    // 100000
  const int E    = in_sizes[1];          // 400000
  const int NL   = in_sizes[16] / H;     // 3
  const int NHID = in_sizes[30];         // 512
  const int NOUT = in_sizes[32];         // 768
  const int G    = out_size / NOUT;      // 2048
  const int T    = 16;

  const float* x_in     = (const float*)d_in[0];
  const float* ea_in    = (const float*)d_in[1];
  const float* lin1_W   = (const float*)d_in[2];
  const float* lin1_b   = (const float*)d_in[3];
  const float* g_lin1W  = (const float*)d_in[4];
  const float* g_lin2W  = (const float*)d_in[5];
  const float* g_att_l  = (const float*)d_in[6];
  const float* g_att_r  = (const float*)d_in[7];
  const float* g_bias   = (const float*)d_in[8];
  const float* gru0_wih = (const float*)d_in[9];
  const float* gru0_whh = (const float*)d_in[10];
  const float* gru0_bih = (const float*)d_in[11];
  const float* gru0_bhh = (const float*)d_in[12];
  const float* atom_W   = (const float*)d_in[13];
  const float* atom_as  = (const float*)d_in[14];
  const float* atom_ad  = (const float*)d_in[15];
  const float* atom_b   = (const float*)d_in[16];
  const float* agru_wih = (const float*)d_in[17];
  const float* agru_whh = (const float*)d_in[18];
  const float* agru_bih = (const float*)d_in[19];
  const float* agru_bhh = (const float*)d_in[20];
  const float* mol_W    = (const float*)d_in[21];
  const float* mol_as   = (const float*)d_in[22];
  const float* mol_ad   = (const float*)d_in[23];
  const float* mol_b    = (const float*)d_in[24];
  const float* mgru_wih = (const float*)d_in[25];
  const float* mgru_whh = (const float*)d_in[26];
  const float* mgru_bih = (const float*)d_in[27];
  const float* mgru_bhh = (const float*)d_in[28];
  const float* lin2_W   = (const float*)d_in[29];
  const float* lin2_b   = (const float*)d_in[30];
  const float* fc1_W    = (const float*)d_in[31];
  const float* fc1_b    = (const float*)d_in[32];
  const int*  eidx      = (const int*)d_in[33];
  const int*  batch     = (const int*)d_in[34];
  const int*  srcI = eidx;
  const int*  dstI = eidx + E;

  char* wp = (char*)d_ws;
  auto alloc = [&](size_t bytes)->void*{
    void* p = (void*)wp;
    wp += (bytes + 255) & ~(size_t)255;
    return p;
  };
  auto allocUS = [&](size_t elems)->unsigned short*{ return (unsigned short*)alloc(elems*2); };

  // split activation pairs only (no f32 mirrors): 3 pairs x ~100MB
  unsigned short *xH  = allocUS((size_t)N*H), *xL  = allocUS((size_t)N*H);
  unsigned short *tAH = allocUS((size_t)N*H), *tAL = allocUS((size_t)N*H);
  unsigned short *hbH = allocUS((size_t)N*H), *hbL = allocUS((size_t)N*H);
  float*    ea    = (float*)alloc((size_t)E*4);       // CSR-ordered scores/weights
  float*    nd1   = (float*)alloc((size_t)N*4);
  float*    nd2   = (float*)alloc((size_t)N*4);
  unsigned short *ogH  = allocUS((size_t)G*H), *ogL  = allocUS((size_t)G*H);
  unsigned short *og2H = allocUS((size_t)G*H), *og2L = allocUS((size_t)G*H);
  unsigned short *hgH  = allocUS((size_t)G*H), *hgL  = allocUS((size_t)G*H);
  unsigned short *o2H  = allocUS((size_t)G*NHID), *o2L = allocUS((size_t)G*NHID);
  unsigned* gsb   = (unsigned*)alloc((size_t)G*4);
  unsigned* geb   = (unsigned*)alloc((size_t)G*4);
  float*    vvec  = (float*)alloc((size_t)H*4);
  // CSR structures
  const int nb = (N + 255) / 256;
  unsigned* deg     = (unsigned*)alloc((size_t)N*4);
  unsigned* cur     = (unsigned*)alloc((size_t)N*4);
  unsigned* incl    = (unsigned*)alloc((size_t)N*4);
  unsigned* off     = (unsigned*)alloc((size_t)(N+1)*4);
  unsigned* bsum    = (unsigned*)alloc((size_t)nb*4);
  int*      csr_src = (int*)alloc((size_t)E*4);
  int*      csr_eid = (int*)alloc((size_t)E*4);
  // pre-split weight buffers
  const size_t WG = (size_t)768*256;   // one GRU weight matrix
  const size_t WS = (size_t)256*256;   // one square GAT weight
  unsigned short *g0ihH = allocUS(WG), *g0ihL = allocUS(WG);
  unsigned short *g0hhH = allocUS(WG), *g0hhL = allocUS(WG);
  unsigned short *aihH  = allocUS(WG*NL), *aihL = allocUS(WG*NL);
  unsigned short *ahhH  = allocUS(WG*NL), *ahhL = allocUS(WG*NL);
  unsigned short *mihH  = allocUS(WG), *mihL = allocUS(WG);
  unsigned short *mhhH  = allocUS(WG), *mhhL = allocUS(WG);
  unsigned short *gl1H  = allocUS(WS), *gl1L = allocUS(WS);
  unsigned short *gl2H  = allocUS(WS), *gl2L = allocUS(WS);
  unsigned short *atWH  = allocUS(WS*NL), *atWL = allocUS(WS*NL);
  unsigned short *molH  = allocUS(WS), *molL = allocUS(WS);
  unsigned short *l2WH  = allocUS((size_t)NHID*256), *l2WL = allocUS((size_t)NHID*256);
  unsigned short *f1WH  = allocUS((size_t)NOUT*NHID), *f1WL = allocUS((size_t)NOUT*NHID);

  auto gemmps = [&](const unsigned short* AH_, const unsigned short* AL_,
                    const unsigned short* WH_, const unsigned short* WL_,
                    const float* bias, float* C, unsigned short* CH, unsigned short* CL,
                    int M_, int N_, int K_, int op){
    int ncb = N_ / 64;
    int nwg = ((M_ + 63)/64) * ncb;
    gemm_ps_k<<<dim3(nwg), dim3(256), 0, stream>>>(AH_, AL_, WH_, WL_, bias, C, CH, CL,
                                                   M_, N_, K_, op, ncb);
  };
  auto grup = [&](const unsigned short* XiH, const unsigned short* XiL,
                  const unsigned short* HiH, const unsigned short* HiL,
                  const unsigned short* ihH, const unsigned short* ihL,
                  const unsigned short* hhH, const unsigned short* hhL,
                  const float* bih, const float* bhh,
                  unsigned short* OH, unsigned short* OL, int M_){
    int nwg = ((M_ + 63)/64)*4;
    gru_ps_k<<<dim3(nwg), dim3(256), 0, stream>>>(XiH, XiL, HiH, HiL,
                                                  ihH, ihL, hhH, hhL, bih, bhh,
                                                  OH, OL, M_);
  };
  auto wsplit = [&](const float* src, unsigned short* Hd, unsigned short* Ld,
                    int lda, int K, long long rows){
    long long tot = rows * K;
    wsplit_k<<<dim3((unsigned)((tot + 255)/256)), dim3(256), 0, stream>>>(src, Hd, Ld, lda, K, tot);
  };

  // ---- pre-split all weights
  wsplit(gru0_wih, g0ihH, g0ihL, 256, 256, 768);
  wsplit(gru0_whh, g0hhH, g0hhL, 256, 256, 768);
  wsplit(agru_wih, aihH, aihL, 256, 256, (long long)NL*768);
  wsplit(agru_whh, ahhH, ahhL, 256, 256, (long long)NL*768);
  wsplit(mgru_wih, mihH, mihL, 256, 256, 768);
  wsplit(mgru_whh, mhhH, mhhL, 256, 256, 768);
  wsplit(g_lin1W,  gl1H, gl1L, H+1, 256, 256);
  wsplit(g_lin2W,  gl2H, gl2L, 256, 256, 256);
  wsplit(atom_W,   atWH, atWL, 256, 256, (long long)NL*256);
  wsplit(mol_W,    molH, molL, 256, 256, 256);
  wsplit(lin2_W,   l2WH, l2WL, 256, 256, NHID);
  wsplit(fc1_W,    f1WH, f1WL, NHID, NHID, NOUT);

  // ---- build CSR of incoming edges (reused by all 4 attention layers)
  hipMemsetAsync(deg, 0, (size_t)N*4, stream);
  hist_k<<<dim3((E+255)/256), dim3(256), 0, stream>>>(dstI, deg, E);
  scan1_k<<<dim3(nb), dim3(256), 0, stream>>>(deg, incl, bsum, N);
  scan2_k<<<dim3(1), dim3(256), 0, stream>>>(bsum, nb);
  scan3_k<<<dim3(nb), dim3(256), 0, stream>>>(incl, deg, bsum, off, N, E);
  hipMemsetAsync(cur, 0, (size_t)N*4, stream);
  fill_k<<<dim3((E+255)/256), dim3(256), 0, stream>>>(srcI, dstI, off, cur, csr_src, csr_eid, E);

  // ---- input projection (K=300, f32 path) -> x split
  {
    dim3 gr(4, (N + 63)/64);
    gemm_mfma_k<<<gr, dim3(256), 0, stream>>>(x_in, NIN, lin1_W, NIN, lin1_b,
                                              xH, xL, N, H, NIN, OP_LRELU);
  }

  // ---- GATEConv: Y -> hb (dead after edge score), Z -> tA
  {
    int nwg = ((N + 63)/64)*4;
    gemm2_ps_k<<<dim3(nwg), dim3(256), 0, stream>>>(xH, xL, gl1H, gl1L, gl2H, gl2L,
                                                    hbH, hbL, tAH, tAL, N);
  }
  rowdot2_ps_k<<<dim3((N+3)/4), dim3(256), 0, stream>>>(xH, xL, g_att_r, (const float*)nullptr,
                                                        nd1, (float*)nullptr, N);
  gate_edge_score_csr_k<<<dim3((E+3)/4), dim3(256), 0, stream>>>(hbH, hbL, g_lin1W, g_att_l,
                                                                 ea_in, nd1, csr_src, csr_eid,
                                                                 dstI, ea, E, H);
  node_softmax_k<<<dim3(nb), dim3(256), 0, stream>>>(off, csr_src, nullptr, nullptr, ea, N, 0);
  gather_h_k<<<dim3((N+3)/4), dim3(256), 0, stream>>>(tAH, tAL, ea, off, csr_src, g_bias,
                                                      hbH, hbL, N);
  grup(hbH, hbL, xH, xL, g0ihH, g0ihL, g0hhH, g0hhL, gru0_bih, gru0_bhh, tAH, tAL, N);
  { unsigned short* t = xH; xH = tAH; tAH = t; t = xL; xL = tAL; tAL = t; }

  // ---- atom GATConv layers
  for (int l = 0; l < NL; ++l){
    gemmps(xH, xL, atWH + (size_t)l*WS, atWL + (size_t)l*WS, nullptr,
           nullptr, tAH, tAL, N, 256, 256, OP_NONE);               // xw -> tA (split)
    rowdot2_ps_k<<<dim3((N+3)/4), dim3(256), 0, stream>>>(tAH, tAL, atom_as + (size_t)l*H,
                                                          atom_ad + (size_t)l*H, nd1, nd2, N);
    node_softmax_k<<<dim3(nb), dim3(256), 0, stream>>>(off, csr_src, nd1, nd2, ea, N, 1);
    gather_h_k<<<dim3((N+3)/4), dim3(256), 0, stream>>>(tAH, tAL, ea, off, csr_src,
                                                        atom_b + (size_t)l*H, hbH, hbL, N);
    grup(hbH, hbL, xH, xL,
         aihH + (size_t)l*WG, aihL + (size_t)l*WG,
         ahhH + (size_t)l*WG, ahhL + (size_t)l*WG,
         agru_bih + (size_t)l*3*H, agru_bhh + (size_t)l*3*H, tAH, tAL, N);
    { unsigned short* t = xH; xH = tAH; tAH = t; t = xL; xL = tAL; tAL = t; }
  }

  // ---- attentive pooling
  hipMemsetAsync(gsb, 0xFF, (size_t)G*4, stream);
  hipMemsetAsync(geb, 0x00, (size_t)G*4, stream);
  seg_bounds_k<<<dim3((N+255)/256), dim3(256), 0, stream>>>(batch, gsb, geb, N);
  graph_pool_k<<<dim3(G), dim3(256), 0, stream>>>(xH, xL, gsb, geb, ogH, ogL);
  gemmps(xH, xL, molH, molL, nullptr, nullptr, tAH, tAL, N, 256, 256, OP_NONE); // xw -> tA
  rowdot2_ps_k<<<dim3((N+3)/4), dim3(256), 0, stream>>>(tAH, tAL, mol_as, (const float*)nullptr,
                                                        nd1, (float*)nullptr, N);
  precompute_v_k<<<dim3(1), dim3(256), 0, stream>>>(mol_W, mol_ad, vvec);
  unsigned short *cogH = ogH, *cogL = ogL, *cog2H = og2H, *cog2L = og2L;
  for (int t = 0; t < T; ++t){
    mol_pool_k<<<dim3(G), dim3(256), 0, stream>>>(cogH, cogL, vvec, nd1, tAH, tAL,
                                                  gsb, geb, mol_b, hgH, hgL);
    grup(hgH, hgL, cogH, cogL, mihH, mihL, mhhH, mhhL, mgru_bih, mgru_bhh,
         cog2H, cog2L, G);
    { unsigned short* tt = cogH; cogH = cog2H; cog2H = tt;
      tt = cogL; cogL = cog2L; cog2L = tt; }
  }

  // ---- head: lin2 (relu, split out) then fc1 (f32 out to d_out)
  gemmps(cogH, cogL, l2WH, l2WL, lin2_b, nullptr, o2H, o2L, G, NHID, 256, OP_RELU);
  gemmps(o2H, o2L, f1WH, f1WL, fc1_b, (float*)d_out, nullptr, nullptr, G, NOUT, NHID, OP_NONE);
}

// Round 6
// 3893.388 us; speedup vs baseline: 1.6385x; 1.0264x over previous
//
#include <hip/hip_runtime.h>
#include <hip/hip_bf16.h>
#include <math.h>

typedef __attribute__((ext_vector_type(8))) short           short8;   // 8 bf16 (4 VGPRs)
typedef __attribute__((ext_vector_type(8))) unsigned short  ushort8;
typedef __attribute__((ext_vector_type(4))) unsigned short  us4;
typedef __attribute__((ext_vector_type(4))) float           f32x4;

__device__ __forceinline__ float lreluf(float v){ return v >= 0.f ? v : 0.01f*v; }
__device__ __forceinline__ float sigf(float v){ return 1.f/(1.f + expf(-v)); }

#define OP_NONE  0
#define OP_LRELU 1
#define OP_RELU  2

// async global->LDS, 16B per lane, dest = wave-uniform base + lane*16
#define GLDS16(gp, lp) __builtin_amdgcn_global_load_lds( \
    (const __attribute__((address_space(1))) void*)(gp), \
    (__attribute__((address_space(3))) void*)(lp), 16, 0, 0)

__device__ __forceinline__ float applyOp(float v, int op){
  if (op == OP_LRELU) return v >= 0.f ? v : 0.01f*v;
  if (op == OP_RELU)  return v > 0.f ? v : 0.f;
  return v;
}

// f32 -> bf16 RNE, raw ushort
__device__ __forceinline__ unsigned short f2b(float f){
  unsigned x = __float_as_uint(f);
  unsigned lsb = (x >> 16) & 1u;
  return (unsigned short)((x + 0x7fffu + lsb) >> 16);
}
__device__ __forceinline__ float b2f(unsigned short h){
  return __uint_as_float((unsigned)h << 16);
}
__device__ __forceinline__ void split2(float v, unsigned short& h, unsigned short& l){
  h = f2b(v);
  l = f2b(v - b2f(h));
}
__device__ __forceinline__ float rec2(unsigned short h, unsigned short l){
  return b2f(h) + b2f(l);
}

// LDS tile [rows][32] ushort, 16B-chunk XOR swizzle (R3-verified: conflicts = 0)
__device__ __forceinline__ int ldsOff(int row, int chunk){
  return row*32 + ((chunk ^ ((row >> 1) & 3)) << 3);
}

__device__ __forceinline__ float blkSum(float v, float* red){
  int t = threadIdx.x;
  red[t] = v; __syncthreads();
  for (int s = 128; s > 0; s >>= 1){ if (t < s) red[t] += red[t+s]; __syncthreads(); }
  float r = red[0]; __syncthreads();
  return r;
}
__device__ __forceinline__ float blkMax(float v, float* red){
  int t = threadIdx.x;
  red[t] = v; __syncthreads();
  for (int s = 128; s > 0; s >>= 1){ if (t < s) red[t] = fmaxf(red[t], red[t+s]); __syncthreads(); }
  float r = red[0]; __syncthreads();
  return r;
}

// 3-product split-precision accumulate: acc += (aH+aL)*(bH+bL) (drop lo*lo)
__device__ __forceinline__ f32x4 mfma3(short8 aH, short8 aL, short8 bH, short8 bL, f32x4 acc){
  acc = __builtin_amdgcn_mfma_f32_16x16x32_bf16(aL, bH, acc, 0, 0, 0);
  acc = __builtin_amdgcn_mfma_f32_16x16x32_bf16(aH, bL, acc, 0, 0, 0);
  acc = __builtin_amdgcn_mfma_f32_16x16x32_bf16(aH, bH, acc, 0, 0, 0);
  return acc;
}

// ================= weight pre-split: f32 [rows][lda] -> H/L ushort [rows][K] =================
__global__ void wsplit_k(const float* __restrict__ src, unsigned short* __restrict__ Hd,
                         unsigned short* __restrict__ Ld, int lda, int K, long long tot)
{
  long long i = (long long)blockIdx.x*256 + threadIdx.x;
  if (i >= tot) return;
  long long r = i / K; int c = (int)(i % K);
  float v = src[r*lda + c];
  unsigned short h = f2b(v);
  Hd[r*(long long)K + c] = h;
  Ld[r*(long long)K + c] = f2b(v - b2f(h));
}

// ---- async-stage 64x32 pre-split tile pair -> swizzled LDS via global_load_lds.
// Linear dest slot (r,c') = (tid>>2, tid&3) must hold source chunk c = c' ^ ((r>>1)&3)
// so that consumer reads via ldsOff(row, chunk) stay correct (m173 pre-swizzled-source).
__device__ __forceinline__ void stagePS(const unsigned short* __restrict__ GH,
    const unsigned short* __restrict__ GL, int ldk, int row0, int k0,
    unsigned short* __restrict__ ldsH, unsigned short* __restrict__ ldsL, int tid)
{
  int r = tid >> 2;
  int c = (tid & 3) ^ ((r >> 1) & 3);
  size_t go = (size_t)(row0 + r)*ldk + k0 + c*8;
  int wbase = (tid >> 6) * 512;          // wave-uniform LDS base (ushorts)
  GLDS16(&GH[go], &ldsH[wbase]);
  GLDS16(&GL[go], &ldsL[wbase]);
}

// ---- stage 64x32 f32 tile -> split bf16 hi/lo LDS (swizzled). generic K (lin1 only) ----
__device__ __forceinline__ void stage2(const float* __restrict__ src, int lda,
    int row0, int rowmax, int k0, int K,
    unsigned short* __restrict__ ldsH, unsigned short* __restrict__ ldsL, int tid)
{
  int r = tid >> 2, c = tid & 3;
  int gr = row0 + r, gk = k0 + c*8;
  const float* p = src + (size_t)gr*lda + gk;
  float f[8];
  if (gr < rowmax && gk + 8 <= K && ((lda & 3) == 0)){
    float4 f0 = *(const float4*)p;
    float4 f1 = *(const float4*)(p+4);
    f[0]=f0.x; f[1]=f0.y; f[2]=f0.z; f[3]=f0.w;
    f[4]=f1.x; f[5]=f1.y; f[6]=f1.z; f[7]=f1.w;
  } else {
    #pragma unroll
    for (int j = 0; j < 8; ++j) f[j] = (gr < rowmax && gk + j < K) ? p[j] : 0.f;
  }
  ushort8 vh, vl;
  #pragma unroll
  for (int j = 0; j < 8; ++j){
    unsigned short h, l; split2(f[j], h, l);
    vh[j] = h; vl[j] = l;
  }
  int off = ldsOff(r, c);
  *(ushort8*)&ldsH[off] = vh;
  *(ushort8*)&ldsL[off] = vl;
}

// ---------------- generic-K GEMM (f32 inputs; lin1 only): split out ----------------
__global__ __launch_bounds__(256) void gemm_mfma_k(
    const float* __restrict__ A, int lda,
    const float* __restrict__ W, int ldw,
    const float* __restrict__ bias,
    unsigned short* __restrict__ CH, unsigned short* __restrict__ CL,
    int M, int N, int K, int op)
{
  __shared__ unsigned short AsH[64*32], AsL[64*32];
  __shared__ unsigned short WsH[64*32], WsL[64*32];
  const int tid = threadIdx.x;
  const int bm = blockIdx.y * 64, bn = blockIdx.x * 64;
  const int wave = tid >> 6, lane = tid & 63;
  const int wr = wave >> 1, wc = wave & 1;
  const int quad = lane >> 4, id = lane & 15;

  f32x4 acc[2][2] = {};
  const int iters = (K + 31) / 32;
  for (int kt = 0; kt < iters; ++kt){
    int k0 = kt * 32;
    stage2(A, lda, bm, M, k0, K, AsH, AsL, tid);
    stage2(W, ldw, bn, N, k0, K, WsH, WsL, tid);
    __syncthreads();
    short8 aH[2], aL[2], bH[2], bL[2];
    #pragma unroll
    for (int i = 0; i < 2; ++i){
      int off = ldsOff(wr*32 + i*16 + id, quad);
      aH[i] = *(const short8*)&AsH[off];
      aL[i] = *(const short8*)&AsL[off];
    }
    #pragma unroll
    for (int j = 0; j < 2; ++j){
      int off = ldsOff(wc*32 + j*16 + id, quad);
      bH[j] = *(const short8*)&WsH[off];
      bL[j] = *(const short8*)&WsL[off];
    }
    #pragma unroll
    for (int i = 0; i < 2; ++i)
      #pragma unroll
      for (int j = 0; j < 2; ++j)
        acc[i][j] = mfma3(aH[i], aL[i], bH[j], bL[j], acc[i][j]);
    __syncthreads();
  }
  #pragma unroll
  for (int i = 0; i < 2; ++i){
    int gr0 = bm + wr*32 + i*16 + quad*4;
    #pragma unroll
    for (int j = 0; j < 2; ++j){
      int gc = bn + wc*32 + j*16 + id;
      if (gc >= N) continue;
      float bv = bias ? bias[gc] : 0.f;
      #pragma unroll
      for (int r = 0; r < 4; ++r){
        int row = gr0 + r;
        if (row >= M) continue;
        float v = applyOp(acc[i][j][r] + bv, op);
        unsigned short h, l; split2(v, h, l);
        CH[(size_t)row*N + gc] = h;
        CL[(size_t)row*N + gc] = l;
      }
    }
  }
}

// ---------------- pre-split GEMM: C = act(A @ W^T + b); f32 and/or split out ----------------
__global__ __launch_bounds__(256) void gemm_ps_k(
    const unsigned short* __restrict__ AH, const unsigned short* __restrict__ AL,
    const unsigned short* __restrict__ WH_, const unsigned short* __restrict__ WL_,
    const float* __restrict__ bias, float* __restrict__ C,
    unsigned short* __restrict__ CH, unsigned short* __restrict__ CL,
    int M, int N, int K, int op, int ncb)
{
  __shared__ unsigned short AsH[64*32], AsL[64*32];
  __shared__ unsigned short WsH[64*32], WsL[64*32];
  int nwg = gridDim.x, bid = blockIdx.x;
  int q = nwg >> 3, r = nwg & 7;
  int xcd = bid & 7, jj = bid >> 3;
  int idx = (xcd < r ? xcd*(q+1) : r*(q+1) + (xcd - r)*q) + jj;
  const int bm = (idx / ncb)*64, bn = (idx % ncb)*64;
  const int tid = threadIdx.x;
  const int wave = tid >> 6, lane = tid & 63;
  const int wr = wave >> 1, wc = wave & 1;
  const int quad = lane >> 4, id = lane & 15;

  f32x4 acc[2][2] = {};
  const int iters = K >> 5;
  for (int kt = 0; kt < iters; ++kt){
    int k0 = kt * 32;
    stagePS(AH, AL, K, bm, k0, AsH, AsL, tid);
    stagePS(WH_, WL_, K, bn, k0, WsH, WsL, tid);
    __syncthreads();
    short8 aH[2], aL[2], bH[2], bL[2];
    #pragma unroll
    for (int i = 0; i < 2; ++i){
      int off = ldsOff(wr*32 + i*16 + id, quad);
      aH[i] = *(const short8*)&AsH[off];
      aL[i] = *(const short8*)&AsL[off];
    }
    #pragma unroll
    for (int j = 0; j < 2; ++j){
      int off = ldsOff(wc*32 + j*16 + id, quad);
      bH[j] = *(const short8*)&WsH[off];
      bL[j] = *(const short8*)&WsL[off];
    }
    #pragma unroll
    for (int i = 0; i < 2; ++i)
      #pragma unroll
      for (int j = 0; j < 2; ++j)
        acc[i][j] = mfma3(aH[i], aL[i], bH[j], bL[j], acc[i][j]);
    __syncthreads();
  }
  #pragma unroll
  for (int i = 0; i < 2; ++i){
    int gr0 = bm + wr*32 + i*16 + quad*4;
    #pragma unroll
    for (int j = 0; j < 2; ++j){
      int gc = bn + wc*32 + j*16 + id;
      float bv = bias ? bias[gc] : 0.f;
      #pragma unroll
      for (int rr = 0; rr < 4; ++rr){
        int row = gr0 + rr;
        if (row >= M) continue;
        float v = applyOp(acc[i][j][rr] + bv, op);
        if (C)  C[(size_t)row*N + gc] = v;
        if (CH){
          unsigned short h, l; split2(v, h, l);
          CH[(size_t)row*N + gc] = h;
          CL[(size_t)row*N + gc] = l;
        }
      }
    }
  }
}

// ---------------- fused dual GEMM (GATEConv): Y = A@W1^T, Z = A@W2^T (split out) ----------------
__global__ __launch_bounds__(256) void gemm2_ps_k(
    const unsigned short* __restrict__ AH, const unsigned short* __restrict__ AL,
    const unsigned short* __restrict__ W1H, const unsigned short* __restrict__ W1L,
    const unsigned short* __restrict__ W2H, const unsigned short* __restrict__ W2L,
    unsigned short* __restrict__ YH, unsigned short* __restrict__ YL,
    unsigned short* __restrict__ ZH, unsigned short* __restrict__ ZL, int M)
{
  __shared__ unsigned short AsH[64*32], AsL[64*32];
  __shared__ unsigned short U1H[64*32], U1L[64*32];
  __shared__ unsigned short U2H[64*32], U2L[64*32];
  int nwg = gridDim.x, bid = blockIdx.x;
  int q = nwg >> 3, r = nwg & 7;
  int xcd = bid & 7, jj = bid >> 3;
  int idx = (xcd < r ? xcd*(q+1) : r*(q+1) + (xcd - r)*q) + jj;
  const int bm = (idx >> 2)*64, bn = (idx & 3)*64;
  const int tid = threadIdx.x;
  const int wave = tid >> 6, lane = tid & 63;
  const int wr = wave >> 1, wc = wave & 1;
  const int quad = lane >> 4, id = lane & 15;

  f32x4 acc1[2][2] = {}, acc2[2][2] = {};
  for (int kt = 0; kt < 8; ++kt){
    int k0 = kt * 32;
    stagePS(AH, AL, 256, bm, k0, AsH, AsL, tid);
    stagePS(W1H, W1L, 256, bn, k0, U1H, U1L, tid);
    stagePS(W2H, W2L, 256, bn, k0, U2H, U2L, tid);
    __syncthreads();
    short8 aH[2], aL[2];
    #pragma unroll
    for (int i = 0; i < 2; ++i){
      int off = ldsOff(wr*32 + i*16 + id, quad);
      aH[i] = *(const short8*)&AsH[off];
      aL[i] = *(const short8*)&AsL[off];
    }
    #pragma unroll
    for (int j = 0; j < 2; ++j){
      int off = ldsOff(wc*32 + j*16 + id, quad);
      short8 bh, bl;
      bh = *(const short8*)&U1H[off]; bl = *(const short8*)&U1L[off];
      #pragma unroll
      for (int i = 0; i < 2; ++i) acc1[i][j] = mfma3(aH[i], aL[i], bh, bl, acc1[i][j]);
      bh = *(const short8*)&U2H[off]; bl = *(const short8*)&U2L[off];
      #pragma unroll
      for (int i = 0; i < 2; ++i) acc2[i][j] = mfma3(aH[i], aL[i], bh, bl, acc2[i][j]);
    }
    __syncthreads();
  }
  #pragma unroll
  for (int i = 0; i < 2; ++i){
    int gr0 = bm + wr*32 + i*16 + quad*4;
    #pragma unroll
    for (int j = 0; j < 2; ++j){
      int gc = bn + wc*32 + j*16 + id;
      #pragma unroll
      for (int rr = 0; rr < 4; ++rr){
        int row = gr0 + rr;
        if (row >= M) continue;
        unsigned short h, l;
        split2(acc1[i][j][rr], h, l);
        YH[(size_t)row*256 + gc] = h; YL[(size_t)row*256 + gc] = l;
        split2(acc2[i][j][rr], h, l);
        ZH[(size_t)row*256 + gc] = h; ZL[(size_t)row*256 + gc] = l;
      }
    }
  }
}

// ---------------- GRU phase over pre-split A and 3 gate weights ----------------
__device__ __forceinline__ void gru_phase_ps(
    const unsigned short* __restrict__ AH, const unsigned short* __restrict__ AL,
    const unsigned short* __restrict__ WH_, const unsigned short* __restrict__ WL_,
    int bm, int bn, int tid, int wr, int wc, int quad, int id,
    unsigned short* AsH, unsigned short* AsL,
    unsigned short* W0H, unsigned short* W0L,
    unsigned short* W1H, unsigned short* W1L,
    unsigned short* W2H, unsigned short* W2L,
    f32x4 (&accR)[2][2], f32x4 (&accZ)[2][2], f32x4 (&accN)[2][2])
{
  for (int kt = 0; kt < 8; ++kt){
    int k0 = kt * 32;
    stagePS(AH, AL, 256, bm, k0, AsH, AsL, tid);
    stagePS(WH_,          WL_,          256, bn, k0, W0H, W0L, tid);
    stagePS(WH_ + 65536,  WL_ + 65536,  256, bn, k0, W1H, W1L, tid);
    stagePS(WH_ + 131072, WL_ + 131072, 256, bn, k0, W2H, W2L, tid);
    __syncthreads();
    short8 aH[2], aL[2];
    #pragma unroll
    for (int i = 0; i < 2; ++i){
      int off = ldsOff(wr*32 + i*16 + id, quad);
      aH[i] = *(const short8*)&AsH[off];
      aL[i] = *(const short8*)&AsL[off];
    }
    #pragma unroll
    for (int j = 0; j < 2; ++j){
      int off = ldsOff(wc*32 + j*16 + id, quad);
      short8 bh, bl;
      bh = *(const short8*)&W0H[off]; bl = *(const short8*)&W0L[off];
      #pragma unroll
      for (int i = 0; i < 2; ++i) accR[i][j] = mfma3(aH[i], aL[i], bh, bl, accR[i][j]);
      bh = *(const short8*)&W1H[off]; bl = *(const short8*)&W1L[off];
      #pragma unroll
      for (int i = 0; i < 2; ++i) accZ[i][j] = mfma3(aH[i], aL[i], bh, bl, accZ[i][j]);
      bh = *(const short8*)&W2H[off]; bl = *(const short8*)&W2L[off];
      #pragma unroll
      for (int i = 0; i < 2; ++i) accN[i][j] = mfma3(aH[i], aL[i], bh, bl, accN[i][j]);
    }
    __syncthreads();
  }
}

// ---------------- pre-split fused GRU: Out = relu(gru(Xin, Hid)), split I/O only ----------------
__global__ __launch_bounds__(256) void gru_ps_k(
    const unsigned short* __restrict__ XinH, const unsigned short* __restrict__ XinL,
    const unsigned short* __restrict__ HidH, const unsigned short* __restrict__ HidL,
    const unsigned short* __restrict__ wihH, const unsigned short* __restrict__ wihL,
    const unsigned short* __restrict__ whhH, const unsigned short* __restrict__ whhL,
    const float* __restrict__ bih, const float* __restrict__ bhh,
    unsigned short* __restrict__ OutH, unsigned short* __restrict__ OutL, int M)
{
  __shared__ unsigned short AsH[64*32], AsL[64*32];
  __shared__ unsigned short W0H[64*32], W0L[64*32];
  __shared__ unsigned short W1H[64*32], W1L[64*32];
  __shared__ unsigned short W2H[64*32], W2L[64*32];
  int nwg = gridDim.x, bid = blockIdx.x;
  int q = nwg >> 3, r = nwg & 7;
  int xcd = bid & 7, jj = bid >> 3;
  int idx = (xcd < r ? xcd*(q+1) : r*(q+1) + (xcd - r)*q) + jj;
  const int bm = (idx >> 2)*64, bn = (idx & 3)*64;
  const int tid = threadIdx.x;
  const int wave = tid >> 6, lane = tid & 63;
  const int wr = wave >> 1, wc = wave & 1;
  const int quad = lane >> 4, id = lane & 15;

  f32x4 accR[2][2] = {}, accZ[2][2] = {}, accI[2][2] = {}, accH[2][2] = {};

  gru_phase_ps(XinH, XinL, wihH, wihL, bm, bn, tid, wr, wc, quad, id,
               AsH, AsL, W0H, W0L, W1H, W1L, W2H, W2L, accR, accZ, accI);
  gru_phase_ps(HidH, HidL, whhH, whhL, bm, bn, tid, wr, wc, quad, id,
               AsH, AsL, W0H, W0L, W1H, W1L, W2H, W2L, accR, accZ, accH);

  #pragma unroll
  for (int i = 0; i < 2; ++i){
    int gr0 = bm + wr*32 + i*16 + quad*4;
    #pragma unroll
    for (int j = 0; j < 2; ++j){
      int gc = bn + wc*32 + j*16 + id;
      float br_  = bih[gc]     + bhh[gc];
      float bz_  = bih[256+gc] + bhh[256+gc];
      float bn_i = bih[512+gc], bn_h = bhh[512+gc];
      #pragma unroll
      for (int rr = 0; rr < 4; ++rr){
        int row = gr0 + rr;
        if (row >= M) continue;
        float rg = sigf(accR[i][j][rr] + br_);
        float zg = sigf(accZ[i][j][rr] + bz_);
        float ng = tanhf(accI[i][j][rr] + bn_i + rg*(accH[i][j][rr] + bn_h));
        float hv = rec2(HidH[(size_t)row*256 + gc], HidL[(size_t)row*256 + gc]);
        float o = (1.f - zg)*ng + zg*hv;
        o = o > 0.f ? o : 0.f;
        unsigned short h, l; split2(o, h, l);
        OutH[(size_t)row*256 + gc] = h;
        OutL[(size_t)row*256 + gc] = l;
      }
    }
  }
}

// ---------------- row dots over split pair: y1[m]=dot(X[m,:],w1), y2 optional ----------------
__global__ __launch_bounds__(256) void rowdot2_ps_k(
    const unsigned short* __restrict__ XH, const unsigned short* __restrict__ XL,
    const float* __restrict__ w1, const float* __restrict__ w2,
    float* __restrict__ y1, float* __restrict__ y2, int M)
{
  int m = blockIdx.x*4 + (threadIdx.x >> 6);
  if (m >= M) return;
  int lane = threadIdx.x & 63;
  us4 vh = *(const us4*)&XH[(size_t)m*256 + lane*4];
  us4 vl = *(const us4*)&XL[(size_t)m*256 + lane*4];
  float p1 = 0.f, p2 = 0.f;
  #pragma unroll
  for (int u = 0; u < 4; ++u){
    float xv = rec2(vh[u], vl[u]);
    int c = lane*4 + u;
    p1 += xv * w1[c];
    if (w2) p2 += xv * w2[c];
  }
  for (int o = 32; o > 0; o >>= 1){
    p1 += __shfl_down(p1, o);
    if (w2) p2 += __shfl_down(p2, o);
  }
  if (lane == 0){ y1[m] = p1; if (w2) y2[m] = p2; }
}

// ================= CSR build (dst-sorted incoming-edge lists) =================
__global__ void hist_k(const int* __restrict__ key, unsigned* __restrict__ deg, int E){
  int e = blockIdx.x*256 + threadIdx.x;
  if (e >= E) return;
  atomicAdd(&deg[key[e]], 1u);
}

__global__ __launch_bounds__(256) void scan1_k(const unsigned* __restrict__ deg,
    unsigned* __restrict__ incl, unsigned* __restrict__ bsum, int N)
{
  __shared__ unsigned sm[256];
  int t = threadIdx.x;
  int i = blockIdx.x*256 + t;
  unsigned v = (i < N) ? deg[i] : 0u;
  sm[t] = v; __syncthreads();
  for (int s = 1; s < 256; s <<= 1){
    unsigned u = (t >= s) ? sm[t - s] : 0u;
    __syncthreads();
    sm[t] += u;
    __syncthreads();
  }
  if (i < N) incl[i] = sm[t];
  if (t == 255) bsum[blockIdx.x] = sm[255];
}

__global__ __launch_bounds__(256) void scan2_k(unsigned* __restrict__ bsum, int nb){
  __shared__ unsigned sm[256];
  __shared__ unsigned carry;
  int t = threadIdx.x;
  if (t == 0) carry = 0u;
  __syncthreads();
  for (int base = 0; base < nb; base += 256){
    int i = base + t;
    unsigned v = (i < nb) ? bsum[i] : 0u;
    sm[t] = v; __syncthreads();
    for (int s = 1; s < 256; s <<= 1){
      unsigned u = (t >= s) ? sm[t - s] : 0u;
      __syncthreads();
      sm[t] += u;
      __syncthreads();
    }
    unsigned total = sm[255];
    unsigned c = carry;
    if (i < nb) bsum[i] = c + sm[t] - v;
    __syncthreads();
    if (t == 0) carry = c + total;
    __syncthreads();
  }
}

__global__ void scan3_k(const unsigned* __restrict__ incl, const unsigned* __restrict__ deg,
    const unsigned* __restrict__ bsum, unsigned* __restrict__ off, int N, int E)
{
  int i = blockIdx.x*256 + threadIdx.x;
  if (i < N) off[i] = incl[i] - deg[i] + bsum[blockIdx.x];
  if (i == 0) off[N] = (unsigned)E;
}

__global__ void fill_k(const int* __restrict__ src, const int* __restrict__ dst,
    const unsigned* __restrict__ off, unsigned* __restrict__ cur,
    int* __restrict__ csr_src, int* __restrict__ csr_eid, int* __restrict__ epos, int E)
{
  int e = blockIdx.x*256 + threadIdx.x;
  if (e >= E) return;
  int d = dst[e];
  unsigned p = off[d] + atomicAdd(&cur[d], 1u);
  csr_src[p] = src[e];
  csr_eid[p] = e;
  epos[e] = (int)p;
}

// CSC fill: for each edge, q = slot in src-keyed list; payload = dst-CSR position
__global__ void fill2_k(const int* __restrict__ src, const int* __restrict__ epos,
    const unsigned* __restrict__ off2, unsigned* __restrict__ cur,
    int* __restrict__ csc_pos, int E)
{
  int e = blockIdx.x*256 + threadIdx.x;
  if (e >= E) return;
  int s = src[e];
  unsigned qq = off2[s] + atomicAdd(&cur[s], 1u);
  csc_pos[qq] = epos[e];
}

// ---------------- GATEConv edge score, iterated by SRC node (Y row loaded once) ----------------
__global__ __launch_bounds__(256) void gate_edge_score_csc_k(
    const unsigned short* __restrict__ YH, const unsigned short* __restrict__ YL,
    const float* __restrict__ g_lin1W,
    const float* __restrict__ att_l, const float* __restrict__ ea_in,
    const float* __restrict__ xr,
    const unsigned* __restrict__ off2, const int* __restrict__ csc_pos,
    const int* __restrict__ csr_eid, const int* __restrict__ dst,
    float* __restrict__ a_out, int N, int H)
{
  int s = blockIdx.x*4 + (threadIdx.x >> 6);
  if (s >= N) return;
  int lane = threadIdx.x & 63;
  unsigned q0 = off2[s], q1 = off2[s+1];
  if (q0 == q1) return;
  us4 vh = *(const us4*)&YH[(size_t)s*256 + lane*4];
  us4 vl = *(const us4*)&YL[(size_t)s*256 + lane*4];
  float y4[4], w4[4], a4[4];
  #pragma unroll
  for (int u = 0; u < 4; ++u){
    int c = lane*4 + u;
    y4[u] = rec2(vh[u], vl[u]);
    w4[u] = g_lin1W[(size_t)c*(H+1) + H];   // edge-attr column
    a4[u] = att_l[c];
  }
  for (unsigned qq = q0; qq < q1; ++qq){
    int p = csc_pos[qq];
    int e = csr_eid[p];
    int d = dst[e];
    float eav = ea_in[e];
    float acc = 0.f;
    #pragma unroll
    for (int u = 0; u < 4; ++u)
      acc += lreluf(y4[u] + eav * w4[u]) * a4[u];
    for (int o = 32; o > 0; o >>= 1) acc += __shfl_down(acc, o);
    if (lane == 0) a_out[p] = lreluf(acc + xr[d]);
  }
}

// ---------------- per-node segment softmax over CSR (no atomics) ----------------
__global__ void node_softmax_k(const unsigned* __restrict__ off, const int* __restrict__ csr_src,
    const float* __restrict__ nd1, const float* __restrict__ nd2,
    float* __restrict__ w, int N, int mode)
{
  int n = blockIdx.x*256 + threadIdx.x;
  if (n >= N) return;
  unsigned p0 = off[n], p1 = off[n+1];
  float m = -INFINITY;
  if (mode){
    float d = nd2[n];
    for (unsigned p = p0; p < p1; ++p){
      float a = lreluf(nd1[csr_src[p]] + d);
      w[p] = a;
      m = fmaxf(m, a);
    }
  } else {
    for (unsigned p = p0; p < p1; ++p) m = fmaxf(m, w[p]);
  }
  float ssum = 0.f;
  for (unsigned p = p0; p < p1; ++p){
    float e = expf(w[p] - m);
    w[p] = e; ssum += e;
  }
  float inv = (ssum > 0.f) ? 1.f/ssum : 0.f;
  for (unsigned p = p0; p < p1; ++p) w[p] *= inv;
}

// ---------------- gather: h[n] = elu( sum_e w[e]*Z[src[e]] + bias ), 1-deep prefetch ----------------
__global__ __launch_bounds__(256) void gather_h_k(
    const unsigned short* __restrict__ ZH, const unsigned short* __restrict__ ZL,
    const float* __restrict__ w, const unsigned* __restrict__ off,
    const int* __restrict__ csr_src, const float* __restrict__ bias,
    unsigned short* __restrict__ hH, unsigned short* __restrict__ hL, int N)
{
  int n = blockIdx.x*4 + (threadIdx.x >> 6);
  if (n >= N) return;
  int lane = threadIdx.x & 63;
  unsigned p0 = off[n], p1 = off[n+1];
  float4 acc = make_float4(0.f, 0.f, 0.f, 0.f);
  if (p0 < p1){
    size_t zo = (size_t)csr_src[p0]*256 + lane*4;
    us4 zh_n = *(const us4*)&ZH[zo];
    us4 zl_n = *(const us4*)&ZL[zo];
    float w_n = w[p0];
    for (unsigned p = p0; p < p1; ++p){
      us4 zh = zh_n, zl = zl_n;
      float wv = w_n;
      if (p + 1 < p1){
        size_t zo2 = (size_t)csr_src[p+1]*256 + lane*4;
        zh_n = *(const us4*)&ZH[zo2];
        zl_n = *(const us4*)&ZL[zo2];
        w_n = w[p+1];
      }
      acc.x = fmaf(wv, rec2(zh[0], zl[0]), acc.x);
      acc.y = fmaf(wv, rec2(zh[1], zl[1]), acc.y);
      acc.z = fmaf(wv, rec2(zh[2], zl[2]), acc.z);
      acc.w = fmaf(wv, rec2(zh[3], zl[3]), acc.w);
    }
  }
  const float4 b = *(const float4*)&bias[lane*4];
  float vals[4];
  float v;
  v = acc.x + b.x; vals[0] = v > 0.f ? v : expf(v) - 1.f;
  v = acc.y + b.y; vals[1] = v > 0.f ? v : expf(v) - 1.f;
  v = acc.z + b.z; vals[2] = v > 0.f ? v : expf(v) - 1.f;
  v = acc.w + b.w; vals[3] = v > 0.f ? v : expf(v) - 1.f;
  us4 vh, vl;
  #pragma unroll
  for (int u = 0; u < 4; ++u){
    unsigned short h, l; split2(vals[u], h, l);
    vh[u] = h; vl[u] = l;
  }
  *(us4*)&hH[(size_t)n*256 + lane*4] = vh;
  *(us4*)&hL[(size_t)n*256 + lane*4] = vl;
}

// ---------------- pooling ----------------
__global__ void seg_bounds_k(const int* __restrict__ batch, unsigned* __restrict__ gs,
                             unsigned* __restrict__ ge, int N){
  int n = blockIdx.x*256 + threadIdx.x;
  if (n >= N) return;
  int g = batch[n];
  atomicMin(&gs[g], (unsigned)n);
  atomicMax(&ge[g], (unsigned)(n+1));
}
__global__ __launch_bounds__(256) void graph_pool_k(
    const unsigned short* __restrict__ xH, const unsigned short* __restrict__ xL,
    const unsigned* __restrict__ gs, const unsigned* __restrict__ ge,
    unsigned short* __restrict__ outgH, unsigned short* __restrict__ outgL)
{
  int g = blockIdx.x, t = threadIdx.x;
  unsigned s0 = gs[g], e0 = ge[g];
  float acc = 0.f;
  for (unsigned n = s0; n < e0; ++n)
    acc += rec2(xH[(size_t)n*256 + t], xL[(size_t)n*256 + t]);
  acc = acc > 0.f ? acc : 0.f;
  unsigned short h, l; split2(acc, h, l);
  outgH[(size_t)g*256 + t] = h;
  outgL[(size_t)g*256 + t] = l;
}
__global__ void precompute_v_k(const float* __restrict__ W, const float* __restrict__ ad,
                               float* __restrict__ v){
  int i = threadIdx.x;
  float acc = 0.f;
  for (int j = 0; j < 256; ++j) acc += W[(size_t)j*256 + i] * ad[j];
  v[i] = acc;
}
// fused mol attention timestep (split in/out)
__global__ __launch_bounds__(256) void mol_pool_k(
    const unsigned short* __restrict__ ogH, const unsigned short* __restrict__ ogL,
    const float* __restrict__ v, const float* __restrict__ asrc,
    const unsigned short* __restrict__ xwH, const unsigned short* __restrict__ xwL,
    const unsigned* __restrict__ gs, const unsigned* __restrict__ geb,
    const float* __restrict__ bias,
    unsigned short* __restrict__ hgH, unsigned short* __restrict__ hgL)
{
  __shared__ float red[256];
  int g = blockIdx.x, t = threadIdx.x;
  float ogv = rec2(ogH[(size_t)g*256 + t], ogL[(size_t)g*256 + t]);
  float tg = blkSum(ogv * v[t], red);
  unsigned s0 = gs[g], e0 = geb[g];
  float mx = -INFINITY;
  for (unsigned n = s0 + t; n < e0; n += 256) mx = fmaxf(mx, lreluf(asrc[n] + tg));
  mx = blkMax(mx, red);
  float sm = 0.f;
  for (unsigned n = s0 + t; n < e0; n += 256) sm += expf(lreluf(asrc[n] + tg) - mx);
  sm = blkSum(sm, red);
  float acc = 0.f;
  if (e0 > s0 && sm > 0.f){
    float inv = 1.f / sm;
    for (unsigned n = s0; n < e0; ++n){
      float w = expf(lreluf(asrc[n] + tg) - mx) * inv;
      acc = fmaf(w, rec2(xwH[(size_t)n*256 + t], xwL[(size_t)n*256 + t]), acc);
    }
  }
  float h0 = acc + bias[t];
  h0 = h0 > 0.f ? h0 : expf(h0) - 1.f;
  unsigned short h, l; split2(h0, h, l);
  hgH[(size_t)g*256 + t] = h;
  hgL[(size_t)g*256 + t] = l;
}

// ---------------- launcher ----------------
extern "C" void kernel_launch(void* const* d_in, const int* in_sizes, int n_in,
                              void* d_out, int out_size, void* d_ws, size_t ws_size,
                              hipStream_t stream)
{
  (void)n_in; (void)ws_size;
  const int H    = in_sizes[3];          // 256
  const int NIN  = in_sizes[2] / H;      // 300
  const int N    = in_sizes[0] / NIN;    // 100000
  const int E    = in_sizes[1];          // 400000
  const int NL   = in_sizes[16] / H;     // 3
  const int NHID = in_sizes[30];         // 512
  const int NOUT = in_sizes[32];         // 768
  const int G    = out_size / NOUT;      // 2048
  const int T    = 16;

  const float* x_in     = (const float*)d_in[0];
  const float* ea_in    = (const float*)d_in[1];
  const float* lin1_W   = (const float*)d_in[2];
  const float* lin1_b   = (const float*)d_in[3];
  const float* g_lin1W  = (const float*)d_in[4];
  const float* g_lin2W  = (const float*)d_in[5];
  const float* g_att_l  = (const float*)d_in[6];
  const float* g_att_r  = (const float*)d_in[7];
  const float* g_bias   = (const float*)d_in[8];
  const float* gru0_wih = (const float*)d_in[9];
  const float* gru0_whh = (const float*)d_in[10];
  const float* gru0_bih = (const float*)d_in[11];
  const float* gru0_bhh = (const float*)d_in[12];
  const float* atom_W   = (const float*)d_in[13];
  const float* atom_as  = (const float*)d_in[14];
  const float* atom_ad  = (const float*)d_in[15];
  const float* atom_b   = (const float*)d_in[16];
  const float* agru_wih = (const float*)d_in[17];
  const float* agru_whh = (const float*)d_in[18];
  const float* agru_bih = (const float*)d_in[19];
  const float* agru_bhh = (const float*)d_in[20];
  const float* mol_W    = (const float*)d_in[21];
  const float* mol_as   = (const float*)d_in[22];
  const float* mol_ad   = (const float*)d_in[23];
  const float* mol_b    = (const float*)d_in[24];
  const float* mgru_wih = (const float*)d_in[25];
  const float* mgru_whh = (const float*)d_in[26];
  const float* mgru_bih = (const float*)d_in[27];
  const float* mgru_bhh = (const float*)d_in[28];
  const float* lin2_W   = (const float*)d_in[29];
  const float* lin2_b   = (const float*)d_in[30];
  const float* fc1_W    = (const float*)d_in[31];
  const float* fc1_b    = (const float*)d_in[32];
  const int*  eidx      = (const int*)d_in[33];
  const int*  batch     = (const int*)d_in[34];
  const int*  srcI = eidx;
  const int*  dstI = eidx + E;

  char* wp = (char*)d_ws;
  auto alloc = [&](size_t bytes)->void*{
    void* p = (void*)wp;
    wp += (bytes + 255) & ~(size_t)255;
    return p;
  };
  auto allocUS = [&](size_t elems)->unsigned short*{ return (unsigned short*)alloc(elems*2); };

  // split activation pairs only (no f32 mirrors): 3 pairs x ~100MB
  unsigned short *xH  = allocUS((size_t)N*H), *xL  = allocUS((size_t)N*H);
  unsigned short *tAH = allocUS((size_t)N*H), *tAL = allocUS((size_t)N*H);
  unsigned short *hbH = allocUS((size_t)N*H), *hbL = allocUS((size_t)N*H);
  float*    ea    = (float*)alloc((size_t)E*4);       // CSR-ordered scores/weights
  float*    nd1   = (float*)alloc((size_t)N*4);
  float*    nd2   = (float*)alloc((size_t)N*4);
  unsigned short *ogH  = allocUS((size_t)G*H), *ogL  = allocUS((size_t)G*H);
  unsigned short *og2H = allocUS((size_t)G*H), *og2L = allocUS((size_t)G*H);
  unsigned short *hgH  = allocUS((size_t)G*H), *hgL  = allocUS((size_t)G*H);
  unsigned short *o2H  = allocUS((size_t)G*NHID), *o2L = allocUS((size_t)G*NHID);
  unsigned* gsb   = (unsigned*)alloc((size_t)G*4);
  unsigned* geb   = (unsigned*)alloc((size_t)G*4);
  float*    vvec  = (float*)alloc((size_t)H*4);
  // CSR/CSC structures
  const int nb = (N + 255) / 256;
  unsigned* deg     = (unsigned*)alloc((size_t)N*4);
  unsigned* cur     = (unsigned*)alloc((size_t)N*4);
  unsigned* incl    = (unsigned*)alloc((size_t)N*4);
  unsigned* off     = (unsigned*)alloc((size_t)(N+1)*4);
  unsigned* off2    = (unsigned*)alloc((size_t)(N+1)*4);
  unsigned* bsum    = (unsigned*)alloc((size_t)nb*4);
  int*      csr_src = (int*)alloc((size_t)E*4);
  int*      csr_eid = (int*)alloc((size_t)E*4);
  int*      epos    = (int*)alloc((size_t)E*4);
  int*      csc_pos = (int*)alloc((size_t)E*4);
  // pre-split weight buffers
  const size_t WG = (size_t)768*256;   // one GRU weight matrix
  const size_t WS = (size_t)256*256;   // one square GAT weight
  unsigned short *g0ihH = allocUS(WG), *g0ihL = allocUS(WG);
  unsigned short *g0hhH = allocUS(WG), *g0hhL = allocUS(WG);
  unsigned short *aihH  = allocUS(WG*NL), *aihL = allocUS(WG*NL);
  unsigned short *ahhH  = allocUS(WG*NL), *ahhL = allocUS(WG*NL);
  unsigned short *mihH  = allocUS(WG), *mihL = allocUS(WG);
  unsigned short *mhhH  = allocUS(WG), *mhhL = allocUS(WG);
  unsigned short *gl1H  = allocUS(WS), *gl1L = allocUS(WS);
  unsigned short *gl2H  = allocUS(WS), *gl2L = allocUS(WS);
  unsigned short *atWH  = allocUS(WS*NL), *atWL = allocUS(WS*NL);
  unsigned short *molH  = allocUS(WS), *molL = allocUS(WS);
  unsigned short *l2WH  = allocUS((size_t)NHID*256), *l2WL = allocUS((size_t)NHID*256);
  unsigned short *f1WH  = allocUS((size_t)NOUT*NHID), *f1WL = allocUS((size_t)NOUT*NHID);

  auto gemmps = [&](const unsigned short* AH_, const unsigned short* AL_,
                    const unsigned short* WH_, const unsigned short* WL_,
                    const float* bias, float* C, unsigned short* CH, unsigned short* CL,
                    int M_, int N_, int K_, int op){
    int ncb = N_ / 64;
    int nwg = ((M_ + 63)/64) * ncb;
    gemm_ps_k<<<dim3(nwg), dim3(256), 0, stream>>>(AH_, AL_, WH_, WL_, bias, C, CH, CL,
                                                   M_, N_, K_, op, ncb);
  };
  auto grup = [&](const unsigned short* XiH, const unsigned short* XiL,
                  const unsigned short* HiH, const unsigned short* HiL,
                  const unsigned short* ihH, const unsigned short* ihL,
                  const unsigned short* hhH, const unsigned short* hhL,
                  const float* bih, const float* bhh,
                  unsigned short* OH, unsigned short* OL, int M_){
    int nwg = ((M_ + 63)/64)*4;
    gru_ps_k<<<dim3(nwg), dim3(256), 0, stream>>>(XiH, XiL, HiH, HiL,
                                                  ihH, ihL, hhH, hhL, bih, bhh,
                                                  OH, OL, M_);
  };
  auto wsplit = [&](const float* src, unsigned short* Hd, unsigned short* Ld,
                    int lda, int K, long long rows){
    long long tot = rows * K;
    wsplit_k<<<dim3((unsigned)((tot + 255)/256)), dim3(256), 0, stream>>>(src, Hd, Ld, lda, K, tot);
  };

  // ---- pre-split all weights
  wsplit(gru0_wih, g0ihH, g0ihL, 256, 256, 768);
  wsplit(gru0_whh, g0hhH, g0hhL, 256, 256, 768);
  wsplit(agru_wih, aihH, aihL, 256, 256, (long long)NL*768);
  wsplit(agru_whh, ahhH, ahhL, 256, 256, (long long)NL*768);
  wsplit(mgru_wih, mihH, mihL, 256, 256, 768);
  wsplit(mgru_whh, mhhH, mhhL, 256, 256, 768);
  wsplit(g_lin1W,  gl1H, gl1L, H+1, 256, 256);
  wsplit(g_lin2W,  gl2H, gl2L, 256, 256, 256);
  wsplit(atom_W,   atWH, atWL, 256, 256, (long long)NL*256);
  wsplit(mol_W,    molH, molL, 256, 256, 256);
  wsplit(lin2_W,   l2WH, l2WL, 256, 256, NHID);
  wsplit(fc1_W,    f1WH, f1WL, NHID, NHID, NOUT);

  // ---- build dst-CSR (incoming edges) + src-CSC (outgoing, payload = CSR position)
  hipMemsetAsync(deg, 0, (size_t)N*4, stream);
  hist_k<<<dim3((E+255)/256), dim3(256), 0, stream>>>(dstI, deg, E);
  scan1_k<<<dim3(nb), dim3(256), 0, stream>>>(deg, incl, bsum, N);
  scan2_k<<<dim3(1), dim3(256), 0, stream>>>(bsum, nb);
  scan3_k<<<dim3(nb), dim3(256), 0, stream>>>(incl, deg, bsum, off, N, E);
  hipMemsetAsync(cur, 0, (size_t)N*4, stream);
  fill_k<<<dim3((E+255)/256), dim3(256), 0, stream>>>(srcI, dstI, off, cur, csr_src, csr_eid, epos, E);
  hipMemsetAsync(deg, 0, (size_t)N*4, stream);
  hist_k<<<dim3((E+255)/256), dim3(256), 0, stream>>>(srcI, deg, E);
  scan1_k<<<dim3(nb), dim3(256), 0, stream>>>(deg, incl, bsum, N);
  scan2_k<<<dim3(1), dim3(256), 0, stream>>>(bsum, nb);
  scan3_k<<<dim3(nb), dim3(256), 0, stream>>>(incl, deg, bsum, off2, N, E);
  hipMemsetAsync(cur, 0, (size_t)N*4, stream);
  fill2_k<<<dim3((E+255)/256), dim3(256), 0, stream>>>(srcI, epos, off2, cur, csc_pos, E);

  // ---- input projection (K=300, f32 path) -> x split
  {
    dim3 gr(4, (N + 63)/64);
    gemm_mfma_k<<<gr, dim3(256), 0, stream>>>(x_in, NIN, lin1_W, NIN, lin1_b,
                                              xH, xL, N, H, NIN, OP_LRELU);
  }

  // ---- GATEConv: Y -> hb (dead after edge score), Z -> tA
  {
    int nwg = ((N + 63)/64)*4;
    gemm2_ps_k<<<dim3(nwg), dim3(256), 0, stream>>>(xH, xL, gl1H, gl1L, gl2H, gl2L,
                                                    hbH, hbL, tAH, tAL, N);
  }
  rowdot2_ps_k<<<dim3((N+3)/4), dim3(256), 0, stream>>>(xH, xL, g_att_r, (const float*)nullptr,
                                                        nd1, (float*)nullptr, N);
  gate_edge_score_csc_k<<<dim3((N+3)/4), dim3(256), 0, stream>>>(hbH, hbL, g_lin1W, g_att_l,
                                                                 ea_in, nd1, off2, csc_pos,
                                                                 csr_eid, dstI, ea, N, H);
  node_softmax_k<<<dim3(nb), dim3(256), 0, stream>>>(off, csr_src, nullptr, nullptr, ea, N, 0);
  gather_h_k<<<dim3((N+3)/4), dim3(256), 0, stream>>>(tAH, tAL, ea, off, csr_src, g_bias,
                                                      hbH, hbL, N);
  grup(hbH, hbL, xH, xL, g0ihH, g0ihL, g0hhH, g0hhL, gru0_bih, gru0_bhh, tAH, tAL, N);
  { unsigned short* t = xH; xH = tAH; tAH = t; t = xL; xL = tAL; tAL = t; }

  // ---- atom GATConv layers
  for (int l = 0; l < NL; ++l){
    gemmps(xH, xL, atWH + (size_t)l*WS, atWL + (size_t)l*WS, nullptr,
           nullptr, tAH, tAL, N, 256, 256, OP_NONE);               // xw -> tA (split)
    rowdot2_ps_k<<<dim3((N+3)/4), dim3(256), 0, stream>>>(tAH, tAL, atom_as + (size_t)l*H,
                                                          atom_ad + (size_t)l*H, nd1, nd2, N);
    node_softmax_k<<<dim3(nb), dim3(256), 0, stream>>>(off, csr_src, nd1, nd2, ea, N, 1);
    gather_h_k<<<dim3((N+3)/4), dim3(256), 0, stream>>>(tAH, tAL, ea, off, csr_src,
                                                        atom_b + (size_t)l*H, hbH, hbL, N);
    grup(hbH, hbL, xH, xL,
         aihH + (size_t)l*WG, aihL + (size_t)l*WG,
         ahhH + (size_t)l*WG, ahhL + (size_t)l*WG,
         agru_bih + (size_t)l*3*H, agru_bhh + (size_t)l*3*H, tAH, tAL, N);
    { unsigned short* t = xH; xH = tAH; tAH = t; t = xL; xL = tAL; tAL = t; }
  }

  // ---- attentive pooling
  hipMemsetAsync(gsb, 0xFF, (size_t)G*4, stream);
  hipMemsetAsync(geb, 0x00, (size_t)G*4, stream);
  seg_bounds_k<<<dim3((N+255)/256), dim3(256), 0, stream>>>(batch, gsb, geb, N);
  graph_pool_k<<<dim3(G), dim3(256), 0, stream>>>(xH, xL, gsb, geb, ogH, ogL);
  gemmps(xH, xL, molH, molL, nullptr, nullptr, tAH, tAL, N, 256, 256, OP_NONE); // xw -> tA
  rowdot2_ps_k<<<dim3((N+3)/4), dim3(256), 0, stream>>>(tAH, tAL, mol_as, (const float*)nullptr,
                                                        nd1, (float*)nullptr, N);
  precompute_v_k<<<dim3(1), dim3(256), 0, stream>>>(mol_W, mol_ad, vvec);
  unsigned short *cogH = ogH, *cogL = ogL, *cog2H = og2H, *cog2L = og2L;
  for (int t = 0; t < T; ++t){
    mol_pool_k<<<dim3(G), dim3(256), 0, stream>>>(cogH, cogL, vvec, nd1, tAH, tAL,
                                                  gsb, geb, mol_b, hgH, hgL);
    grup(hgH, hgL, cogH, cogL, mihH, mihL, mhhH, mhhL, mgru_bih, mgru_bhh,
         cog2H, cog2L, G);
    { unsigned short* tt = cogH; cogH = cog2H; cog2H = tt;
      tt = cogL; cogL = cog2L; cog2L = tt; }
  }

  // ---- head: lin2 (relu, split out) then fc1 (f32 out to d_out)
  gemmps(cogH, cogL, l2WH, l2WL, lin2_b, nullptr, o2H, o2L, G, NHID, 256, OP_RELU);
  gemmps(o2H, o2L, f1WH, f1WL, fc1_b, (float*)d_out, nullptr, nullptr, G, NOUT, NHID, OP_NONE);
}

// Round 8
// 3656.310 us; speedup vs baseline: 1.7447x; 1.0648x over previous
//
#include <hip/hip_runtime.h>
#include <hip/hip_bf16.h>
#include <hip/hip_fp16.h>
#include <math.h>

typedef __attribute__((ext_vector_type(8))) short           short8;   // 8 bf16 (4 VGPRs)
typedef __attribute__((ext_vector_type(8))) unsigned short  ushort8;
typedef __attribute__((ext_vector_type(4))) unsigned short  us4;
typedef __attribute__((ext_vector_type(4))) float           f32x4;

__device__ __forceinline__ float lreluf(float v){ return v >= 0.f ? v : 0.01f*v; }
__device__ __forceinline__ float sigf(float v){ return 1.f/(1.f + expf(-v)); }

#define OP_NONE  0
#define OP_LRELU 1
#define OP_RELU  2

// async global->LDS, 16B per lane, dest = wave-uniform base + lane*16
#define GLDS16(gp, lp) __builtin_amdgcn_global_load_lds( \
    (const __attribute__((address_space(1))) void*)(gp), \
    (__attribute__((address_space(3))) void*)(lp), 16, 0, 0)

__device__ __forceinline__ float applyOp(float v, int op){
  if (op == OP_LRELU) return v >= 0.f ? v : 0.01f*v;
  if (op == OP_RELU)  return v > 0.f ? v : 0.f;
  return v;
}

// f32 -> bf16 RNE, raw ushort
__device__ __forceinline__ unsigned short f2b(float f){
  unsigned x = __float_as_uint(f);
  unsigned lsb = (x >> 16) & 1u;
  return (unsigned short)((x + 0x7fffu + lsb) >> 16);
}
__device__ __forceinline__ float b2f(unsigned short h){
  return __uint_as_float((unsigned)h << 16);
}
__device__ __forceinline__ void split2(float v, unsigned short& h, unsigned short& l){
  h = f2b(v);
  l = f2b(v - b2f(h));
}
__device__ __forceinline__ float rec2(unsigned short h, unsigned short l){
  return b2f(h) + b2f(l);
}
// fp16 message storage (10 mantissa bits; VALU-only consumers)
__device__ __forceinline__ unsigned short f2h(float f){
  return __half_as_ushort(__float2half(f));
}
__device__ __forceinline__ float h2f(unsigned short u){
  return __half2float(__ushort_as_half(u));
}

// LDS tile [rows][32] ushort, 16B-chunk XOR swizzle (R3-verified: conflicts = 0)
__device__ __forceinline__ int ldsOff(int row, int chunk){
  return row*32 + ((chunk ^ ((row >> 1) & 3)) << 3);
}

__device__ __forceinline__ float blkSum(float v, float* red){
  int t = threadIdx.x;
  red[t] = v; __syncthreads();
  for (int s = 128; s > 0; s >>= 1){ if (t < s) red[t] += red[t+s]; __syncthreads(); }
  float r = red[0]; __syncthreads();
  return r;
}
__device__ __forceinline__ float blkMax(float v, float* red){
  int t = threadIdx.x;
  red[t] = v; __syncthreads();
  for (int s = 128; s > 0; s >>= 1){ if (t < s) red[t] = fmaxf(red[t], red[t+s]); __syncthreads(); }
  float r = red[0]; __syncthreads();
  return r;
}

// 3-product split-precision accumulate: acc += (aH+aL)*(bH+bL) (drop lo*lo)
__device__ __forceinline__ f32x4 mfma3(short8 aH, short8 aL, short8 bH, short8 bL, f32x4 acc){
  acc = __builtin_amdgcn_mfma_f32_16x16x32_bf16(aL, bH, acc, 0, 0, 0);
  acc = __builtin_amdgcn_mfma_f32_16x16x32_bf16(aH, bL, acc, 0, 0, 0);
  acc = __builtin_amdgcn_mfma_f32_16x16x32_bf16(aH, bH, acc, 0, 0, 0);
  return acc;
}

// ================= weight pre-split: f32 [rows][lda] -> H/L ushort [rows][K] =================
__global__ void wsplit_k(const float* __restrict__ src, unsigned short* __restrict__ Hd,
                         unsigned short* __restrict__ Ld, int lda, int K, long long tot)
{
  long long i = (long long)blockIdx.x*256 + threadIdx.x;
  if (i >= tot) return;
  long long r = i / K; int c = (int)(i % K);
  float v = src[r*lda + c];
  unsigned short h = f2b(v);
  Hd[r*(long long)K + c] = h;
  Ld[r*(long long)K + c] = f2b(v - b2f(h));
}

// ---- async-stage 64x32 pre-split tile pair -> swizzled LDS via global_load_lds.
__device__ __forceinline__ void stagePS(const unsigned short* __restrict__ GH,
    const unsigned short* __restrict__ GL, int ldk, int row0, int k0,
    unsigned short* __restrict__ ldsH, unsigned short* __restrict__ ldsL, int tid)
{
  int r = tid >> 2;
  int c = (tid & 3) ^ ((r >> 1) & 3);
  size_t go = (size_t)(row0 + r)*ldk + k0 + c*8;
  int wbase = (tid >> 6) * 512;          // wave-uniform LDS base (ushorts)
  GLDS16(&GH[go], &ldsH[wbase]);
  GLDS16(&GL[go], &ldsL[wbase]);
}

// ---- stage 64x32 f32 tile -> split bf16 hi/lo LDS (swizzled). generic K (lin1 only) ----
__device__ __forceinline__ void stage2(const float* __restrict__ src, int lda,
    int row0, int rowmax, int k0, int K,
    unsigned short* __restrict__ ldsH, unsigned short* __restrict__ ldsL, int tid)
{
  int r = tid >> 2, c = tid & 3;
  int gr = row0 + r, gk = k0 + c*8;
  const float* p = src + (size_t)gr*lda + gk;
  float f[8];
  if (gr < rowmax && gk + 8 <= K && ((lda & 3) == 0)){
    float4 f0 = *(const float4*)p;
    float4 f1 = *(const float4*)(p+4);
    f[0]=f0.x; f[1]=f0.y; f[2]=f0.z; f[3]=f0.w;
    f[4]=f1.x; f[5]=f1.y; f[6]=f1.z; f[7]=f1.w;
  } else {
    #pragma unroll
    for (int j = 0; j < 8; ++j) f[j] = (gr < rowmax && gk + j < K) ? p[j] : 0.f;
  }
  ushort8 vh, vl;
  #pragma unroll
  for (int j = 0; j < 8; ++j){
    unsigned short h, l; split2(f[j], h, l);
    vh[j] = h; vl[j] = l;
  }
  int off = ldsOff(r, c);
  *(ushort8*)&ldsH[off] = vh;
  *(ushort8*)&ldsL[off] = vl;
}

// ---------------- generic-K GEMM (f32 inputs; lin1 only): split out ----------------
__global__ __launch_bounds__(256) void gemm_mfma_k(
    const float* __restrict__ A, int lda,
    const float* __restrict__ W, int ldw,
    const float* __restrict__ bias,
    unsigned short* __restrict__ CH, unsigned short* __restrict__ CL,
    int M, int N, int K, int op)
{
  __shared__ unsigned short AsH[64*32], AsL[64*32];
  __shared__ unsigned short WsH[64*32], WsL[64*32];
  const int tid = threadIdx.x;
  const int bm = blockIdx.y * 64, bn = blockIdx.x * 64;
  const int wave = tid >> 6, lane = tid & 63;
  const int wr = wave >> 1, wc = wave & 1;
  const int quad = lane >> 4, id = lane & 15;

  f32x4 acc[2][2] = {};
  const int iters = (K + 31) / 32;
  for (int kt = 0; kt < iters; ++kt){
    int k0 = kt * 32;
    stage2(A, lda, bm, M, k0, K, AsH, AsL, tid);
    stage2(W, ldw, bn, N, k0, K, WsH, WsL, tid);
    __syncthreads();
    short8 aH[2], aL[2], bH[2], bL[2];
    #pragma unroll
    for (int i = 0; i < 2; ++i){
      int off = ldsOff(wr*32 + i*16 + id, quad);
      aH[i] = *(const short8*)&AsH[off];
      aL[i] = *(const short8*)&AsL[off];
    }
    #pragma unroll
    for (int j = 0; j < 2; ++j){
      int off = ldsOff(wc*32 + j*16 + id, quad);
      bH[j] = *(const short8*)&WsH[off];
      bL[j] = *(const short8*)&WsL[off];
    }
    #pragma unroll
    for (int i = 0; i < 2; ++i)
      #pragma unroll
      for (int j = 0; j < 2; ++j)
        acc[i][j] = mfma3(aH[i], aL[i], bH[j], bL[j], acc[i][j]);
    __syncthreads();
  }
  #pragma unroll
  for (int i = 0; i < 2; ++i){
    int gr0 = bm + wr*32 + i*16 + quad*4;
    #pragma unroll
    for (int j = 0; j < 2; ++j){
      int gc = bn + wc*32 + j*16 + id;
      if (gc >= N) continue;
      float bv = bias ? bias[gc] : 0.f;
      #pragma unroll
      for (int r = 0; r < 4; ++r){
        int row = gr0 + r;
        if (row >= M) continue;
        float v = applyOp(acc[i][j][r] + bv, op);
        unsigned short h, l; split2(v, h, l);
        CH[(size_t)row*N + gc] = h;
        CL[(size_t)row*N + gc] = l;
      }
    }
  }
}

// ---------------- pre-split GEMM. Out: f32 C, and/or CH/CL (CL==null -> fp16 single) ----------------
__global__ __launch_bounds__(256) void gemm_ps_k(
    const unsigned short* __restrict__ AH, const unsigned short* __restrict__ AL,
    const unsigned short* __restrict__ WH_, const unsigned short* __restrict__ WL_,
    const float* __restrict__ bias, float* __restrict__ C,
    unsigned short* __restrict__ CH, unsigned short* __restrict__ CL,
    int M, int N, int K, int op, int ncb)
{
  __shared__ unsigned short AsH[64*32], AsL[64*32];
  __shared__ unsigned short WsH[64*32], WsL[64*32];
  int nwg = gridDim.x, bid = blockIdx.x;
  int q = nwg >> 3, r = nwg & 7;
  int xcd = bid & 7, jj = bid >> 3;
  int idx = (xcd < r ? xcd*(q+1) : r*(q+1) + (xcd - r)*q) + jj;
  const int bm = (idx / ncb)*64, bn = (idx % ncb)*64;
  const int tid = threadIdx.x;
  const int wave = tid >> 6, lane = tid & 63;
  const int wr = wave >> 1, wc = wave & 1;
  const int quad = lane >> 4, id = lane & 15;

  f32x4 acc[2][2] = {};
  const int iters = K >> 5;
  for (int kt = 0; kt < iters; ++kt){
    int k0 = kt * 32;
    stagePS(AH, AL, K, bm, k0, AsH, AsL, tid);
    stagePS(WH_, WL_, K, bn, k0, WsH, WsL, tid);
    __syncthreads();
    short8 aH[2], aL[2], bH[2], bL[2];
    #pragma unroll
    for (int i = 0; i < 2; ++i){
      int off = ldsOff(wr*32 + i*16 + id, quad);
      aH[i] = *(const short8*)&AsH[off];
      aL[i] = *(const short8*)&AsL[off];
    }
    #pragma unroll
    for (int j = 0; j < 2; ++j){
      int off = ldsOff(wc*32 + j*16 + id, quad);
      bH[j] = *(const short8*)&WsH[off];
      bL[j] = *(const short8*)&WsL[off];
    }
    #pragma unroll
    for (int i = 0; i < 2; ++i)
      #pragma unroll
      for (int j = 0; j < 2; ++j)
        acc[i][j] = mfma3(aH[i], aL[i], bH[j], bL[j], acc[i][j]);
    __syncthreads();
  }
  #pragma unroll
  for (int i = 0; i < 2; ++i){
    int gr0 = bm + wr*32 + i*16 + quad*4;
    #pragma unroll
    for (int j = 0; j < 2; ++j){
      int gc = bn + wc*32 + j*16 + id;
      float bv = bias ? bias[gc] : 0.f;
      #pragma unroll
      for (int rr = 0; rr < 4; ++rr){
        int row = gr0 + rr;
        if (row >= M) continue;
        float v = applyOp(acc[i][j][rr] + bv, op);
        if (C)  C[(size_t)row*N + gc] = v;
        if (CH){
          if (CL){
            unsigned short h, l; split2(v, h, l);
            CH[(size_t)row*N + gc] = h;
            CL[(size_t)row*N + gc] = l;
          } else {
            CH[(size_t)row*N + gc] = f2h(v);
          }
        }
      }
    }
  }
}

// ---------------- fused dual GEMM (GATEConv): Y,Z fp16 single out ----------------
__global__ __launch_bounds__(256) void gemm2_ps_k(
    const unsigned short* __restrict__ AH, const unsigned short* __restrict__ AL,
    const unsigned short* __restrict__ W1H, const unsigned short* __restrict__ W1L,
    const unsigned short* __restrict__ W2H, const unsigned short* __restrict__ W2L,
    unsigned short* __restrict__ YB, unsigned short* __restrict__ ZB, int M)
{
  __shared__ unsigned short AsH[64*32], AsL[64*32];
  __shared__ unsigned short U1H[64*32], U1L[64*32];
  __shared__ unsigned short U2H[64*32], U2L[64*32];
  int nwg = gridDim.x, bid = blockIdx.x;
  int q = nwg >> 3, r = nwg & 7;
  int xcd = bid & 7, jj = bid >> 3;
  int idx = (xcd < r ? xcd*(q+1) : r*(q+1) + (xcd - r)*q) + jj;
  const int bm = (idx >> 2)*64, bn = (idx & 3)*64;
  const int tid = threadIdx.x;
  const int wave = tid >> 6, lane = tid & 63;
  const int wr = wave >> 1, wc = wave & 1;
  const int quad = lane >> 4, id = lane & 15;

  f32x4 acc1[2][2] = {}, acc2[2][2] = {};
  for (int kt = 0; kt < 8; ++kt){
    int k0 = kt * 32;
    stagePS(AH, AL, 256, bm, k0, AsH, AsL, tid);
    stagePS(W1H, W1L, 256, bn, k0, U1H, U1L, tid);
    stagePS(W2H, W2L, 256, bn, k0, U2H, U2L, tid);
    __syncthreads();
    short8 aH[2], aL[2];
    #pragma unroll
    for (int i = 0; i < 2; ++i){
      int off = ldsOff(wr*32 + i*16 + id, quad);
      aH[i] = *(const short8*)&AsH[off];
      aL[i] = *(const short8*)&AsL[off];
    }
    #pragma unroll
    for (int j = 0; j < 2; ++j){
      int off = ldsOff(wc*32 + j*16 + id, quad);
      short8 bh, bl;
      bh = *(const short8*)&U1H[off]; bl = *(const short8*)&U1L[off];
      #pragma unroll
      for (int i = 0; i < 2; ++i) acc1[i][j] = mfma3(aH[i], aL[i], bh, bl, acc1[i][j]);
      bh = *(const short8*)&U2H[off]; bl = *(const short8*)&U2L[off];
      #pragma unroll
      for (int i = 0; i < 2; ++i) acc2[i][j] = mfma3(aH[i], aL[i], bh, bl, acc2[i][j]);
    }
    __syncthreads();
  }
  #pragma unroll
  for (int i = 0; i < 2; ++i){
    int gr0 = bm + wr*32 + i*16 + quad*4;
    #pragma unroll
    for (int j = 0; j < 2; ++j){
      int gc = bn + wc*32 + j*16 + id;
      #pragma unroll
      for (int rr = 0; rr < 4; ++rr){
        int row = gr0 + rr;
        if (row >= M) continue;
        YB[(size_t)row*256 + gc] = f2h(acc1[i][j][rr]);
        ZB[(size_t)row*256 + gc] = f2h(acc2[i][j][rr]);
      }
    }
  }
}

// ---------------- GRU phase over pre-split A and 3 gate weights ----------------
__device__ __forceinline__ void gru_phase_ps(
    const unsigned short* __restrict__ AH, const unsigned short* __restrict__ AL,
    const unsigned short* __restrict__ WH_, const unsigned short* __restrict__ WL_,
    int bm, int bn, int tid, int wr, int wc, int quad, int id,
    unsigned short* AsH, unsigned short* AsL,
    unsigned short* W0H, unsigned short* W0L,
    unsigned short* W1H, unsigned short* W1L,
    unsigned short* W2H, unsigned short* W2L,
    f32x4 (&accR)[2][2], f32x4 (&accZ)[2][2], f32x4 (&accN)[2][2])
{
  for (int kt = 0; kt < 8; ++kt){
    int k0 = kt * 32;
    stagePS(AH, AL, 256, bm, k0, AsH, AsL, tid);
    stagePS(WH_,          WL_,          256, bn, k0, W0H, W0L, tid);
    stagePS(WH_ + 65536,  WL_ + 65536,  256, bn, k0, W1H, W1L, tid);
    stagePS(WH_ + 131072, WL_ + 131072, 256, bn, k0, W2H, W2L, tid);
    __syncthreads();
    short8 aH[2], aL[2];
    #pragma unroll
    for (int i = 0; i < 2; ++i){
      int off = ldsOff(wr*32 + i*16 + id, quad);
      aH[i] = *(const short8*)&AsH[off];
      aL[i] = *(const short8*)&AsL[off];
    }
    #pragma unroll
    for (int j = 0; j < 2; ++j){
      int off = ldsOff(wc*32 + j*16 + id, quad);
      short8 bh, bl;
      bh = *(const short8*)&W0H[off]; bl = *(const short8*)&W0L[off];
      #pragma unroll
      for (int i = 0; i < 2; ++i) accR[i][j] = mfma3(aH[i], aL[i], bh, bl, accR[i][j]);
      bh = *(const short8*)&W1H[off]; bl = *(const short8*)&W1L[off];
      #pragma unroll
      for (int i = 0; i < 2; ++i) accZ[i][j] = mfma3(aH[i], aL[i], bh, bl, accZ[i][j]);
      bh = *(const short8*)&W2H[off]; bl = *(const short8*)&W2L[off];
      #pragma unroll
      for (int i = 0; i < 2; ++i) accN[i][j] = mfma3(aH[i], aL[i], bh, bl, accN[i][j]);
    }
    __syncthreads();
  }
}

// ---------------- pre-split fused GRU: Out = relu(gru(Xin, Hid)), split I/O only ----------------
__global__ __launch_bounds__(256) void gru_ps_k(
    const unsigned short* __restrict__ XinH, const unsigned short* __restrict__ XinL,
    const unsigned short* __restrict__ HidH, const unsigned short* __restrict__ HidL,
    const unsigned short* __restrict__ wihH, const unsigned short* __restrict__ wihL,
    const unsigned short* __restrict__ whhH, const unsigned short* __restrict__ whhL,
    const float* __restrict__ bih, const float* __restrict__ bhh,
    unsigned short* __restrict__ OutH, unsigned short* __restrict__ OutL, int M)
{
  __shared__ unsigned short AsH[64*32], AsL[64*32];
  __shared__ unsigned short W0H[64*32], W0L[64*32];
  __shared__ unsigned short W1H[64*32], W1L[64*32];
  __shared__ unsigned short W2H[64*32], W2L[64*32];
  int nwg = gridDim.x, bid = blockIdx.x;
  int q = nwg >> 3, r = nwg & 7;
  int xcd = bid & 7, jj = bid >> 3;
  int idx = (xcd < r ? xcd*(q+1) : r*(q+1) + (xcd - r)*q) + jj;
  const int bm = (idx >> 2)*64, bn = (idx & 3)*64;
  const int tid = threadIdx.x;
  const int wave = tid >> 6, lane = tid & 63;
  const int wr = wave >> 1, wc = wave & 1;
  const int quad = lane >> 4, id = lane & 15;

  f32x4 accR[2][2] = {}, accZ[2][2] = {}, accI[2][2] = {}, accH[2][2] = {};

  gru_phase_ps(XinH, XinL, wihH, wihL, bm, bn, tid, wr, wc, quad, id,
               AsH, AsL, W0H, W0L, W1H, W1L, W2H, W2L, accR, accZ, accI);
  gru_phase_ps(HidH, HidL, whhH, whhL, bm, bn, tid, wr, wc, quad, id,
               AsH, AsL, W0H, W0L, W1H, W1L, W2H, W2L, accR, accZ, accH);

  #pragma unroll
  for (int i = 0; i < 2; ++i){
    int gr0 = bm + wr*32 + i*16 + quad*4;
    #pragma unroll
    for (int j = 0; j < 2; ++j){
      int gc = bn + wc*32 + j*16 + id;
      float br_  = bih[gc]     + bhh[gc];
      float bz_  = bih[256+gc] + bhh[256+gc];
      float bn_i = bih[512+gc], bn_h = bhh[512+gc];
      #pragma unroll
      for (int rr = 0; rr < 4; ++rr){
        int row = gr0 + rr;
        if (row >= M) continue;
        float rg = sigf(accR[i][j][rr] + br_);
        float zg = sigf(accZ[i][j][rr] + bz_);
        float ng = tanhf(accI[i][j][rr] + bn_i + rg*(accH[i][j][rr] + bn_h));
        float hv = rec2(HidH[(size_t)row*256 + gc], HidL[(size_t)row*256 + gc]);
        float o = (1.f - zg)*ng + zg*hv;
        o = o > 0.f ? o : 0.f;
        unsigned short h, l; split2(o, h, l);
        OutH[(size_t)row*256 + gc] = h;
        OutL[(size_t)row*256 + gc] = l;
      }
    }
  }
}

// ---------------- row dots over split pair (x only) ----------------
__global__ __launch_bounds__(256) void rowdot2_ps_k(
    const unsigned short* __restrict__ XH, const unsigned short* __restrict__ XL,
    const float* __restrict__ w1, const float* __restrict__ w2,
    float* __restrict__ y1, float* __restrict__ y2, int M)
{
  int m = blockIdx.x*4 + (threadIdx.x >> 6);
  if (m >= M) return;
  int lane = threadIdx.x & 63;
  us4 vh = *(const us4*)&XH[(size_t)m*256 + lane*4];
  us4 vl = *(const us4*)&XL[(size_t)m*256 + lane*4];
  float p1 = 0.f, p2 = 0.f;
  #pragma unroll
  for (int u = 0; u < 4; ++u){
    float xv = rec2(vh[u], vl[u]);
    int c = lane*4 + u;
    p1 += xv * w1[c];
    if (w2) p2 += xv * w2[c];
  }
  for (int o = 32; o > 0; o >>= 1){
    p1 += __shfl_down(p1, o);
    if (w2) p2 += __shfl_down(p2, o);
  }
  if (lane == 0){ y1[m] = p1; if (w2) y2[m] = p2; }
}

// ---------------- row dots over single fp16 buffer (xw) ----------------
__global__ __launch_bounds__(256) void rowdot_b_k(
    const unsigned short* __restrict__ XB,
    const float* __restrict__ w1, const float* __restrict__ w2,
    float* __restrict__ y1, float* __restrict__ y2, int M)
{
  int m = blockIdx.x*4 + (threadIdx.x >> 6);
  if (m >= M) return;
  int lane = threadIdx.x & 63;
  us4 vh = *(const us4*)&XB[(size_t)m*256 + lane*4];
  float p1 = 0.f, p2 = 0.f;
  #pragma unroll
  for (int u = 0; u < 4; ++u){
    float xv = h2f(vh[u]);
    int c = lane*4 + u;
    p1 += xv * w1[c];
    if (w2) p2 += xv * w2[c];
  }
  for (int o = 32; o > 0; o >>= 1){
    p1 += __shfl_down(p1, o);
    if (w2) p2 += __shfl_down(p2, o);
  }
  if (lane == 0){ y1[m] = p1; if (w2) y2[m] = p2; }
}

// ================= CSR build (dst-sorted incoming-edge lists) =================
__global__ void hist_k(const int* __restrict__ key, unsigned* __restrict__ deg, int E){
  int e = blockIdx.x*256 + threadIdx.x;
  if (e >= E) return;
  atomicAdd(&deg[key[e]], 1u);
}

__global__ __launch_bounds__(256) void scan1_k(const unsigned* __restrict__ deg,
    unsigned* __restrict__ incl, unsigned* __restrict__ bsum, int N)
{
  __shared__ unsigned sm[256];
  int t = threadIdx.x;
  int i = blockIdx.x*256 + t;
  unsigned v = (i < N) ? deg[i] : 0u;
  sm[t] = v; __syncthreads();
  for (int s = 1; s < 256; s <<= 1){
    unsigned u = (t >= s) ? sm[t - s] : 0u;
    __syncthreads();
    sm[t] += u;
    __syncthreads();
  }
  if (i < N) incl[i] = sm[t];
  if (t == 255) bsum[blockIdx.x] = sm[255];
}

__global__ __launch_bounds__(256) void scan2_k(unsigned* __restrict__ bsum, int nb){
  __shared__ unsigned sm[256];
  __shared__ unsigned carry;
  int t = threadIdx.x;
  if (t == 0) carry = 0u;
  __syncthreads();
  for (int base = 0; base < nb; base += 256){
    int i = base + t;
    unsigned v = (i < nb) ? bsum[i] : 0u;
    sm[t] = v; __syncthreads();
    for (int s = 1; s < 256; s <<= 1){
      unsigned u = (t >= s) ? sm[t - s] : 0u;
      __syncthreads();
      sm[t] += u;
      __syncthreads();
    }
    unsigned total = sm[255];
    unsigned c = carry;
    if (i < nb) bsum[i] = c + sm[t] - v;
    __syncthreads();
    if (t == 0) carry = c + total;
    __syncthreads();
  }
}

__global__ void scan3_k(const unsigned* __restrict__ incl, const unsigned* __restrict__ deg,
    const unsigned* __restrict__ bsum, unsigned* __restrict__ off, int N, int E)
{
  int i = blockIdx.x*256 + threadIdx.x;
  if (i < N) off[i] = incl[i] - deg[i] + bsum[blockIdx.x];
  if (i == 0) off[N] = (unsigned)E;
}

__global__ void fill_k(const int* __restrict__ src, const int* __restrict__ dst,
    const unsigned* __restrict__ off, unsigned* __restrict__ cur,
    int* __restrict__ csr_src, int* __restrict__ csr_eid, int* __restrict__ epos, int E)
{
  int e = blockIdx.x*256 + threadIdx.x;
  if (e >= E) return;
  int d = dst[e];
  unsigned p = off[d] + atomicAdd(&cur[d], 1u);
  csr_src[p] = src[e];
  csr_eid[p] = e;
  epos[e] = (int)p;
}

// CSC fill: for each edge, q = slot in src-keyed list; payload = dst-CSR position
__global__ void fill2_k(const int* __restrict__ src, const int* __restrict__ epos,
    const unsigned* __restrict__ off2, unsigned* __restrict__ cur,
    int* __restrict__ csc_pos, int E)
{
  int e = blockIdx.x*256 + threadIdx.x;
  if (e >= E) return;
  int s = src[e];
  unsigned qq = off2[s] + atomicAdd(&cur[s], 1u);
  csc_pos[qq] = epos[e];
}

// ---------------- GATEConv edge score, iterated by SRC node (Y fp16, row loaded once) ----------------
__global__ __launch_bounds__(256) void gate_edge_score_csc_k(
    const unsigned short* __restrict__ YB,
    const float* __restrict__ g_lin1W,
    const float* __restrict__ att_l, const float* __restrict__ ea_in,
    const float* __restrict__ xr,
    const unsigned* __restrict__ off2, const int* __restrict__ csc_pos,
    const int* __restrict__ csr_eid, const int* __restrict__ dst,
    float* __restrict__ a_out, int N, int H)
{
  int s = blockIdx.x*4 + (threadIdx.x >> 6);
  if (s >= N) return;
  int lane = threadIdx.x & 63;
  unsigned q0 = off2[s], q1 = off2[s+1];
  if (q0 == q1) return;
  us4 vh = *(const us4*)&YB[(size_t)s*256 + lane*4];
  float y4[4], w4[4], a4[4];
  #pragma unroll
  for (int u = 0; u < 4; ++u){
    int c = lane*4 + u;
    y4[u] = h2f(vh[u]);
    w4[u] = g_lin1W[(size_t)c*(H+1) + H];   // edge-attr column
    a4[u] = att_l[c];
  }
  for (unsigned qq = q0; qq < q1; ++qq){
    int p = csc_pos[qq];
    int e = csr_eid[p];
    int d = dst[e];
    float eav = ea_in[e];
    float acc = 0.f;
    #pragma unroll
    for (int u = 0; u < 4; ++u)
      acc += lreluf(y4[u] + eav * w4[u]) * a4[u];
    for (int o = 32; o > 0; o >>= 1) acc += __shfl_down(acc, o);
    if (lane == 0) a_out[p] = lreluf(acc + xr[d]);
  }
}

// ---------------- per-node segment softmax over CSR (no atomics) ----------------
__global__ void node_softmax_k(const unsigned* __restrict__ off, const int* __restrict__ csr_src,
    const float* __restrict__ nd1, const float* __restrict__ nd2,
    float* __restrict__ w, int N, int mode)
{
  int n = blockIdx.x*256 + threadIdx.x;
  if (n >= N) return;
  unsigned p0 = off[n], p1 = off[n+1];
  float m = -INFINITY;
  if (mode){
    float d = nd2[n];
    for (unsigned p = p0; p < p1; ++p){
      float a = lreluf(nd1[csr_src[p]] + d);
      w[p] = a;
      m = fmaxf(m, a);
    }
  } else {
    for (unsigned p = p0; p < p1; ++p) m = fmaxf(m, w[p]);
  }
  float ssum = 0.f;
  for (unsigned p = p0; p < p1; ++p){
    float e = expf(w[p] - m);
    w[p] = e; ssum += e;
  }
  float inv = (ssum > 0.f) ? 1.f/ssum : 0.f;
  for (unsigned p = p0; p < p1; ++p) w[p] *= inv;
}

// ---------------- gather: h[n] = elu( sum_e w[e]*Z[src[e]] + bias ), Z fp16, split out ----------------
__global__ __launch_bounds__(256) void gather_h_k(
    const unsigned short* __restrict__ ZB,
    const float* __restrict__ w, const unsigned* __restrict__ off,
    const int* __restrict__ csr_src, const float* __restrict__ bias,
    unsigned short* __restrict__ hH, unsigned short* __restrict__ hL, int N)
{
  int n = blockIdx.x*4 + (threadIdx.x >> 6);
  if (n >= N) return;
  int lane = threadIdx.x & 63;
  unsigned p0 = off[n], p1 = off[n+1];
  float4 acc = make_float4(0.f, 0.f, 0.f, 0.f);
  if (p0 < p1){
    us4 zh_n = *(const us4*)&ZB[(size_t)csr_src[p0]*256 + lane*4];
    float w_n = w[p0];
    for (unsigned p = p0; p < p1; ++p){
      us4 zh = zh_n;
      float wv = w_n;
      if (p + 1 < p1){
        zh_n = *(const us4*)&ZB[(size_t)csr_src[p+1]*256 + lane*4];
        w_n = w[p+1];
      }
      acc.x = fmaf(wv, h2f(zh[0]), acc.x);
      acc.y = fmaf(wv, h2f(zh[1]), acc.y);
      acc.z = fmaf(wv, h2f(zh[2]), acc.z);
      acc.w = fmaf(wv, h2f(zh[3]), acc.w);
    }
  }
  const float4 b = *(const float4*)&bias[lane*4];
  float vals[4];
  float v;
  v = acc.x + b.x; vals[0] = v > 0.f ? v : expf(v) - 1.f;
  v = acc.y + b.y; vals[1] = v > 0.f ? v : expf(v) - 1.f;
  v = acc.z + b.z; vals[2] = v > 0.f ? v : expf(v) - 1.f;
  v = acc.w + b.w; vals[3] = v > 0.f ? v : expf(v) - 1.f;
  us4 vh, vl;
  #pragma unroll
  for (int u = 0; u < 4; ++u){
    unsigned short h, l; split2(vals[u], h, l);
    vh[u] = h; vl[u] = l;
  }
  *(us4*)&hH[(size_t)n*256 + lane*4] = vh;
  *(us4*)&hL[(size_t)n*256 + lane*4] = vl;
}

// ---------------- pooling ----------------
__global__ void seg_bounds_k(const int* __restrict__ batch, unsigned* __restrict__ gs,
                             unsigned* __restrict__ ge, int N){
  int n = blockIdx.x*256 + threadIdx.x;
  if (n >= N) return;
  int g = batch[n];
  atomicMin(&gs[g], (unsigned)n);
  atomicMax(&ge[g], (unsigned)(n+1));
}
__global__ __launch_bounds__(256) void graph_pool_k(
    const unsigned short* __restrict__ xH, const unsigned short* __restrict__ xL,
    const unsigned* __restrict__ gs, const unsigned* __restrict__ ge,
    unsigned short* __restrict__ outgH, unsigned short* __restrict__ outgL)
{
  int g = blockIdx.x, t = threadIdx.x;
  unsigned s0 = gs[g], e0 = ge[g];
  float acc = 0.f;
  for (unsigned n = s0; n < e0; ++n)
    acc += rec2(xH[(size_t)n*256 + t], xL[(size_t)n*256 + t]);
  acc = acc > 0.f ? acc : 0.f;
  unsigned short h, l; split2(acc, h, l);
  outgH[(size_t)g*256 + t] = h;
  outgL[(size_t)g*256 + t] = l;
}
__global__ void precompute_v_k(const float* __restrict__ W, const float* __restrict__ ad,
                               float* __restrict__ v){
  int i = threadIdx.x;
  float acc = 0.f;
  for (int j = 0; j < 256; ++j) acc += W[(size_t)j*256 + i] * ad[j];
  v[i] = acc;
}
// fused mol attention timestep (xw fp16 single)
__global__ __launch_bounds__(256) void mol_pool_k(
    const unsigned short* __restrict__ ogH, const unsigned short* __restrict__ ogL,
    const float* __restrict__ v, const float* __restrict__ asrc,
    const unsigned short* __restrict__ xwB,
    const unsigned* __restrict__ gs, const unsigned* __restrict__ geb,
    const float* __restrict__ bias,
    unsigned short* __restrict__ hgH, unsigned short* __restrict__ hgL)
{
  __shared__ float red[256];
  int g = blockIdx.x, t = threadIdx.x;
  float ogv = rec2(ogH[(size_t)g*256 + t], ogL[(size_t)g*256 + t]);
  float tg = blkSum(ogv * v[t], red);
  unsigned s0 = gs[g], e0 = geb[g];
  float mx = -INFINITY;
  for (unsigned n = s0 + t; n < e0; n += 256) mx = fmaxf(mx, lreluf(asrc[n] + tg));
  mx = blkMax(mx, red);
  float sm = 0.f;
  for (unsigned n = s0 + t; n < e0; n += 256) sm += expf(lreluf(asrc[n] + tg) - mx);
  sm = blkSum(sm, red);
  float acc = 0.f;
  if (e0 > s0 && sm > 0.f){
    float inv = 1.f / sm;
    for (unsigned n = s0; n < e0; ++n){
      float w = expf(lreluf(asrc[n] + tg) - mx) * inv;
      acc = fmaf(w, h2f(xwB[(size_t)n*256 + t]), acc);
    }
  }
  float h0 = acc + bias[t];
  h0 = h0 > 0.f ? h0 : expf(h0) - 1.f;
  unsigned short h, l; split2(h0, h, l);
  hgH[(size_t)g*256 + t] = h;
  hgL[(size_t)g*256 + t] = l;
}

// ---------------- launcher ----------------
extern "C" void kernel_launch(void* const* d_in, const int* in_sizes, int n_in,
                              void* d_out, int out_size, void* d_ws, size_t ws_size,
                              hipStream_t stream)
{
  (void)n_in; (void)ws_size;
  const int H    = in_sizes[3];          // 256
  const int NIN  = in_sizes[2] / H;      // 300
  const int N    = in_sizes[0] / NIN;    // 100000
  const int E    = in_sizes[1];          // 400000
  const int NL   = in_sizes[16] / H;     // 3
  const int NHID = in_sizes[30];         // 512
  const int NOUT = in_sizes[32];         // 768
  const int G    = out_size / NOUT;      // 2048
  const int T    = 16;

  const float* x_in     = (const float*)d_in[0];
  const float* ea_in    = (const float*)d_in[1];
  const float* lin1_W   = (const float*)d_in[2];
  const float* lin1_b   = (const float*)d_in[3];
  const float* g_lin1W  = (const float*)d_in[4];
  const float* g_lin2W  = (const float*)d_in[5];
  const float* g_att_l  = (const float*)d_in[6];
  const float* g_att_r  = (const float*)d_in[7];
  const float* g_bias   = (const float*)d_in[8];
  const float* gru0_wih = (const float*)d_in[9];
  const float* gru0_whh = (const float*)d_in[10];
  const float* gru0_bih = (const float*)d_in[11];
  const float* gru0_bhh = (const float*)d_in[12];
  const float* atom_W   = (const float*)d_in[13];
  const float* atom_as  = (const float*)d_in[14];
  const float* atom_ad  = (const float*)d_in[15];
  const float* atom_b   = (const float*)d_in[16];
  const float* agru_wih = (const float*)d_in[17];
  const float* agru_whh = (const float*)d_in[18];
  const float* agru_bih = (const float*)d_in[19];
  const float* agru_bhh = (const float*)d_in[20];
  const float* mol_W    = (const float*)d_in[21];
  const float* mol_as   = (const float*)d_in[22];
  const float* mol_ad   = (const float*)d_in[23];
  const float* mol_b    = (const float*)d_in[24];
  const float* mgru_wih = (const float*)d_in[25];
  const float* mgru_whh = (const float*)d_in[26];
  const float* mgru_bih = (const float*)d_in[27];
  const float* mgru_bhh = (const float*)d_in[28];
  const float* lin2_W   = (const float*)d_in[29];
  const float* lin2_b   = (const float*)d_in[30];
  const float* fc1_W    = (const float*)d_in[31];
  const float* fc1_b    = (const float*)d_in[32];
  const int*  eidx      = (const int*)d_in[33];
  const int*  batch     = (const int*)d_in[34];
  const int*  srcI = eidx;
  const int*  dstI = eidx + E;

  char* wp = (char*)d_ws;
  auto alloc = [&](size_t bytes)->void*{
    void* p = (void*)wp;
    wp += (bytes + 255) & ~(size_t)255;
    return p;
  };
  auto allocUS = [&](size_t elems)->unsigned short*{ return (unsigned short*)alloc(elems*2); };

  // activation buffers: 3 split pairs + 1 single fp16 message buffer
  unsigned short *xH   = allocUS((size_t)N*H), *xL   = allocUS((size_t)N*H);
  unsigned short *hbH  = allocUS((size_t)N*H), *hbL  = allocUS((size_t)N*H);
  unsigned short *outH = allocUS((size_t)N*H), *outL = allocUS((size_t)N*H);
  unsigned short *xwB  = allocUS((size_t)N*H);
  float*    ea    = (float*)alloc((size_t)E*4);       // CSR-ordered scores/weights
  float*    nd1   = (float*)alloc((size_t)N*4);
  float*    nd2   = (float*)alloc((size_t)N*4);
  unsigned short *ogH  = allocUS((size_t)G*H), *ogL  = allocUS((size_t)G*H);
  unsigned short *og2H = allocUS((size_t)G*H), *og2L = allocUS((size_t)G*H);
  unsigned short *hgH  = allocUS((size_t)G*H), *hgL  = allocUS((size_t)G*H);
  unsigned short *o2H  = allocUS((size_t)G*NHID), *o2L = allocUS((size_t)G*NHID);
  unsigned* gsb   = (unsigned*)alloc((size_t)G*4);
  unsigned* geb   = (unsigned*)alloc((size_t)G*4);
  float*    vvec  = (float*)alloc((size_t)H*4);
  // CSR/CSC structures
  const int nb = (N + 255) / 256;
  unsigned* deg     = (unsigned*)alloc((size_t)N*4);
  unsigned* cur     = (unsigned*)alloc((size_t)N*4);
  unsigned* incl    = (unsigned*)alloc((size_t)N*4);
  unsigned* off     = (unsigned*)alloc((size_t)(N+1)*4);
  unsigned* off2    = (unsigned*)alloc((size_t)(N+1)*4);
  unsigned* bsum    = (unsigned*)alloc((size_t)nb*4);
  int*      csr_src = (int*)alloc((size_t)E*4);
  int*      csr_eid = (int*)alloc((size_t)E*4);
  int*      epos    = (int*)alloc((size_t)E*4);
  int*      csc_pos = (int*)alloc((size_t)E*4);
  // pre-split weight buffers
  const size_t WG = (size_t)768*256;   // one GRU weight matrix
  const size_t WS = (size_t)256*256;   // one square GAT weight
  unsigned short *g0ihH = allocUS(WG), *g0ihL = allocUS(WG);
  unsigned short *g0hhH = allocUS(WG), *g0hhL = allocUS(WG);
  unsigned short *aihH  = allocUS(WG*NL), *aihL = allocUS(WG*NL);
  unsigned short *ahhH  = allocUS(WG*NL), *ahhL = allocUS(WG*NL);
  unsigned short *mihH  = allocUS(WG), *mihL = allocUS(WG);
  unsigned short *mhhH  = allocUS(WG), *mhhL = allocUS(WG);
  unsigned short *gl1H  = allocUS(WS), *gl1L = allocUS(WS);
  unsigned short *gl2H  = allocUS(WS), *gl2L = allocUS(WS);
  unsigned short *atWH  = allocUS(WS*NL), *atWL = allocUS(WS*NL);
  unsigned short *molH  = allocUS(WS), *molL = allocUS(WS);
  unsigned short *l2WH  = allocUS((size_t)NHID*256), *l2WL = allocUS((size_t)NHID*256);
  unsigned short *f1WH  = allocUS((size_t)NOUT*NHID), *f1WL = allocUS((size_t)NOUT*NHID);

  auto gemmps = [&](const unsigned short* AH_, const unsigned short* AL_,
                    const unsigned short* WH_, const unsigned short* WL_,
                    const float* bias, float* C, unsigned short* CH, unsigned short* CL,
                    int M_, int N_, int K_, int op){
    int ncb = N_ / 64;
    int nwg = ((M_ + 63)/64) * ncb;
    gemm_ps_k<<<dim3(nwg), dim3(256), 0, stream>>>(AH_, AL_, WH_, WL_, bias, C, CH, CL,
                                                   M_, N_, K_, op, ncb);
  };
  auto grup = [&](const unsigned short* XiH, const unsigned short* XiL,
                  const unsigned short* HiH, const unsigned short* HiL,
                  const unsigned short* ihH, const unsigned short* ihL,
                  const unsigned short* hhH, const unsigned short* hhL,
                  const float* bih, const float* bhh,
                  unsigned short* OH, unsigned short* OL, int M_){
    int nwg = ((M_ + 63)/64)*4;
    gru_ps_k<<<dim3(nwg), dim3(256), 0, stream>>>(XiH, XiL, HiH, HiL,
                                                  ihH, ihL, hhH, hhL, bih, bhh,
                                                  OH, OL, M_);
  };
  auto wsplit = [&](const float* src, unsigned short* Hd, unsigned short* Ld,
                    int lda, int K, long long rows){
    long long tot = rows * K;
    wsplit_k<<<dim3((unsigned)((tot + 255)/256)), dim3(256), 0, stream>>>(src, Hd, Ld, lda, K, tot);
  };

  // ---- pre-split all weights
  wsplit(gru0_wih, g0ihH, g0ihL, 256, 256, 768);
  wsplit(gru0_whh, g0hhH, g0hhL, 256, 256, 768);
  wsplit(agru_wih, aihH, aihL, 256, 256, (long long)NL*768);
  wsplit(agru_whh, ahhH, ahhL, 256, 256, (long long)NL*768);
  wsplit(mgru_wih, mihH, mihL, 256, 256, 768);
  wsplit(mgru_whh, mhhH, mhhL, 256, 256, 768);
  wsplit(g_lin1W,  gl1H, gl1L, H+1, 256, 256);
  wsplit(g_lin2W,  gl2H, gl2L, 256, 256, 256);
  wsplit(atom_W,   atWH, atWL, 256, 256, (long long)NL*256);
  wsplit(mol_W,    molH, molL, 256, 256, 256);
  wsplit(lin2_W,   l2WH, l2WL, 256, 256, NHID);
  wsplit(fc1_W,    f1WH, f1WL, NHID, NHID, NOUT);

  // ---- build dst-CSR (incoming edges) + src-CSC (outgoing, payload = CSR position)
  hipMemsetAsync(deg, 0, (size_t)N*4, stream);
  hist_k<<<dim3((E+255)/256), dim3(256), 0, stream>>>(dstI, deg, E);
  scan1_k<<<dim3(nb), dim3(256), 0, stream>>>(deg, incl, bsum, N);
  scan2_k<<<dim3(1), dim3(256), 0, stream>>>(bsum, nb);
  scan3_k<<<dim3(nb), dim3(256), 0, stream>>>(incl, deg, bsum, off, N, E);
  hipMemsetAsync(cur, 0, (size_t)N*4, stream);
  fill_k<<<dim3((E+255)/256), dim3(256), 0, stream>>>(srcI, dstI, off, cur, csr_src, csr_eid, epos, E);
  hipMemsetAsync(deg, 0, (size_t)N*4, stream);
  hist_k<<<dim3((E+255)/256), dim3(256), 0, stream>>>(srcI, deg, E);
  scan1_k<<<dim3(nb), dim3(256), 0, stream>>>(deg, incl, bsum, N);
  scan2_k<<<dim3(1), dim3(256), 0, stream>>>(bsum, nb);
  scan3_k<<<dim3(nb), dim3(256), 0, stream>>>(incl, deg, bsum, off2, N, E);
  hipMemsetAsync(cur, 0, (size_t)N*4, stream);
  fill2_k<<<dim3((E+255)/256), dim3(256), 0, stream>>>(srcI, epos, off2, cur, csc_pos, E);

  // ---- input projection (K=300, f32 path) -> x split
  {
    dim3 gr(4, (N + 63)/64);
    gemm_mfma_k<<<gr, dim3(256), 0, stream>>>(x_in, NIN, lin1_W, NIN, lin1_b,
                                              xH, xL, N, H, NIN, OP_LRELU);
  }

  // ---- GATEConv: Y -> outH (scratch fp16, dead before GRU writes), Z -> xwB (fp16)
  {
    int nwg = ((N + 63)/64)*4;
    gemm2_ps_k<<<dim3(nwg), dim3(256), 0, stream>>>(xH, xL, gl1H, gl1L, gl2H, gl2L,
                                                    outH, xwB, N);
  }
  rowdot2_ps_k<<<dim3((N+3)/4), dim3(256), 0, stream>>>(xH, xL, g_att_r, (const float*)nullptr,
                                                        nd1, (float*)nullptr, N);
  gate_edge_score_csc_k<<<dim3((N+3)/4), dim3(256), 0, stream>>>(outH, g_lin1W, g_att_l,
                                                                 ea_in, nd1, off2, csc_pos,
                                                                 csr_eid, dstI, ea, N, H);
  node_softmax_k<<<dim3(nb), dim3(256), 0, stream>>>(off, csr_src, nullptr, nullptr, ea, N, 0);
  gather_h_k<<<dim3((N+3)/4), dim3(256), 0, stream>>>(xwB, ea, off, csr_src, g_bias,
                                                      hbH, hbL, N);
  grup(hbH, hbL, xH, xL, g0ihH, g0ihL, g0hhH, g0hhL, gru0_bih, gru0_bhh, outH, outL, N);
  { unsigned short* t = xH; xH = outH; outH = t; t = xL; xL = outL; outL = t; }

  // ---- atom GATConv layers
  for (int l = 0; l < NL; ++l){
    gemmps(xH, xL, atWH + (size_t)l*WS, atWL + (size_t)l*WS, nullptr,
           nullptr, xwB, nullptr, N, 256, 256, OP_NONE);           // xw -> fp16 single
    rowdot_b_k<<<dim3((N+3)/4), dim3(256), 0, stream>>>(xwB, atom_as + (size_t)l*H,
                                                        atom_ad + (size_t)l*H, nd1, nd2, N);
    node_softmax_k<<<dim3(nb), dim3(256), 0, stream>>>(off, csr_src, nd1, nd2, ea, N, 1);
    gather_h_k<<<dim3((N+3)/4), dim3(256), 0, stream>>>(xwB, ea, off, csr_src,
                                                        atom_b + (size_t)l*H, hbH, hbL, N);
    grup(hbH, hbL, xH, xL,
         aihH + (size_t)l*WG, aihL + (size_t)l*WG,
         ahhH + (size_t)l*WG, ahhL + (size_t)l*WG,
         agru_bih + (size_t)l*3*H, agru_bhh + (size_t)l*3*H, outH, outL, N);
    { unsigned short* t = xH; xH = outH; outH = t; t = xL; xL = outL; outL = t; }
  }

  // ---- attentive pooling
  hipMemsetAsync(gsb, 0xFF, (size_t)G*4, stream);
  hipMemsetAsync(geb, 0x00, (size_t)G*4, stream);
  seg_bounds_k<<<dim3((N+255)/256), dim3(256), 0, stream>>>(batch, gsb, geb, N);
  graph_pool_k<<<dim3(G), dim3(256), 0, stream>>>(xH, xL, gsb, geb, ogH, ogL);
  gemmps(xH, xL, molH, molL, nullptr, nullptr, xwB, nullptr, N, 256, 256, OP_NONE); // xw fp16
  rowdot_b_k<<<dim3((N+3)/4), dim3(256), 0, stream>>>(xwB, mol_as, (const float*)nullptr,
                                                      nd1, (float*)nullptr, N);
  precompute_v_k<<<dim3(1), dim3(256), 0, stream>>>(mol_W, mol_ad, vvec);
  unsigned short *cogH = ogH, *cogL = ogL, *cog2H = og2H, *cog2L = og2L;
  for (int t = 0; t < T; ++t){
    mol_pool_k<<<dim3(G), dim3(256), 0, stream>>>(cogH, cogL, vvec, nd1, xwB,
                                                  gsb, geb, mol_b, hgH, hgL);
    grup(hgH, hgL, cogH, cogL, mihH, mihL, mhhH, mhhL, mgru_bih, mgru_bhh,
         cog2H, cog2L, G);
    { unsigned short* tt = cogH; cogH = cog2H; cog2H = tt;
      tt = cogL; cogL = cog2L; cog2L = tt; }
  }

  // ---- head: lin2 (relu, split out) then fc1 (f32 out to d_out)
  gemmps(cogH, cogL, l2WH, l2WL, lin2_b, nullptr, o2H, o2L, G, NHID, 256, OP_RELU);
  gemmps(o2H, o2L, f1WH, f1WL, fc1_b, (float*)d_out, nullptr, nullptr, G, NOUT, NHID, OP_NONE);
}

// Round 13
// 3209.850 us; speedup vs baseline: 1.9874x; 1.1391x over previous
//
#include <hip/hip_runtime.h>
#include <math.h>

typedef __attribute__((ext_vector_type(8))) _Float16        half8;
typedef __attribute__((ext_vector_type(8))) unsigned short  ushort8;
typedef __attribute__((ext_vector_type(4))) unsigned short  us4;
typedef __attribute__((ext_vector_type(4))) float           f32x4;

__device__ __forceinline__ float lreluf(float v){ return v >= 0.f ? v : 0.01f*v; }
__device__ __forceinline__ float sigf(float v){ return 1.f/(1.f + expf(-v)); }

#define OP_NONE  0
#define OP_LRELU 1
#define OP_RELU  2

// async global->LDS, 16B per lane, dest = wave-uniform base + lane*16
#define GLDS16(gp, lp) __builtin_amdgcn_global_load_lds( \
    (const __attribute__((address_space(1))) void*)(gp), \
    (__attribute__((address_space(3))) void*)(lp), 16, 0, 0)

__device__ __forceinline__ float applyOp(float v, int op){
  if (op == OP_LRELU) return v >= 0.f ? v : 0.01f*v;
  if (op == OP_RELU)  return v > 0.f ? v : 0.f;
  return v;
}

// fp16 <-> f32 (RNE)
__device__ __forceinline__ unsigned short f2h(float f){
  _Float16 h = (_Float16)f;
  return *(unsigned short*)&h;
}
__device__ __forceinline__ float h2f(unsigned short u){
  _Float16 h = *(_Float16*)&u;
  return (float)h;
}
__device__ __forceinline__ void split2h(float v, unsigned short& h, unsigned short& l){
  h = f2h(v);
  l = f2h(v - h2f(h));
}
__device__ __forceinline__ float rec2h(unsigned short h, unsigned short l){
  return h2f(h) + h2f(l);
}

// LDS tile [64][32] fp16 (4KB), 16B-chunk XOR swizzle: 4 chunks/row
__device__ __forceinline__ int ldsOff32(int row, int chunk){
  return row*32 + ((chunk ^ ((row >> 1) & 3)) << 3);
}
// LDS tile [64][64] fp16 (8KB), 8 chunks/row (head GEMMs)
__device__ __forceinline__ int ldsOff64(int row, int chunk){
  return row*64 + ((chunk ^ ((row >> 1) & 7)) << 3);
}

__device__ __forceinline__ float blkSum(float v, float* red){
  int t = threadIdx.x;
  red[t] = v; __syncthreads();
  for (int s = 128; s > 0; s >>= 1){ if (t < s) red[t] += red[t+s]; __syncthreads(); }
  float r = red[0]; __syncthreads();
  return r;
}
__device__ __forceinline__ float blkMax(float v, float* red){
  int t = threadIdx.x;
  red[t] = v; __syncthreads();
  for (int s = 128; s > 0; s >>= 1){ if (t < s) red[t] = fmaxf(red[t], red[t+s]); __syncthreads(); }
  float r = red[0]; __syncthreads();
  return r;
}

__device__ __forceinline__ f32x4 mfma16(half8 a, half8 b, f32x4 acc){
  return __builtin_amdgcn_mfma_f32_16x16x32_f16(a, b, acc, 0, 0, 0);
}

// ================= weight pre-split: fp16 pair, error ~2^-22 =================
__global__ void wsplit16_k(const float* __restrict__ src, unsigned short* __restrict__ Hd,
                           unsigned short* __restrict__ Ld, int lda, int K, long long tot)
{
  long long i = (long long)blockIdx.x*256 + threadIdx.x;
  if (i >= tot) return;
  long long r = i / K; int c = (int)(i % K);
  float v = src[r*lda + c];
  unsigned short h, l; split2h(v, h, l);
  Hd[r*(long long)K + c] = h;
  Ld[r*(long long)K + c] = l;
}

// ---- async-stage [64][32] fp16 tile -> swizzled LDS (1 pass). Rows clamped. ----
__device__ __forceinline__ void stage16b(const unsigned short* __restrict__ G,
    int ldk, int row0, int rowmax, int k0, unsigned short* __restrict__ lds, int tid)
{
  int r = tid >> 2;
  int gr = row0 + r; if (gr >= rowmax) gr = rowmax - 1;
  int c = (tid & 3) ^ ((r >> 1) & 3);
  size_t go = (size_t)gr*ldk + k0 + c*8;
  int wbase = (tid >> 6) * 512;
  GLDS16(&G[go], &lds[wbase]);
}
// ---- async-stage [64][64] fp16 tile -> swizzled LDS (2 passes). Rows clamped. ----
__device__ __forceinline__ void stage16(const unsigned short* __restrict__ G,
    int ldk, int row0, int rowmax, int k0, unsigned short* __restrict__ lds, int tid)
{
  #pragma unroll
  for (int p = 0; p < 2; ++p){
    int r = p*32 + (tid >> 3);
    int gr = row0 + r; if (gr >= rowmax) gr = rowmax - 1;
    int c = (tid & 7) ^ ((r >> 1) & 7);
    size_t go = (size_t)gr*ldk + k0 + c*8;
    int wbase = p*2048 + (tid >> 6)*512;
    GLDS16(&G[go], &lds[wbase]);
  }
}

// ---- stage 64x32 f32 tile -> split fp16 H/L LDS (swizzled, bounds-checked). lin1 ----
__device__ __forceinline__ void stage_f32s(const float* __restrict__ src, int lda,
    int row0, int rowmax, int k0, int K,
    unsigned short* __restrict__ ldsH, unsigned short* __restrict__ ldsL, int tid)
{
  int r = tid >> 2, c = tid & 3;
  int gr = row0 + r, gk = k0 + c*8;
  const float* p = src + (size_t)gr*lda + gk;
  float f[8];
  if (gr < rowmax && gk + 8 <= K && ((lda & 3) == 0)){
    float4 f0 = *(const float4*)p;
    float4 f1 = *(const float4*)(p+4);
    f[0]=f0.x; f[1]=f0.y; f[2]=f0.z; f[3]=f0.w;
    f[4]=f1.x; f[5]=f1.y; f[6]=f1.z; f[7]=f1.w;
  } else {
    #pragma unroll
    for (int j = 0; j < 8; ++j) f[j] = (gr < rowmax && gk + j < K) ? p[j] : 0.f;
  }
  ushort8 vh, vl;
  #pragma unroll
  for (int j = 0; j < 8; ++j){
    unsigned short h, l; split2h(f[j], h, l);
    vh[j] = h; vl[j] = l;
  }
  int off = ldsOff32(r, c);
  *(ushort8*)&ldsH[off] = vh;
  *(ushort8*)&ldsL[off] = vl;
}

// ---------------- lin1 GEMM (f32 inputs, generic K, split x split, 3-prod): fp16 out ----------------
__global__ __launch_bounds__(256) void gemm_l1_k(
    const float* __restrict__ A, int lda,
    const float* __restrict__ W, int ldw,
    const float* __restrict__ bias,
    unsigned short* __restrict__ CB,
    int M, int N, int K, int op)
{
  __shared__ unsigned short AsH[2048], AsL[2048];
  __shared__ unsigned short WsH[2048], WsL[2048];
  const int tid = threadIdx.x;
  const int bm = blockIdx.y * 64, bn = blockIdx.x * 64;
  const int wave = tid >> 6, lane = tid & 63;
  const int wr = wave >> 1, wc = wave & 1;
  const int quad = lane >> 4, id = lane & 15;

  f32x4 acc[2][2] = {};
  const int iters = (K + 31) / 32;
  for (int kt = 0; kt < iters; ++kt){
    int k0 = kt * 32;
    stage_f32s(A, lda, bm, M, k0, K, AsH, AsL, tid);
    stage_f32s(W, ldw, bn, N, k0, K, WsH, WsL, tid);
    __syncthreads();
    half8 aH[2], aL[2], bH[2], bL[2];
    #pragma unroll
    for (int i = 0; i < 2; ++i){
      int off = ldsOff32(wr*32 + i*16 + id, quad);
      aH[i] = *(const half8*)&AsH[off];
      aL[i] = *(const half8*)&AsL[off];
    }
    #pragma unroll
    for (int j = 0; j < 2; ++j){
      int off = ldsOff32(wc*32 + j*16 + id, quad);
      bH[j] = *(const half8*)&WsH[off];
      bL[j] = *(const half8*)&WsL[off];
    }
    #pragma unroll
    for (int i = 0; i < 2; ++i)
      #pragma unroll
      for (int j = 0; j < 2; ++j){
        acc[i][j] = mfma16(aH[i], bH[j], acc[i][j]);
        acc[i][j] = mfma16(aL[i], bH[j], acc[i][j]);
        acc[i][j] = mfma16(aH[i], bL[j], acc[i][j]);
      }
    __syncthreads();
  }
  #pragma unroll
  for (int i = 0; i < 2; ++i){
    int gr0 = bm + wr*32 + i*16 + quad*4;
    #pragma unroll
    for (int j = 0; j < 2; ++j){
      int gc = bn + wc*32 + j*16 + id;
      if (gc >= N) continue;
      float bv = bias ? bias[gc] : 0.f;
      #pragma unroll
      for (int r = 0; r < 4; ++r){
        int row = gr0 + r;
        if (row >= M) continue;
        CB[(size_t)row*N + gc] = f2h(applyOp(acc[i][j][r] + bv, op));
      }
    }
  }
}

// ---------------- node GEMM: A single x W pair (2-prod), BK=32, fp16 out ----------------
__global__ __launch_bounds__(256) void gemm16s_k(
    const unsigned short* __restrict__ A,
    const unsigned short* __restrict__ WH_, const unsigned short* __restrict__ WL_,
    unsigned short* __restrict__ CB, int M)
{
  __shared__ unsigned short As[2048];
  __shared__ unsigned short WsH[2048], WsL[2048];
  int nwg = gridDim.x, bid = blockIdx.x;
  int q = nwg >> 3, r = nwg & 7;
  int xcd = bid & 7, jj = bid >> 3;
  int idx = (xcd < r ? xcd*(q+1) : r*(q+1) + (xcd - r)*q) + jj;
  const int bm = (idx >> 2)*64, bn = (idx & 3)*64;
  const int tid = threadIdx.x;
  const int wave = tid >> 6, lane = tid & 63;
  const int wr = wave >> 1, wc = wave & 1;
  const int quad = lane >> 4, id = lane & 15;

  f32x4 acc[2][2] = {};
  for (int kt = 0; kt < 8; ++kt){
    int k0 = kt * 32;
    stage16b(A, 256, bm, M, k0, As, tid);
    stage16b(WH_, 256, bn, 256, k0, WsH, tid);
    stage16b(WL_, 256, bn, 256, k0, WsL, tid);
    __syncthreads();
    half8 a[2];
    #pragma unroll
    for (int i = 0; i < 2; ++i)
      a[i] = *(const half8*)&As[ldsOff32(wr*32 + i*16 + id, quad)];
    #pragma unroll
    for (int j = 0; j < 2; ++j){
      int off = ldsOff32(wc*32 + j*16 + id, quad);
      half8 bh = *(const half8*)&WsH[off];
      half8 bl = *(const half8*)&WsL[off];
      #pragma unroll
      for (int i = 0; i < 2; ++i){
        acc[i][j] = mfma16(a[i], bh, acc[i][j]);
        acc[i][j] = mfma16(a[i], bl, acc[i][j]);
      }
    }
    __syncthreads();
  }
  #pragma unroll
  for (int i = 0; i < 2; ++i){
    int gr0 = bm + wr*32 + i*16 + quad*4;
    #pragma unroll
    for (int j = 0; j < 2; ++j){
      int gc = bn + wc*32 + j*16 + id;
      #pragma unroll
      for (int rr = 0; rr < 4; ++rr){
        int row = gr0 + rr;
        if (row < M) CB[(size_t)row*256 + gc] = f2h(acc[i][j][rr]);
      }
    }
  }
}

// ---------------- fused dual GEMM (GATEConv): A single x {W1,W2} pairs, fp16 out ----------------
__global__ __launch_bounds__(256) void gemm2s_k(
    const unsigned short* __restrict__ A,
    const unsigned short* __restrict__ W1H, const unsigned short* __restrict__ W1L,
    const unsigned short* __restrict__ W2H, const unsigned short* __restrict__ W2L,
    unsigned short* __restrict__ YB, unsigned short* __restrict__ ZB, int M)
{
  __shared__ unsigned short As[2048];
  __shared__ unsigned short U1H[2048], U1L[2048], U2H[2048], U2L[2048];
  int nwg = gridDim.x, bid = blockIdx.x;
  int q = nwg >> 3, r = nwg & 7;
  int xcd = bid & 7, jj = bid >> 3;
  int idx = (xcd < r ? xcd*(q+1) : r*(q+1) + (xcd - r)*q) + jj;
  const int bm = (idx >> 2)*64, bn = (idx & 3)*64;
  const int tid = threadIdx.x;
  const int wave = tid >> 6, lane = tid & 63;
  const int wr = wave >> 1, wc = wave & 1;
  const int quad = lane >> 4, id = lane & 15;

  f32x4 acc1[2][2] = {}, acc2[2][2] = {};
  for (int kt = 0; kt < 8; ++kt){
    int k0 = kt * 32;
    stage16b(A, 256, bm, M, k0, As, tid);
    stage16b(W1H, 256, bn, 256, k0, U1H, tid);
    stage16b(W1L, 256, bn, 256, k0, U1L, tid);
    stage16b(W2H, 256, bn, 256, k0, U2H, tid);
    stage16b(W2L, 256, bn, 256, k0, U2L, tid);
    __syncthreads();
    half8 a[2];
    #pragma unroll
    for (int i = 0; i < 2; ++i)
      a[i] = *(const half8*)&As[ldsOff32(wr*32 + i*16 + id, quad)];
    #pragma unroll
    for (int j = 0; j < 2; ++j){
      int off = ldsOff32(wc*32 + j*16 + id, quad);
      half8 b1h = *(const half8*)&U1H[off];
      half8 b1l = *(const half8*)&U1L[off];
      half8 b2h = *(const half8*)&U2H[off];
      half8 b2l = *(const half8*)&U2L[off];
      #pragma unroll
      for (int i = 0; i < 2; ++i){
        acc1[i][j] = mfma16(a[i], b1h, acc1[i][j]);
        acc1[i][j] = mfma16(a[i], b1l, acc1[i][j]);
        acc2[i][j] = mfma16(a[i], b2h, acc2[i][j]);
        acc2[i][j] = mfma16(a[i], b2l, acc2[i][j]);
      }
    }
    __syncthreads();
  }
  #pragma unroll
  for (int i = 0; i < 2; ++i){
    int gr0 = bm + wr*32 + i*16 + quad*4;
    #pragma unroll
    for (int j = 0; j < 2; ++j){
      int gc = bn + wc*32 + j*16 + id;
      #pragma unroll
      for (int rr = 0; rr < 4; ++rr){
        int row = gr0 + rr;
        if (row >= M) continue;
        YB[(size_t)row*256 + gc] = f2h(acc1[i][j][rr]);
        ZB[(size_t)row*256 + gc] = f2h(acc2[i][j][rr]);
      }
    }
  }
}

// ---------------- node GRU: A single x W pairs (2-prod), BK=32, 28KB LDS ----------------
__device__ __forceinline__ void gru_phase_s(
    const unsigned short* __restrict__ A,
    const unsigned short* __restrict__ WH, const unsigned short* __restrict__ WL,
    int M, int bm, int bn, int tid, int wr, int wc, int quad, int id,
    unsigned short* As,
    unsigned short* W0H, unsigned short* W0L,
    unsigned short* W1H, unsigned short* W1L,
    unsigned short* W2H, unsigned short* W2L,
    f32x4 (&accR)[2][2], f32x4 (&accZ)[2][2], f32x4 (&accN)[2][2])
{
  for (int kt = 0; kt < 8; ++kt){
    int k0 = kt * 32;
    stage16b(A, 256, bm, M, k0, As, tid);
    stage16b(WH,          256, bn, 256, k0, W0H, tid);
    stage16b(WL,          256, bn, 256, k0, W0L, tid);
    stage16b(WH + 65536,  256, bn, 256, k0, W1H, tid);
    stage16b(WL + 65536,  256, bn, 256, k0, W1L, tid);
    stage16b(WH + 131072, 256, bn, 256, k0, W2H, tid);
    stage16b(WL + 131072, 256, bn, 256, k0, W2L, tid);
    __syncthreads();
    half8 a[2];
    #pragma unroll
    for (int i = 0; i < 2; ++i)
      a[i] = *(const half8*)&As[ldsOff32(wr*32 + i*16 + id, quad)];
    #pragma unroll
    for (int j = 0; j < 2; ++j){
      int off = ldsOff32(wc*32 + j*16 + id, quad);
      half8 bh, bl;
      bh = *(const half8*)&W0H[off]; bl = *(const half8*)&W0L[off];
      #pragma unroll
      for (int i = 0; i < 2; ++i){
        accR[i][j] = mfma16(a[i], bh, accR[i][j]);
        accR[i][j] = mfma16(a[i], bl, accR[i][j]);
      }
      bh = *(const half8*)&W1H[off]; bl = *(const half8*)&W1L[off];
      #pragma unroll
      for (int i = 0; i < 2; ++i){
        accZ[i][j] = mfma16(a[i], bh, accZ[i][j]);
        accZ[i][j] = mfma16(a[i], bl, accZ[i][j]);
      }
      bh = *(const half8*)&W2H[off]; bl = *(const half8*)&W2L[off];
      #pragma unroll
      for (int i = 0; i < 2; ++i){
        accN[i][j] = mfma16(a[i], bh, accN[i][j]);
        accN[i][j] = mfma16(a[i], bl, accN[i][j]);
      }
    }
    __syncthreads();
  }
}

__global__ __launch_bounds__(256) void gru16_k(
    const unsigned short* __restrict__ Xin, const unsigned short* __restrict__ Hid,
    const unsigned short* __restrict__ wihH, const unsigned short* __restrict__ wihL,
    const unsigned short* __restrict__ whhH, const unsigned short* __restrict__ whhL,
    const float* __restrict__ bih, const float* __restrict__ bhh,
    unsigned short* __restrict__ Out, int M)
{
  __shared__ unsigned short As[2048];
  __shared__ unsigned short W0H[2048], W0L[2048];
  __shared__ unsigned short W1H[2048], W1L[2048];
  __shared__ unsigned short W2H[2048], W2L[2048];
  int nwg = gridDim.x, bid = blockIdx.x;
  int q = nwg >> 3, r = nwg & 7;
  int xcd = bid & 7, jj = bid >> 3;
  int idx = (xcd < r ? xcd*(q+1) : r*(q+1) + (xcd - r)*q) + jj;
  const int bm = (idx >> 2)*64, bn = (idx & 3)*64;
  const int tid = threadIdx.x;
  const int wave = tid >> 6, lane = tid & 63;
  const int wr = wave >> 1, wc = wave & 1;
  const int quad = lane >> 4, id = lane & 15;

  f32x4 accR[2][2] = {}, accZ[2][2] = {}, accI[2][2] = {}, accH[2][2] = {};

  gru_phase_s(Xin, wihH, wihL, M, bm, bn, tid, wr, wc, quad, id,
              As, W0H, W0L, W1H, W1L, W2H, W2L, accR, accZ, accI);
  gru_phase_s(Hid, whhH, whhL, M, bm, bn, tid, wr, wc, quad, id,
              As, W0H, W0L, W1H, W1L, W2H, W2L, accR, accZ, accH);

  #pragma unroll
  for (int i = 0; i < 2; ++i){
    int gr0 = bm + wr*32 + i*16 + quad*4;
    #pragma unroll
    for (int j = 0; j < 2; ++j){
      int gc = bn + wc*32 + j*16 + id;
      float br_  = bih[gc]     + bhh[gc];
      float bz_  = bih[256+gc] + bhh[256+gc];
      float bn_i = bih[512+gc], bn_h = bhh[512+gc];
      #pragma unroll
      for (int rr = 0; rr < 4; ++rr){
        int row = gr0 + rr;
        if (row >= M) continue;
        float rg = sigf(accR[i][j][rr] + br_);
        float zg = sigf(accZ[i][j][rr] + bz_);
        float ng = tanhf(accI[i][j][rr] + bn_i + rg*(accH[i][j][rr] + bn_h));
        float hv = h2f(Hid[(size_t)row*256 + gc]);
        float o = (1.f - zg)*ng + zg*hv;
        o = o > 0.f ? o : 0.f;
        Out[(size_t)row*256 + gc] = f2h(o);
      }
    }
  }
}

// ---------------- mol GRU: A pair x W pair (3-prod), BK=32 (G tiny; accuracy-first) ----------------
__device__ __forceinline__ void gru_phase16m(
    const unsigned short* __restrict__ AH, const unsigned short* __restrict__ AL,
    const unsigned short* __restrict__ WH, const unsigned short* __restrict__ WL,
    int M, int bm, int bn, int tid, int wr, int wc, int quad, int id,
    unsigned short* AsH, unsigned short* AsL,
    unsigned short* W0, unsigned short* W1, unsigned short* W2,
    unsigned short* W0L, unsigned short* W1L, unsigned short* W2L,
    f32x4 (&accR)[2][2], f32x4 (&accZ)[2][2], f32x4 (&accN)[2][2])
{
  for (int kt = 0; kt < 8; ++kt){
    int k0 = kt * 32;
    stage16b(AH, 256, bm, M, k0, AsH, tid);
    stage16b(AL, 256, bm, M, k0, AsL, tid);
    stage16b(WH,          256, bn, 256, k0, W0,  tid);
    stage16b(WH + 65536,  256, bn, 256, k0, W1,  tid);
    stage16b(WH + 131072, 256, bn, 256, k0, W2,  tid);
    stage16b(WL,          256, bn, 256, k0, W0L, tid);
    stage16b(WL + 65536,  256, bn, 256, k0, W1L, tid);
    stage16b(WL + 131072, 256, bn, 256, k0, W2L, tid);
    __syncthreads();
    half8 aH[2], aL[2];
    #pragma unroll
    for (int i = 0; i < 2; ++i){
      int off = ldsOff32(wr*32 + i*16 + id, quad);
      aH[i] = *(const half8*)&AsH[off];
      aL[i] = *(const half8*)&AsL[off];
    }
    #pragma unroll
    for (int j = 0; j < 2; ++j){
      int off = ldsOff32(wc*32 + j*16 + id, quad);
      half8 bh, bl;
      bh = *(const half8*)&W0[off]; bl = *(const half8*)&W0L[off];
      #pragma unroll
      for (int i = 0; i < 2; ++i){
        accR[i][j] = mfma16(aH[i], bh, accR[i][j]);
        accR[i][j] = mfma16(aL[i], bh, accR[i][j]);
        accR[i][j] = mfma16(aH[i], bl, accR[i][j]);
      }
      bh = *(const half8*)&W1[off]; bl = *(const half8*)&W1L[off];
      #pragma unroll
      for (int i = 0; i < 2; ++i){
        accZ[i][j] = mfma16(aH[i], bh, accZ[i][j]);
        accZ[i][j] = mfma16(aL[i], bh, accZ[i][j]);
        accZ[i][j] = mfma16(aH[i], bl, accZ[i][j]);
      }
      bh = *(const half8*)&W2[off]; bl = *(const half8*)&W2L[off];
      #pragma unroll
      for (int i = 0; i < 2; ++i){
        accN[i][j] = mfma16(aH[i], bh, accN[i][j]);
        accN[i][j] = mfma16(aL[i], bh, accN[i][j]);
        accN[i][j] = mfma16(aH[i], bl, accN[i][j]);
      }
    }
    __syncthreads();
  }
}

__global__ __launch_bounds__(256) void gru16m_k(
    const unsigned short* __restrict__ XinH, const unsigned short* __restrict__ XinL,
    const unsigned short* __restrict__ HidH, const unsigned short* __restrict__ HidL,
    const unsigned short* __restrict__ wihH, const unsigned short* __restrict__ wihL,
    const unsigned short* __restrict__ whhH, const unsigned short* __restrict__ whhL,
    const float* __restrict__ bih, const float* __restrict__ bhh,
    unsigned short* __restrict__ OutH, unsigned short* __restrict__ OutL, int M)
{
  __shared__ unsigned short AsH[2048], AsL[2048];
  __shared__ unsigned short W0[2048], W1[2048], W2[2048];
  __shared__ unsigned short W0L[2048], W1L[2048], W2L[2048];
  const int bm = (blockIdx.x >> 2)*64, bn = (blockIdx.x & 3)*64;
  const int tid = threadIdx.x;
  const int wave = tid >> 6, lane = tid & 63;
  const int wr = wave >> 1, wc = wave & 1;
  const int quad = lane >> 4, id = lane & 15;

  f32x4 accR[2][2] = {}, accZ[2][2] = {}, accI[2][2] = {}, accH[2][2] = {};

  gru_phase16m(XinH, XinL, wihH, wihL, M, bm, bn, tid, wr, wc, quad, id,
               AsH, AsL, W0, W1, W2, W0L, W1L, W2L, accR, accZ, accI);
  gru_phase16m(HidH, HidL, whhH, whhL, M, bm, bn, tid, wr, wc, quad, id,
               AsH, AsL, W0, W1, W2, W0L, W1L, W2L, accR, accZ, accH);

  #pragma unroll
  for (int i = 0; i < 2; ++i){
    int gr0 = bm + wr*32 + i*16 + quad*4;
    #pragma unroll
    for (int j = 0; j < 2; ++j){
      int gc = bn + wc*32 + j*16 + id;
      float br_  = bih[gc]     + bhh[gc];
      float bz_  = bih[256+gc] + bhh[256+gc];
      float bn_i = bih[512+gc], bn_h = bhh[512+gc];
      #pragma unroll
      for (int rr = 0; rr < 4; ++rr){
        int row = gr0 + rr;
        if (row >= M) continue;
        float rg = sigf(accR[i][j][rr] + br_);
        float zg = sigf(accZ[i][j][rr] + bz_);
        float ng = tanhf(accI[i][j][rr] + bn_i + rg*(accH[i][j][rr] + bn_h));
        float hv = rec2h(HidH[(size_t)row*256 + gc], HidL[(size_t)row*256 + gc]);
        float o = (1.f - zg)*ng + zg*hv;
        o = o > 0.f ? o : 0.f;
        unsigned short h, l; split2h(o, h, l);
        OutH[(size_t)row*256 + gc] = h;
        OutL[(size_t)row*256 + gc] = l;
      }
    }
  }
}

// ---------------- head GEMM: A pair x W pair (3-prod), BK=64 ----------------
__global__ __launch_bounds__(256) void gemm16p_k(
    const unsigned short* __restrict__ AH, const unsigned short* __restrict__ AL,
    const unsigned short* __restrict__ WH_, const unsigned short* __restrict__ WL_,
    const float* __restrict__ bias, float* __restrict__ C,
    unsigned short* __restrict__ CH, unsigned short* __restrict__ CL,
    int M, int N, int K, int op, int ncb)
{
  __shared__ unsigned short AsH[4096], AsL[4096];
  __shared__ unsigned short Ws[4096], WsL[4096];
  int nwg = gridDim.x, bid = blockIdx.x;
  int q = nwg >> 3, r = nwg & 7;
  int xcd = bid & 7, jj = bid >> 3;
  int idx = (xcd < r ? xcd*(q+1) : r*(q+1) + (xcd - r)*q) + jj;
  const int bm = (idx / ncb)*64, bn = (idx % ncb)*64;
  const int tid = threadIdx.x;
  const int wave = tid >> 6, lane = tid & 63;
  const int wr = wave >> 1, wc = wave & 1;
  const int quad = lane >> 4, id = lane & 15;

  f32x4 acc[2][2] = {};
  const int iters = K >> 6;
  for (int kt = 0; kt < iters; ++kt){
    int k0 = kt * 64;
    stage16(AH, K, bm, M, k0, AsH, tid);
    stage16(AL, K, bm, M, k0, AsL, tid);
    stage16(WH_, K, bn, N, k0, Ws, tid);
    stage16(WL_, K, bn, N, k0, WsL, tid);
    __syncthreads();
    #pragma unroll
    for (int kh = 0; kh < 2; ++kh){
      int ch = kh*4 + quad;
      half8 aH[2], aL[2];
      #pragma unroll
      for (int i = 0; i < 2; ++i){
        int off = ldsOff64(wr*32 + i*16 + id, ch);
        aH[i] = *(const half8*)&AsH[off];
        aL[i] = *(const half8*)&AsL[off];
      }
      #pragma unroll
      for (int j = 0; j < 2; ++j){
        int off = ldsOff64(wc*32 + j*16 + id, ch);
        half8 b = *(const half8*)&Ws[off];
        half8 bl = *(const half8*)&WsL[off];
        #pragma unroll
        for (int i = 0; i < 2; ++i){
          acc[i][j] = mfma16(aH[i], b, acc[i][j]);
          acc[i][j] = mfma16(aL[i], b, acc[i][j]);
          acc[i][j] = mfma16(aH[i], bl, acc[i][j]);
        }
      }
    }
    __syncthreads();
  }
  #pragma unroll
  for (int i = 0; i < 2; ++i){
    int gr0 = bm + wr*32 + i*16 + quad*4;
    #pragma unroll
    for (int j = 0; j < 2; ++j){
      int gc = bn + wc*32 + j*16 + id;
      float bv = bias ? bias[gc] : 0.f;
      #pragma unroll
      for (int rr = 0; rr < 4; ++rr){
        int row = gr0 + rr;
        if (row >= M) continue;
        float v = applyOp(acc[i][j][rr] + bv, op);
        if (C)  C[(size_t)row*N + gc] = v;
        if (CH){
          unsigned short h, l; split2h(v, h, l);
          CH[(size_t)row*N + gc] = h;
          CL[(size_t)row*N + gc] = l;
        }
      }
    }
  }
}

// ---------------- row dots over single fp16 buffer ----------------
__global__ __launch_bounds__(256) void rowdot_h_k(
    const unsigned short* __restrict__ XB,
    const float* __restrict__ w1, const float* __restrict__ w2,
    float* __restrict__ y1, float* __restrict__ y2, int M)
{
  int m = blockIdx.x*4 + (threadIdx.x >> 6);
  if (m >= M) return;
  int lane = threadIdx.x & 63;
  us4 vh = *(const us4*)&XB[(size_t)m*256 + lane*4];
  float p1 = 0.f, p2 = 0.f;
  #pragma unroll
  for (int u = 0; u < 4; ++u){
    float xv = h2f(vh[u]);
    int c = lane*4 + u;
    p1 += xv * w1[c];
    if (w2) p2 += xv * w2[c];
  }
  for (int o = 32; o > 0; o >>= 1){
    p1 += __shfl_down(p1, o);
    if (w2) p2 += __shfl_down(p2, o);
  }
  if (lane == 0){ y1[m] = p1; if (w2) y2[m] = p2; }
}

// ================= CSR build =================
__global__ void hist_k(const int* __restrict__ key, unsigned* __restrict__ deg, int E){
  int e = blockIdx.x*256 + threadIdx.x;
  if (e >= E) return;
  atomicAdd(&deg[key[e]], 1u);
}

__global__ __launch_bounds__(256) void scan1_k(const unsigned* __restrict__ deg,
    unsigned* __restrict__ incl, unsigned* __restrict__ bsum, int N)
{
  __shared__ unsigned sm[256];
  int t = threadIdx.x;
  int i = blockIdx.x*256 + t;
  unsigned v = (i < N) ? deg[i] : 0u;
  sm[t] = v; __syncthreads();
  for (int s = 1; s < 256; s <<= 1){
    unsigned u = (t >= s) ? sm[t - s] : 0u;
    __syncthreads();
    sm[t] += u;
    __syncthreads();
  }
  if (i < N) incl[i] = sm[t];
  if (t == 255) bsum[blockIdx.x] = sm[255];
}

__global__ __launch_bounds__(256) void scan2_k(unsigned* __restrict__ bsum, int nb){
  __shared__ unsigned sm[256];
  __shared__ unsigned carry;
  int t = threadIdx.x;
  if (t == 0) carry = 0u;
  __syncthreads();
  for (int base = 0; base < nb; base += 256){
    int i = base + t;
    unsigned v = (i < nb) ? bsum[i] : 0u;
    sm[t] = v; __syncthreads();
    for (int s = 1; s < 256; s <<= 1){
      unsigned u = (t >= s) ? sm[t - s] : 0u;
      __syncthreads();
      sm[t] += u;
      __syncthreads();
    }
    unsigned total = sm[255];
    unsigned c = carry;
    if (i < nb) bsum[i] = c + sm[t] - v;
    __syncthreads();
    if (t == 0) carry = c + total;
    __syncthreads();
  }
}

__global__ void scan3_k(const unsigned* __restrict__ incl, const unsigned* __restrict__ deg,
    const unsigned* __restrict__ bsum, unsigned* __restrict__ off, int N, int E)
{
  int i = blockIdx.x*256 + threadIdx.x;
  if (i < N) off[i] = incl[i] - deg[i] + bsum[blockIdx.x];
  if (i == 0) off[N] = (unsigned)E;
}

__global__ void fill_k(const int* __restrict__ src, const int* __restrict__ dst,
    const unsigned* __restrict__ off, unsigned* __restrict__ cur,
    int* __restrict__ csr_src, int* __restrict__ csr_eid, int* __restrict__ epos, int E)
{
  int e = blockIdx.x*256 + threadIdx.x;
  if (e >= E) return;
  int d = dst[e];
  unsigned p = off[d] + atomicAdd(&cur[d], 1u);
  csr_src[p] = src[e];
  csr_eid[p] = e;
  epos[e] = (int)p;
}

__global__ void fill2_k(const int* __restrict__ src, const int* __restrict__ epos,
    const unsigned* __restrict__ off2, unsigned* __restrict__ cur,
    int* __restrict__ csc_pos, int E)
{
  int e = blockIdx.x*256 + threadIdx.x;
  if (e >= E) return;
  int s = src[e];
  unsigned qq = off2[s] + atomicAdd(&cur[s], 1u);
  csc_pos[qq] = epos[e];
}

// ---------------- GATEConv edge score, iterated by SRC node (Y fp16 single) ----------------
__global__ __launch_bounds__(256) void gate_edge_score_csc_k(
    const unsigned short* __restrict__ YB,
    const float* __restrict__ g_lin1W,
    const float* __restrict__ att_l, const float* __restrict__ ea_in,
    const float* __restrict__ xr,
    const unsigned* __restrict__ off2, const int* __restrict__ csc_pos,
    const int* __restrict__ csr_eid, const int* __restrict__ dst,
    float* __restrict__ a_out, int N, int H)
{
  int s = blockIdx.x*4 + (threadIdx.x >> 6);
  if (s >= N) return;
  int lane = threadIdx.x & 63;
  unsigned q0 = off2[s], q1 = off2[s+1];
  if (q0 == q1) return;
  us4 vh = *(const us4*)&YB[(size_t)s*256 + lane*4];
  float y4[4], w4[4], a4[4];
  #pragma unroll
  for (int u = 0; u < 4; ++u){
    int c = lane*4 + u;
    y4[u] = h2f(vh[u]);
    w4[u] = g_lin1W[(size_t)c*(H+1) + H];   // edge-attr column
    a4[u] = att_l[c];
  }
  for (unsigned qq = q0; qq < q1; ++qq){
    int p = csc_pos[qq];
    int e = csr_eid[p];
    int d = dst[e];
    float eav = ea_in[e];
    float acc = 0.f;
    #pragma unroll
    for (int u = 0; u < 4; ++u)
      acc += lreluf(y4[u] + eav * w4[u]) * a4[u];
    for (int o = 32; o > 0; o >>= 1) acc += __shfl_down(acc, o);
    if (lane == 0) a_out[p] = lreluf(acc + xr[d]);
  }
}

// ---------------- per-node segment softmax over CSR ----------------
__global__ void node_softmax_k(const unsigned* __restrict__ off, const int* __restrict__ csr_src,
    const float* __restrict__ nd1, const float* __restrict__ nd2,
    float* __restrict__ w, int N, int mode)
{
  int n = blockIdx.x*256 + threadIdx.x;
  if (n >= N) return;
  unsigned p0 = off[n], p1 = off[n+1];
  float m = -INFINITY;
  if (mode){
    float d = nd2[n];
    for (unsigned p = p0; p < p1; ++p){
      float a = lreluf(nd1[csr_src[p]] + d);
      w[p] = a;
      m = fmaxf(m, a);
    }
  } else {
    for (unsigned p = p0; p < p1; ++p) m = fmaxf(m, w[p]);
  }
  float ssum = 0.f;
  for (unsigned p = p0; p < p1; ++p){
    float e = expf(w[p] - m);
    w[p] = e; ssum += e;
  }
  float inv = (ssum > 0.f) ? 1.f/ssum : 0.f;
  for (unsigned p = p0; p < p1; ++p) w[p] *= inv;
}

// ---------------- gather: h[n] = elu( sum w*Z[src] + bias ), fp16 in/out ----------------
__global__ __launch_bounds__(256) void gather_h_k(
    const unsigned short* __restrict__ ZB,
    const float* __restrict__ w, const unsigned* __restrict__ off,
    const int* __restrict__ csr_src, const float* __restrict__ bias,
    unsigned short* __restrict__ hB, int N)
{
  int n = blockIdx.x*4 + (threadIdx.x >> 6);
  if (n >= N) return;
  int lane = threadIdx.x & 63;
  unsigned p0 = off[n], p1 = off[n+1];
  float4 acc = make_float4(0.f, 0.f, 0.f, 0.f);
  if (p0 < p1){
    us4 zh_n = *(const us4*)&ZB[(size_t)csr_src[p0]*256 + lane*4];
    float w_n = w[p0];
    for (unsigned p = p0; p < p1; ++p){
      us4 zh = zh_n;
      float wv = w_n;
      if (p + 1 < p1){
        zh_n = *(const us4*)&ZB[(size_t)csr_src[p+1]*256 + lane*4];
        w_n = w[p+1];
      }
      acc.x = fmaf(wv, h2f(zh[0]), acc.x);
      acc.y = fmaf(wv, h2f(zh[1]), acc.y);
      acc.z = fmaf(wv, h2f(zh[2]), acc.z);
      acc.w = fmaf(wv, h2f(zh[3]), acc.w);
    }
  }
  const float4 b = *(const float4*)&bias[lane*4];
  us4 vo;
  float v;
  v = acc.x + b.x; vo[0] = f2h(v > 0.f ? v : expf(v) - 1.f);
  v = acc.y + b.y; vo[1] = f2h(v > 0.f ? v : expf(v) - 1.f);
  v = acc.z + b.z; vo[2] = f2h(v > 0.f ? v : expf(v) - 1.f);
  v = acc.w + b.w; vo[3] = f2h(v > 0.f ? v : expf(v) - 1.f);
  *(us4*)&hB[(size_t)n*256 + lane*4] = vo;
}

// ---------------- pooling ----------------
__global__ void seg_bounds_k(const int* __restrict__ batch, unsigned* __restrict__ gs,
                             unsigned* __restrict__ ge, int N){
  int n = blockIdx.x*256 + threadIdx.x;
  if (n >= N) return;
  int g = batch[n];
  atomicMin(&gs[g], (unsigned)n);
  atomicMax(&ge[g], (unsigned)(n+1));
}
__global__ __launch_bounds__(256) void graph_pool_k(
    const unsigned short* __restrict__ xB,
    const unsigned* __restrict__ gs, const unsigned* __restrict__ ge,
    unsigned short* __restrict__ ogH, unsigned short* __restrict__ ogL)
{
  int g = blockIdx.x, t = threadIdx.x;
  unsigned s0 = gs[g], e0 = ge[g];
  float acc = 0.f;
  for (unsigned n = s0; n < e0; ++n)
    acc += h2f(xB[(size_t)n*256 + t]);
  acc = acc > 0.f ? acc : 0.f;
  unsigned short h, l; split2h(acc, h, l);
  ogH[(size_t)g*256 + t] = h;
  ogL[(size_t)g*256 + t] = l;
}
__global__ void precompute_v_k(const float* __restrict__ W, const float* __restrict__ ad,
                               float* __restrict__ v){
  int i = threadIdx.x;
  float acc = 0.f;
  for (int j = 0; j < 256; ++j) acc += W[(size_t)j*256 + i] * ad[j];
  v[i] = acc;
}
// fused mol attention timestep (og pair, xw single, hg pair out)
__global__ __launch_bounds__(256) void mol_pool_k(
    const unsigned short* __restrict__ ogH, const unsigned short* __restrict__ ogL,
    const float* __restrict__ v, const float* __restrict__ asrc,
    const unsigned short* __restrict__ xwB,
    const unsigned* __restrict__ gs, const unsigned* __restrict__ geb,
    const float* __restrict__ bias,
    unsigned short* __restrict__ hgH, unsigned short* __restrict__ hgL)
{
  __shared__ float red[256];
  int g = blockIdx.x, t = threadIdx.x;
  float ogv = rec2h(ogH[(size_t)g*256 + t], ogL[(size_t)g*256 + t]);
  float tg = blkSum(ogv * v[t], red);
  unsigned s0 = gs[g], e0 = geb[g];
  float mx = -INFINITY;
  for (unsigned n = s0 + t; n < e0; n += 256) mx = fmaxf(mx, lreluf(asrc[n] + tg));
  mx = blkMax(mx, red);
  float sm = 0.f;
  for (unsigned n = s0 + t; n < e0; n += 256) sm += expf(lreluf(asrc[n] + tg) - mx);
  sm = blkSum(sm, red);
  float acc = 0.f;
  if (e0 > s0 && sm > 0.f){
    float inv = 1.f / sm;
    for (unsigned n = s0; n < e0; ++n){
      float w = expf(lreluf(asrc[n] + tg) - mx) * inv;
      acc = fmaf(w, h2f(xwB[(size_t)n*256 + t]), acc);
    }
  }
  float h0 = acc + bias[t];
  h0 = h0 > 0.f ? h0 : expf(h0) - 1.f;
  unsigned short h, l; split2h(h0, h, l);
  hgH[(size_t)g*256 + t] = h;
  hgL[(size_t)g*256 + t] = l;
}

// ---------------- launcher ----------------
extern "C" void kernel_launch(void* const* d_in, const int* in_sizes, int n_in,
                              void* d_out, int out_size, void* d_ws, size_t ws_size,
                              hipStream_t stream)
{
  (void)n_in; (void)ws_size;
  const int H    = in_sizes[3];          // 256
  const int NIN  = in_sizes[2] / H;      // 300
  const int N    = in_sizes[0] / NIN;    // 100000
  const int E    = in_sizes[1];          // 400000
  const int NL   = in_sizes[16] / H;     // 3
  const int NHID = in_sizes[30];         // 512
  const int NOUT = in_sizes[32];         // 768
  const int G    = out_size / NOUT;      // 2048
  const int T    = 16;

  const float* x_in     = (const float*)d_in[0];
  const float* ea_in    = (const float*)d_in[1];
  const float* lin1_W   = (const float*)d_in[2];
  const float* lin1_b   = (const float*)d_in[3];
  const float* g_lin1W  = (const float*)d_in[4];
  const float* g_lin2W  = (const float*)d_in[5];
  const float* g_att_l  = (const float*)d_in[6];
  const float* g_att_r  = (const float*)d_in[7];
  const float* g_bias   = (const float*)d_in[8];
  const float* gru0_wih = (const float*)d_in[9];
  const float* gru0_whh = (const float*)d_in[10];
  const float* gru0_bih = (const float*)d_in[11];
  const float* gru0_bhh = (const float*)d_in[12];
  const float* atom_W   = (const float*)d_in[13];
  const float* atom_as  = (const float*)d_in[14];
  const float* atom_ad  = (const float*)d_in[15];
  const float* atom_b   = (const float*)d_in[16];
  const float* agru_wih = (const float*)d_in[17];
  const float* agru_whh = (const float*)d_in[18];
  const float* agru_bih = (const float*)d_in[19];
  const float* agru_bhh = (const float*)d_in[20];
  const float* mol_W    = (const float*)d_in[21];
  const float* mol_as   = (const float*)d_in[22];
  const float* mol_ad   = (const float*)d_in[23];
  const float* mol_b    = (const float*)d_in[24];
  const float* mgru_wih = (const float*)d_in[25];
  const float* mgru_whh = (const float*)d_in[26];
  const float* mgru_bih = (const float*)d_in[27];
  const float* mgru_bhh = (const float*)d_in[28];
  const float* lin2_W   = (const float*)d_in[29];
  const float* lin2_b   = (const float*)d_in[30];
  const float* fc1_W    = (const float*)d_in[31];
  const float* fc1_b    = (const float*)d_in[32];
  const int*  eidx      = (const int*)d_in[33];
  const int*  batch     = (const int*)d_in[34];
  const int*  srcI = eidx;
  const int*  dstI = eidx + E;

  char* wp = (char*)d_ws;
  auto alloc = [&](size_t bytes)->void*{
    void* p = (void*)wp;
    wp += (bytes + 255) & ~(size_t)255;
    return p;
  };
  auto allocUS = [&](size_t elems)->unsigned short*{ return (unsigned short*)alloc(elems*2); };

  // activations: 4 single fp16 buffers
  unsigned short *x   = allocUS((size_t)N*H);
  unsigned short *hb  = allocUS((size_t)N*H);
  unsigned short *out = allocUS((size_t)N*H);
  unsigned short *xw  = allocUS((size_t)N*H);
  float*    ea    = (float*)alloc((size_t)E*4);
  float*    nd1   = (float*)alloc((size_t)N*4);
  float*    nd2   = (float*)alloc((size_t)N*4);
  unsigned short *ogH  = allocUS((size_t)G*H), *ogL  = allocUS((size_t)G*H);
  unsigned short *og2H = allocUS((size_t)G*H), *og2L = allocUS((size_t)G*H);
  unsigned short *hgH  = allocUS((size_t)G*H), *hgL  = allocUS((size_t)G*H);
  unsigned short *o2H  = allocUS((size_t)G*NHID), *o2L = allocUS((size_t)G*NHID);
  unsigned* gsb   = (unsigned*)alloc((size_t)G*4);
  unsigned* geb   = (unsigned*)alloc((size_t)G*4);
  float*    vvec  = (float*)alloc((size_t)H*4);
  // CSR/CSC structures
  const int nb = (N + 255) / 256;
  unsigned* deg     = (unsigned*)alloc((size_t)N*4);
  unsigned* cur     = (unsigned*)alloc((size_t)N*4);
  unsigned* incl    = (unsigned*)alloc((size_t)N*4);
  unsigned* off     = (unsigned*)alloc((size_t)(N+1)*4);
  unsigned* off2    = (unsigned*)alloc((size_t)(N+1)*4);
  unsigned* bsum    = (unsigned*)alloc((size_t)nb*4);
  int*      csr_src = (int*)alloc((size_t)E*4);
  int*      csr_eid = (int*)alloc((size_t)E*4);
  int*      epos    = (int*)alloc((size_t)E*4);
  int*      csc_pos = (int*)alloc((size_t)E*4);
  // weights: all fp16 pairs
  const size_t WG = (size_t)768*256;
  const size_t WS = (size_t)256*256;
  unsigned short *g0ihH = allocUS(WG), *g0ihL = allocUS(WG);
  unsigned short *g0hhH = allocUS(WG), *g0hhL = allocUS(WG);
  unsigned short *aihH  = allocUS(WG*NL), *aihL = allocUS(WG*NL);
  unsigned short *ahhH  = allocUS(WG*NL), *ahhL = allocUS(WG*NL);
  unsigned short *mihH  = allocUS(WG), *mihL = allocUS(WG);
  unsigned short *mhhH  = allocUS(WG), *mhhL = allocUS(WG);
  unsigned short *gl1H  = allocUS(WS), *gl1L = allocUS(WS);
  unsigned short *gl2H  = allocUS(WS), *gl2L = allocUS(WS);
  unsigned short *atWH  = allocUS(WS*NL), *atWL = allocUS(WS*NL);
  unsigned short *molWH = allocUS(WS), *molWL = allocUS(WS);
  unsigned short *l2WH  = allocUS((size_t)NHID*256), *l2WL = allocUS((size_t)NHID*256);
  unsigned short *f1WH  = allocUS((size_t)NOUT*NHID), *f1WL = allocUS((size_t)NOUT*NHID);

  auto gemms = [&](const unsigned short* A_, const unsigned short* WH_,
                   const unsigned short* WL_, unsigned short* CB, int M_){
    int nwg = ((M_ + 63)/64)*4;
    gemm16s_k<<<dim3(nwg), dim3(256), 0, stream>>>(A_, WH_, WL_, CB, M_);
  };
  auto gruN = [&](const unsigned short* Xi, const unsigned short* Hi,
                  const unsigned short* ihH, const unsigned short* ihL,
                  const unsigned short* hhH, const unsigned short* hhL,
                  const float* bih, const float* bhh,
                  unsigned short* O, int M_){
    int nwg = ((M_ + 63)/64)*4;
    gru16_k<<<dim3(nwg), dim3(256), 0, stream>>>(Xi, Hi, ihH, ihL, hhH, hhL, bih, bhh, O, M_);
  };
  auto wsplit = [&](const float* src, unsigned short* Hd, unsigned short* Ld,
                    int lda, int K, long long rows){
    long long tot = rows * K;
    wsplit16_k<<<dim3((unsigned)((tot + 255)/256)), dim3(256), 0, stream>>>(src, Hd, Ld, lda, K, tot);
  };

  // ---- split all weights to fp16 pairs (error ~2^-22)
  wsplit(gru0_wih, g0ihH, g0ihL, 256, 256, 768);
  wsplit(gru0_whh, g0hhH, g0hhL, 256, 256, 768);
  wsplit(agru_wih, aihH, aihL, 256, 256, (long long)NL*768);
  wsplit(agru_whh, ahhH, ahhL, 256, 256, (long long)NL*768);
  wsplit(mgru_wih, mihH, mihL, 256, 256, 768);
  wsplit(mgru_whh, mhhH, mhhL, 256, 256, 768);
  wsplit(g_lin1W,  gl1H, gl1L, H+1, 256, 256);
  wsplit(g_lin2W,  gl2H, gl2L, 256, 256, 256);
  wsplit(atom_W,   atWH, atWL, 256, 256, (long long)NL*256);
  wsplit(mol_W,    molWH, molWL, 256, 256, 256);
  wsplit(lin2_W, l2WH, l2WL, 256, 256, NHID);
  wsplit(fc1_W,  f1WH, f1WL, NHID, NHID, NOUT);

  // ---- build dst-CSR + src-CSC
  hipMemsetAsync(deg, 0, (size_t)N*4, stream);
  hist_k<<<dim3((E+255)/256), dim3(256), 0, stream>>>(dstI, deg, E);
  scan1_k<<<dim3(nb), dim3(256), 0, stream>>>(deg, incl, bsum, N);
  scan2_k<<<dim3(1), dim3(256), 0, stream>>>(bsum, nb);
  scan3_k<<<dim3(nb), dim3(256), 0, stream>>>(incl, deg, bsum, off, N, E);
  hipMemsetAsync(cur, 0, (size_t)N*4, stream);
  fill_k<<<dim3((E+255)/256), dim3(256), 0, stream>>>(srcI, dstI, off, cur, csr_src, csr_eid, epos, E);
  hipMemsetAsync(deg, 0, (size_t)N*4, stream);
  hist_k<<<dim3((E+255)/256), dim3(256), 0, stream>>>(srcI, deg, E);
  scan1_k<<<dim3(nb), dim3(256), 0, stream>>>(deg, incl, bsum, N);
  scan2_k<<<dim3(1), dim3(256), 0, stream>>>(bsum, nb);
  scan3_k<<<dim3(nb), dim3(256), 0, stream>>>(incl, deg, bsum, off2, N, E);
  hipMemsetAsync(cur, 0, (size_t)N*4, stream);
  fill2_k<<<dim3((E+255)/256), dim3(256), 0, stream>>>(srcI, epos, off2, cur, csc_pos, E);

  // ---- input projection (K=300, split x split) -> x single fp16
  {
    dim3 gr(4, (N + 63)/64);
    gemm_l1_k<<<gr, dim3(256), 0, stream>>>(x_in, NIN, lin1_W, NIN, lin1_b,
                                            x, N, H, NIN, OP_LRELU);
  }

  // ---- GATEConv: Y -> out (scratch, dead before GRU writes), Z -> xw
  {
    int nwg = ((N + 63)/64)*4;
    gemm2s_k<<<dim3(nwg), dim3(256), 0, stream>>>(x, gl1H, gl1L, gl2H, gl2L, out, xw, N);
  }
  rowdot_h_k<<<dim3((N+3)/4), dim3(256), 0, stream>>>(x, g_att_r, (const float*)nullptr,
                                                      nd1, (float*)nullptr, N);
  gate_edge_score_csc_k<<<dim3((N+3)/4), dim3(256), 0, stream>>>(out, g_lin1W, g_att_l,
                                                                 ea_in, nd1, off2, csc_pos,
                                                                 csr_eid, dstI, ea, N, H);
  node_softmax_k<<<dim3(nb), dim3(256), 0, stream>>>(off, csr_src, nullptr, nullptr, ea, N, 0);
  gather_h_k<<<dim3((N+3)/4), dim3(256), 0, stream>>>(xw, ea, off, csr_src, g_bias, hb, N);
  gruN(hb, x, g0ihH, g0ihL, g0hhH, g0hhL, gru0_bih, gru0_bhh, out, N);
  { unsigned short* t = x; x = out; out = t; }

  // ---- atom GATConv layers
  for (int l = 0; l < NL; ++l){
    gemms(x, atWH + (size_t)l*WS, atWL + (size_t)l*WS, xw, N);
    rowdot_h_k<<<dim3((N+3)/4), dim3(256), 0, stream>>>(xw, atom_as + (size_t)l*H,
                                                        atom_ad + (size_t)l*H, nd1, nd2, N);
    node_softmax_k<<<dim3(nb), dim3(256), 0, stream>>>(off, csr_src, nd1, nd2, ea, N, 1);
    gather_h_k<<<dim3((N+3)/4), dim3(256), 0, stream>>>(xw, ea, off, csr_src,
                                                        atom_b + (size_t)l*H, hb, N);
    gruN(hb, x, aihH + (size_t)l*WG, aihL + (size_t)l*WG,
         ahhH + (size_t)l*WG, ahhL + (size_t)l*WG,
         agru_bih + (size_t)l*3*H, agru_bhh + (size_t)l*3*H, out, N);
    { unsigned short* t = x; x = out; out = t; }
  }

  // ---- attentive pooling
  hipMemsetAsync(gsb, 0xFF, (size_t)G*4, stream);
  hipMemsetAsync(geb, 0x00, (size_t)G*4, stream);
  seg_bounds_k<<<dim3((N+255)/256), dim3(256), 0, stream>>>(batch, gsb, geb, N);
  graph_pool_k<<<dim3(G), dim3(256), 0, stream>>>(x, gsb, geb, ogH, ogL);
  gemms(x, molWH, molWL, xw, N);
  rowdot_h_k<<<dim3((N+3)/4), dim3(256), 0, stream>>>(xw, mol_as, (const float*)nullptr,
                                                      nd1, (float*)nullptr, N);
  precompute_v_k<<<dim3(1), dim3(256), 0, stream>>>(mol_W, mol_ad, vvec);
  unsigned short *cogH = ogH, *cogL = ogL, *cog2H = og2H, *cog2L = og2L;
  for (int t = 0; t < T; ++t){
    mol_pool_k<<<dim3(G), dim3(256), 0, stream>>>(cogH, cogL, vvec, nd1, xw,
                                                  gsb, geb, mol_b, hgH, hgL);
    gru16m_k<<<dim3(((G+63)/64)*4), dim3(256), 0, stream>>>(hgH, hgL, cogH, cogL,
                                                            mihH, mihL, mhhH, mhhL,
                                                            mgru_bih, mgru_bhh,
                                                            cog2H, cog2L, G);
    { unsigned short* tt = cogH; cogH = cog2H; cog2H = tt;
      tt = cogL; cogL = cog2L; cog2L = tt; }
  }

  // ---- head: lin2 (relu, pair out) then fc1 (f32 out), both 3-prod pair x pair
  {
    int ncb = NHID / 64;
    int nwg = ((G + 63)/64) * ncb;
    gemm16p_k<<<dim3(nwg), dim3(256), 0, stream>>>(cogH, cogL, l2WH, l2WL, lin2_b,
                                                   nullptr, o2H, o2L, G, NHID, 256, OP_RELU, ncb);
  }
  {
    int ncb = NOUT / 64;
    int nwg = ((G + 63)/64) * ncb;
    gemm16p_k<<<dim3(nwg), dim3(256), 0, stream>>>(o2H, o2L, f1WH, f1WL, fc1_b,
                                                   (float*)d_out, nullptr, nullptr,
                                                   G, NOUT, NHID, OP_NONE, ncb);
  }
}